// Round 3
// baseline (391.335 us; speedup 1.0000x reference)
//
#include <hip/hip_runtime.h>
#include <math.h>

static constexpr int BATCH = 4;
static constexpr int SEQ   = 2048;
static constexpr int DIM   = 1024;

typedef __attribute__((ext_vector_type(8))) short     bf16x8;  // MFMA A/B frag (4 VGPRs)
typedef __attribute__((ext_vector_type(4))) float     f32x4;   // MFMA C/D frag

// fp32 -> bf16 (RNE) and back, bit-exact helpers for hi/lo splitting
__device__ __forceinline__ unsigned short f2b(float v) {
    unsigned int u = __float_as_uint(v);
    u = u + 0x7fffu + ((u >> 16) & 1u);
    return (unsigned short)(u >> 16);
}
__device__ __forceinline__ float b2f(unsigned short h) {
    return __uint_as_float(((unsigned int)h) << 16);
}

// ---------------------------------------------------------------------------
// convert_x: fp32 -> (hi, lo) bf16, elementwise.
// ---------------------------------------------------------------------------
__global__ __launch_bounds__(256) void convert_x_kernel(
    const float* __restrict__ X, unsigned short* __restrict__ hi,
    unsigned short* __restrict__ lo)
{
    const int i = blockIdx.x * 256 + threadIdx.x;   // float4 index
    const float4 v = ((const float4*)X)[i];
    ushort4 h, l;
    h.x = f2b(v.x); l.x = f2b(v.x - b2f(h.x));
    h.y = f2b(v.y); l.y = f2b(v.y - b2f(h.y));
    h.z = f2b(v.z); l.z = f2b(v.z - b2f(h.z));
    h.w = f2b(v.w); l.w = f2b(v.w - b2f(h.w));
    ((ushort4*)hi)[i] = h;
    ((ushort4*)lo)[i] = l;
}

// ---------------------------------------------------------------------------
// convert_wqk: Wq (y=0) / Wk (y=1) fp32 -> hi/lo bf16, NO transpose.
// ---------------------------------------------------------------------------
__global__ __launch_bounds__(256) void convert_wqk_kernel(
    const float* __restrict__ Wq, const float* __restrict__ Wk,
    unsigned short* __restrict__ hi, unsigned short* __restrict__ lo)
{
    const int z = blockIdx.y;
    const float* __restrict__ W = z ? Wk : Wq;
    const int i = blockIdx.x * 256 + threadIdx.x;   // float4 index within matrix
    const int o = z * (DIM * DIM / 4) + i;
    const float4 v = ((const float4*)W)[i];
    ushort4 h, l;
    h.x = f2b(v.x); l.x = f2b(v.x - b2f(h.x));
    h.y = f2b(v.y); l.y = f2b(v.y - b2f(h.y));
    h.z = f2b(v.z); l.z = f2b(v.z - b2f(h.z));
    h.w = f2b(v.w); l.w = f2b(v.w - b2f(h.w));
    ((ushort4*)hi)[o] = h;
    ((ushort4*)lo)[o] = l;
}

// ---------------------------------------------------------------------------
// convert_wv: Wv[k][n] fp32 -> WvT[n][k] hi bf16 (V is single-term).
// ---------------------------------------------------------------------------
__global__ __launch_bounds__(256) void convert_wv_kernel(
    const float* __restrict__ W, unsigned short* __restrict__ WT)
{
    __shared__ float t[32][33];
    const int n0 = blockIdx.x * 32, k0 = blockIdx.y * 32;
    const int tx = threadIdx.x & 31, ty = threadIdx.x >> 5;  // ty: 0..7
#pragma unroll
    for (int i = 0; i < 4; ++i)
        t[ty + i * 8][tx] = W[(size_t)(k0 + ty + i * 8) * DIM + (n0 + tx)];
    __syncthreads();
#pragma unroll
    for (int i = 0; i < 4; ++i)
        WT[(size_t)(n0 + ty + i * 8) * DIM + (k0 + tx)] = f2b(t[tx][ty + i * 8]);
}

// ---------------------------------------------------------------------------
// mask_pack: int32 mask [2048][2048] -> bitmask [2048][32] u64 (bit=1: mask).
// ---------------------------------------------------------------------------
__global__ __launch_bounds__(256) void mask_pack_kernel(
    const int* __restrict__ mask, unsigned long long* __restrict__ Mb)
{
    const int row  = blockIdx.x;
    const int lane = threadIdx.x & 63, w = threadIdx.x >> 6;
#pragma unroll
    for (int c = w; c < SEQ / 64; c += 4) {
        const int v = mask[(size_t)row * SEQ + c * 64 + lane];
        const unsigned long long bits = __ballot(v != 0);
        if (lane == 0) Mb[(size_t)row * (SEQ / 64) + c] = bits;
    }
}

// ---------------------------------------------------------------------------
// Async staging of a (rows x 32)-elem bf16 tile via global_load_lds w=16.
// XOR-swizzled unpadded 64 B rows; wave-uniform LDS dest. Works for any
// block size that is a multiple of 64 (each wave stages 32 rows).
// ---------------------------------------------------------------------------
__device__ __forceinline__ void stage_async(
    const unsigned short* __restrict__ g, int gstride, int row0, int k0,
    unsigned short* lds, int tid)
{
    const int w = tid >> 6, lane = tid & 63;
    const int c = (lane & 3) ^ ((lane >> 4) & 3);   // global chunk this lane fetches
#pragma unroll
    for (int h = 0; h < 2; ++h) {
        const int row = 32 * w + 16 * h + (lane >> 2);
        const unsigned short* src = g + (size_t)(row0 + row) * gstride + k0 + 8 * c;
        unsigned short* dst = lds + (32 * w + 16 * h) * 32;   // wave-uniform
        __builtin_amdgcn_global_load_lds(
            (const __attribute__((address_space(1))) void*)src,
            (__attribute__((address_space(3))) void*)dst, 16, 0, 0);
    }
}

__device__ __forceinline__ bf16x8 fragr(const unsigned short* lds, int row, int qsw)
{
    return *(const bf16x8*)(lds + row * 32 + qsw * 8);
}

// ---------------------------------------------------------------------------
// m_gemm: Mt = Wk . Wq^T  (so Mt[j][i] = sum_o Wq[i][o] Wk[j][o]), 3-term
// split bf16, 128x128 tile, K-split over z (4 chunks of 256). fp32 partials.
// ---------------------------------------------------------------------------
__global__ __launch_bounds__(256) void m_gemm_kernel(
    const unsigned short* __restrict__ Whi, const unsigned short* __restrict__ Wlo,
    float* __restrict__ Mtp)
{
    __shared__ unsigned short Ah[128 * 32], Al[128 * 32];
    __shared__ unsigned short Bh[128 * 32], Bl[128 * 32];

    const int tid = threadIdx.x;
    const int w = tid >> 6, lane = tid & 63;
    const int wm = (w >> 1) * 64, wn = (w & 1) * 64;
    const int m0 = blockIdx.y * 128, n0 = blockIdx.x * 128;
    const int z = blockIdx.z;                        // K chunk

    const unsigned short* __restrict__ Ahg = Whi + (size_t)DIM * DIM;  // Wk hi
    const unsigned short* __restrict__ Alg = Wlo + (size_t)DIM * DIM;  // Wk lo
    const unsigned short* __restrict__ Bhg = Whi;                      // Wq hi
    const unsigned short* __restrict__ Blg = Wlo;                      // Wq lo
    float* __restrict__ Cp = Mtp + (size_t)z * DIM * DIM;

    f32x4 acc[4][4];
#pragma unroll
    for (int i = 0; i < 4; ++i)
#pragma unroll
        for (int j = 0; j < 4; ++j) acc[i][j] = (f32x4){0.f, 0.f, 0.f, 0.f};

    const int fr = lane & 15, quad = lane >> 4;
    const int qsw = quad ^ ((fr >> 2) & 3);

    for (int k0 = z * 256; k0 < z * 256 + 256; k0 += 32) {
        stage_async(Ahg, DIM, m0, k0, Ah, tid);
        stage_async(Alg, DIM, m0, k0, Al, tid);
        stage_async(Bhg, DIM, n0, k0, Bh, tid);
        stage_async(Blg, DIM, n0, k0, Bl, tid);
        __syncthreads();

        bf16x8 ah[4], al[4];
#pragma unroll
        for (int mt = 0; mt < 4; ++mt) {
            ah[mt] = fragr(Ah, wm + mt * 16 + fr, qsw);
            al[mt] = fragr(Al, wm + mt * 16 + fr, qsw);
        }
#pragma unroll
        for (int nt = 0; nt < 4; ++nt) {
            const bf16x8 bh = fragr(Bh, wn + nt * 16 + fr, qsw);
            const bf16x8 bl = fragr(Bl, wn + nt * 16 + fr, qsw);
#pragma unroll
            for (int mt = 0; mt < 4; ++mt) {
                acc[mt][nt] = __builtin_amdgcn_mfma_f32_16x16x32_bf16(ah[mt], bh, acc[mt][nt], 0, 0, 0);
                acc[mt][nt] = __builtin_amdgcn_mfma_f32_16x16x32_bf16(ah[mt], bl, acc[mt][nt], 0, 0, 0);
                acc[mt][nt] = __builtin_amdgcn_mfma_f32_16x16x32_bf16(al[mt], bh, acc[mt][nt], 0, 0, 0);
            }
        }
        __syncthreads();
    }

    const int col = lane & 15, rq = lane >> 4;
#pragma unroll
    for (int mt = 0; mt < 4; ++mt)
#pragma unroll
        for (int nt = 0; nt < 4; ++nt)
#pragma unroll
            for (int e = 0; e < 4; ++e) {
                const int m = m0 + wm + mt * 16 + rq * 4 + e;
                const int n = n0 + wn + nt * 16 + col;
                Cp[(size_t)m * DIM + n] = acc[mt][nt][e];
            }
}

// ---------------------------------------------------------------------------
// m_reduce: sum 4 K-split partials, split to hi/lo bf16.
// ---------------------------------------------------------------------------
__global__ __launch_bounds__(256) void m_reduce_kernel(
    const float* __restrict__ Mtp, unsigned short* __restrict__ Mthi,
    unsigned short* __restrict__ Mtlo)
{
    const int i = blockIdx.x * 256 + threadIdx.x;   // float4 index
    const size_t q = (size_t)DIM * DIM / 4;
    const float4 a = ((const float4*)Mtp)[i];
    const float4 b = ((const float4*)Mtp)[i + q];
    const float4 c = ((const float4*)Mtp)[i + 2 * q];
    const float4 d = ((const float4*)Mtp)[i + 3 * q];
    const float4 v = make_float4(a.x + b.x + c.x + d.x, a.y + b.y + c.y + d.y,
                                 a.z + b.z + c.z + d.z, a.w + b.w + c.w + d.w);
    ushort4 h, l;
    h.x = f2b(v.x); l.x = f2b(v.x - b2f(h.x));
    h.y = f2b(v.y); l.y = f2b(v.y - b2f(h.y));
    h.z = f2b(v.z); l.z = f2b(v.z - b2f(h.z));
    h.w = f2b(v.w); l.w = f2b(v.w - b2f(h.w));
    ((ushort4*)Mthi)[i] = h;
    ((ushort4*)Mtlo)[i] = l;
}

// ---------------------------------------------------------------------------
// yv_gemm: z=0 -> Y = X @ Mt^T (3-term, hi/lo out, [8192][1024])
//          z=1 -> V = X @ WvT^T (1-term), written TRANSPOSED as Vt[b][d][s]
// ---------------------------------------------------------------------------
__global__ __launch_bounds__(256) void yv_gemm_kernel(
    const unsigned short* __restrict__ Xhi, const unsigned short* __restrict__ Xlo,
    const unsigned short* __restrict__ Mthi, const unsigned short* __restrict__ Mtlo,
    const unsigned short* __restrict__ WvT,
    unsigned short* __restrict__ Yhi, unsigned short* __restrict__ Ylo,
    unsigned short* __restrict__ Vt)
{
    __shared__ unsigned short Ah[128 * 32], Al[128 * 32];
    __shared__ unsigned short Bh[128 * 32], Bl[128 * 32];

    const int tid = threadIdx.x;
    const int w = tid >> 6, lane = tid & 63;
    const int wm = (w >> 1) * 64, wn = (w & 1) * 64;
    const int m0 = blockIdx.y * 128, n0 = blockIdx.x * 128;
    const int z = blockIdx.z;
    const bool full = (z == 0);

    const unsigned short* __restrict__ Bhg = full ? Mthi : WvT;
    const unsigned short* __restrict__ Blg = Mtlo;

    f32x4 acc[4][4];
#pragma unroll
    for (int i = 0; i < 4; ++i)
#pragma unroll
        for (int j = 0; j < 4; ++j) acc[i][j] = (f32x4){0.f, 0.f, 0.f, 0.f};

    const int fr = lane & 15, quad = lane >> 4;
    const int qsw = quad ^ ((fr >> 2) & 3);

    for (int k0 = 0; k0 < DIM; k0 += 32) {
        stage_async(Xhi, DIM, m0, k0, Ah, tid);
        stage_async(Bhg, DIM, n0, k0, Bh, tid);
        if (full) {
            stage_async(Xlo, DIM, m0, k0, Al, tid);
            stage_async(Blg, DIM, n0, k0, Bl, tid);
        }
        __syncthreads();

        bf16x8 ah[4], al[4];
#pragma unroll
        for (int mt = 0; mt < 4; ++mt)
            ah[mt] = fragr(Ah, wm + mt * 16 + fr, qsw);
        if (full) {
#pragma unroll
            for (int mt = 0; mt < 4; ++mt)
                al[mt] = fragr(Al, wm + mt * 16 + fr, qsw);
        }
#pragma unroll
        for (int nt = 0; nt < 4; ++nt) {
            const bf16x8 bh = fragr(Bh, wn + nt * 16 + fr, qsw);
#pragma unroll
            for (int mt = 0; mt < 4; ++mt)
                acc[mt][nt] = __builtin_amdgcn_mfma_f32_16x16x32_bf16(ah[mt], bh, acc[mt][nt], 0, 0, 0);
            if (full) {
                const bf16x8 bl = fragr(Bl, wn + nt * 16 + fr, qsw);
#pragma unroll
                for (int mt = 0; mt < 4; ++mt) {
                    acc[mt][nt] = __builtin_amdgcn_mfma_f32_16x16x32_bf16(ah[mt], bl, acc[mt][nt], 0, 0, 0);
                    acc[mt][nt] = __builtin_amdgcn_mfma_f32_16x16x32_bf16(al[mt], bh, acc[mt][nt], 0, 0, 0);
                }
            }
        }
        __syncthreads();
    }

    const int col = lane & 15, rq = lane >> 4;
    if (full) {
#pragma unroll
        for (int mt = 0; mt < 4; ++mt)
#pragma unroll
            for (int nt = 0; nt < 4; ++nt)
#pragma unroll
                for (int e = 0; e < 4; ++e) {
                    const int m = m0 + wm + mt * 16 + rq * 4 + e;
                    const int n = n0 + wn + nt * 16 + col;
                    const float v = acc[mt][nt][e];
                    const unsigned short h = f2b(v);
                    Yhi[(size_t)m * DIM + n] = h;
                    Ylo[(size_t)m * DIM + n] = f2b(v - b2f(h));
                }
    } else {
        // V: write transposed, Vt[b][n][s], 4 consecutive s per ushort4
#pragma unroll
        for (int mt = 0; mt < 4; ++mt)
#pragma unroll
            for (int nt = 0; nt < 4; ++nt) {
                const int m = m0 + wm + mt * 16 + rq * 4;      // 4-aligned
                const int bb = m >> 11, s = m & (SEQ - 1);
                const int n = n0 + wn + nt * 16 + col;
                ushort4 pk;
                pk.x = f2b(acc[mt][nt][0]);
                pk.y = f2b(acc[mt][nt][1]);
                pk.z = f2b(acc[mt][nt][2]);
                pk.w = f2b(acc[mt][nt][3]);
                *(ushort4*)(Vt + (size_t)bb * DIM * SEQ + (size_t)n * SEQ + s) = pk;
            }
    }
}

// ---------------------------------------------------------------------------
// s_gemm256: S[b] = (Y[b] . X[b]^T) * 1/32, masked to -inf. fp32 output.
// 256x256 tile, BK=32, 512 threads (8 waves, 2Mx4N, 128x64 per wave).
// 6-PHASE term schedule, 16-MFMA clusters, counted vmcnt (T3+T4+T5):
//   ph0a: stage Ah' | vmcnt(6) bar | read ah[0-3],bh[0-3] | 16 MFMA hh-m0
//   ph0b: stage Bh' |               read ah[4-7]          | 16 MFMA hh-m1
//   ph1a: stage Bl' | vmcnt(8) bar | read bl[0-3]         | 16 MFMA hl-m0
//   ph1b:                                                   16 MFMA hl-m1
//   ph2a: stage Al' | vmcnt(8) bar | read al[0-3]         | 16 MFMA lh-m0
//   ph2b:                           read al[4-7]          | 16 MFMA lh-m1
// b-phases read only tiles already guaranteed by the preceding a-phase's
// vmcnt+barrier, so barrier count stays 3/iter. Accumulation per acc element
// stays hh -> hl -> lh per K-step (bit-exact vs previous version).
// Mask applied from the packed bitmask (1 u64 load per (mt,e) row-word).
// ---------------------------------------------------------------------------
__global__ __launch_bounds__(512, 2) void s_gemm256_kernel(
    const unsigned short* __restrict__ Yhi, const unsigned short* __restrict__ Ylo,
    const unsigned short* __restrict__ Xhi, const unsigned short* __restrict__ Xlo,
    const unsigned long long* __restrict__ Mb, float* __restrict__ Sc)
{
    extern __shared__ unsigned short smem[];
    // layout (ushort offsets): buffer c at c*32768:
    //   Ah = +0, Al = +8192, Bh = +16384, Bl = +24576   (each 256x32)

    const int tid = threadIdx.x;
    const int w = tid >> 6, lane = tid & 63;
    const int wm = (w >> 2) * 128, wn = (w & 3) * 64;
    const int m0 = blockIdx.y * 256, n0 = blockIdx.x * 256;
    const int b = blockIdx.z;

    const unsigned short* __restrict__ Ahg = Yhi + (size_t)b * SEQ * DIM;
    const unsigned short* __restrict__ Alg = Ylo + (size_t)b * SEQ * DIM;
    const unsigned short* __restrict__ Bhg = Xhi + (size_t)b * SEQ * DIM;
    const unsigned short* __restrict__ Blg = Xlo + (size_t)b * SEQ * DIM;
    float* __restrict__ Sb = Sc + (size_t)b * SEQ * SEQ;

    f32x4 acc[8][4];
#pragma unroll
    for (int i = 0; i < 8; ++i)
#pragma unroll
        for (int j = 0; j < 4; ++j) acc[i][j] = (f32x4){0.f, 0.f, 0.f, 0.f};

    const int fr = lane & 15, quad = lane >> 4;
    const int qsw = quad ^ ((fr >> 2) & 3);

    // prologue: issue K-step 0 into buffer 0 in phase-consumption order.
    stage_async(Ahg, DIM, m0, 0, smem + 0,     tid);
    stage_async(Bhg, DIM, n0, 0, smem + 16384, tid);
    stage_async(Blg, DIM, n0, 0, smem + 24576, tid);
    stage_async(Alg, DIM, m0, 0, smem + 8192,  tid);

    for (int it = 0; it < DIM / 32 - 1; ++it) {
        const int cur = (it & 1) * 32768;
        const int nxt = cur ^ 32768;
        const unsigned short* Ah = smem + cur;
        const unsigned short* Al = smem + cur + 8192;
        const unsigned short* Bh = smem + cur + 16384;
        const unsigned short* Bl = smem + cur + 24576;
        const int k1 = it * 32 + 32;

        bf16x8 ah[8], al[8], bh[4], bl[4];

        // ---- ph0a (hh, m-half 0) ----
        stage_async(Ahg, DIM, m0, k1, smem + nxt, tid);
        asm volatile("s_waitcnt vmcnt(6)" ::: "memory");
        __builtin_amdgcn_s_barrier();
#pragma unroll
        for (int mt = 0; mt < 4; ++mt)
            ah[mt] = fragr(Ah, wm + mt * 16 + fr, qsw);
#pragma unroll
        for (int nt = 0; nt < 4; ++nt)
            bh[nt] = fragr(Bh, wn + nt * 16 + fr, qsw);
        __builtin_amdgcn_s_setprio(1);
#pragma unroll
        for (int nt = 0; nt < 4; ++nt)
#pragma unroll
            for (int mt = 0; mt < 4; ++mt)
                acc[mt][nt] = __builtin_amdgcn_mfma_f32_16x16x32_bf16(ah[mt], bh[nt], acc[mt][nt], 0, 0, 0);
        __builtin_amdgcn_s_setprio(0);

        // ---- ph0b (hh, m-half 1) ----
        stage_async(Bhg, DIM, n0, k1, smem + nxt + 16384, tid);
#pragma unroll
        for (int mt = 4; mt < 8; ++mt)
            ah[mt] = fragr(Ah, wm + mt * 16 + fr, qsw);
        __builtin_amdgcn_s_setprio(1);
#pragma unroll
        for (int nt = 0; nt < 4; ++nt)
#pragma unroll
            for (int mt = 4; mt < 8; ++mt)
                acc[mt][nt] = __builtin_amdgcn_mfma_f32_16x16x32_bf16(ah[mt], bh[nt], acc[mt][nt], 0, 0, 0);
        __builtin_amdgcn_s_setprio(0);

        // ---- ph1a (hl, m-half 0) ----
        stage_async(Blg, DIM, n0, k1, smem + nxt + 24576, tid);
        asm volatile("s_waitcnt vmcnt(8)" ::: "memory");
        __builtin_amdgcn_s_barrier();
#pragma unroll
        for (int nt = 0; nt < 4; ++nt)
            bl[nt] = fragr(Bl, wn + nt * 16 + fr, qsw);
        __builtin_amdgcn_s_setprio(1);
#pragma unroll
        for (int nt = 0; nt < 4; ++nt)
#pragma unroll
            for (int mt = 0; mt < 4; ++mt)
                acc[mt][nt] = __builtin_amdgcn_mfma_f32_16x16x32_bf16(ah[mt], bl[nt], acc[mt][nt], 0, 0, 0);
        __builtin_amdgcn_s_setprio(0);

        // ---- ph1b (hl, m-half 1) ----
        __builtin_amdgcn_s_setprio(1);
#pragma unroll
        for (int nt = 0; nt < 4; ++nt)
#pragma unroll
            for (int mt = 4; mt < 8; ++mt)
                acc[mt][nt] = __builtin_amdgcn_mfma_f32_16x16x32_bf16(ah[mt], bl[nt], acc[mt][nt], 0, 0, 0);
        __builtin_amdgcn_s_setprio(0);

        // ---- ph2a (lh, m-half 0) ----
        stage_async(Alg, DIM, m0, k1, smem + nxt + 8192, tid);
        asm volatile("s_waitcnt vmcnt(8)" ::: "memory");
        __builtin_amdgcn_s_barrier();
#pragma unroll
        for (int mt = 0; mt < 4; ++mt)
            al[mt] = fragr(Al, wm + mt * 16 + fr, qsw);
        __builtin_amdgcn_s_setprio(1);
#pragma unroll
        for (int nt = 0; nt < 4; ++nt)
#pragma unroll
            for (int mt = 0; mt < 4; ++mt)
                acc[mt][nt] = __builtin_amdgcn_mfma_f32_16x16x32_bf16(al[mt], bh[nt], acc[mt][nt], 0, 0, 0);
        __builtin_amdgcn_s_setprio(0);

        // ---- ph2b (lh, m-half 1) ----
#pragma unroll
        for (int mt = 4; mt < 8; ++mt)
            al[mt] = fragr(Al, wm + mt * 16 + fr, qsw);
        __builtin_amdgcn_s_setprio(1);
#pragma unroll
        for (int nt = 0; nt < 4; ++nt)
#pragma unroll
            for (int mt = 4; mt < 8; ++mt)
                acc[mt][nt] = __builtin_amdgcn_mfma_f32_16x16x32_bf16(al[mt], bh[nt], acc[mt][nt], 0, 0, 0);
        __builtin_amdgcn_s_setprio(0);
    }

    {   // ---- peeled last K-step (cur = buffer 1): no prefetch ----
        const unsigned short* Ah = smem + 32768;
        const unsigned short* Al = smem + 32768 + 8192;
        const unsigned short* Bh = smem + 32768 + 16384;
        const unsigned short* Bl = smem + 32768 + 24576;

        bf16x8 ah[8], al[8], bh[4], bl[4];

        asm volatile("s_waitcnt vmcnt(4)" ::: "memory");
        __builtin_amdgcn_s_barrier();
#pragma unroll
        for (int mt = 0; mt < 8; ++mt)
            ah[mt] = fragr(Ah, wm + mt * 16 + fr, qsw);
#pragma unroll
        for (int nt = 0; nt < 4; ++nt)
            bh[nt] = fragr(Bh, wn + nt * 16 + fr, qsw);
        __builtin_amdgcn_s_setprio(1);
#pragma unroll
        for (int nt = 0; nt < 4; ++nt)
#pragma unroll
            for (int mt = 0; mt < 8; ++mt)
                acc[mt][nt] = __builtin_amdgcn_mfma_f32_16x16x32_bf16(ah[mt], bh[nt], acc[mt][nt], 0, 0, 0);
        __builtin_amdgcn_s_setprio(0);

        asm volatile("s_waitcnt vmcnt(2)" ::: "memory");
        __builtin_amdgcn_s_barrier();
#pragma unroll
        for (int nt = 0; nt < 4; ++nt)
            bl[nt] = fragr(Bl, wn + nt * 16 + fr, qsw);
        __builtin_amdgcn_s_setprio(1);
#pragma unroll
        for (int nt = 0; nt < 4; ++nt)
#pragma unroll
            for (int mt = 0; mt < 8; ++mt)
                acc[mt][nt] = __builtin_amdgcn_mfma_f32_16x16x32_bf16(ah[mt], bl[nt], acc[mt][nt], 0, 0, 0);
        __builtin_amdgcn_s_setprio(0);

        asm volatile("s_waitcnt vmcnt(0)" ::: "memory");
        __builtin_amdgcn_s_barrier();
#pragma unroll
        for (int mt = 0; mt < 8; ++mt)
            al[mt] = fragr(Al, wm + mt * 16 + fr, qsw);
        __builtin_amdgcn_s_setprio(1);
#pragma unroll
        for (int nt = 0; nt < 4; ++nt)
#pragma unroll
            for (int mt = 0; mt < 8; ++mt)
                acc[mt][nt] = __builtin_amdgcn_mfma_f32_16x16x32_bf16(al[mt], bh[nt], acc[mt][nt], 0, 0, 0);
        __builtin_amdgcn_s_setprio(0);
    }

    const int col = lane & 15, rq = lane >> 4;
    const int wword = (n0 + wn) >> 6;             // one u64 covers nt*16+col
#pragma unroll
    for (int mt = 0; mt < 8; ++mt)
#pragma unroll
        for (int e = 0; e < 4; ++e) {
            const int m = m0 + wm + mt * 16 + rq * 4 + e;
            const unsigned long long word = Mb[(size_t)m * (SEQ / 64) + wword];
#pragma unroll
            for (int nt = 0; nt < 4; ++nt) {
                const int n = n0 + wn + nt * 16 + col;
                const float v = acc[mt][nt][e] * 0.03125f;
                const bool msk = (word >> (nt * 16 + col)) & 1ull;
                Sb[(size_t)m * SEQ + n] = msk ? -INFINITY : v;
            }
        }
}

// ---------------------------------------------------------------------------
// Row softmax on pre-masked, pre-scaled fp32 S; writes bf16 P in place
// (row r -> first 2048 ushorts of the row's 16 KB).
// ---------------------------------------------------------------------------
__global__ __launch_bounds__(256) void softmax_kernel(float* __restrict__ Sc)
{
    const int r = blockIdx.x;          // b*2048 + m
    float* __restrict__ row = Sc + (size_t)r * SEQ;

    const int tid  = threadIdx.x;
    const int lane = tid & 63;
    const int wid  = tid >> 6;

    float x[8];
    float mx = -INFINITY;
#pragma unroll
    for (int j = 0; j < 8; ++j) {
        x[j] = row[tid + j * 256];
        mx = fmaxf(mx, x[j]);
    }
    __shared__ float redm[4];
#pragma unroll
    for (int off = 32; off > 0; off >>= 1)
        mx = fmaxf(mx, __shfl_down(mx, off, 64));
    if (lane == 0) redm[wid] = mx;
    __syncthreads();
    mx = fmaxf(fmaxf(redm[0], redm[1]), fmaxf(redm[2], redm[3]));

    float sum = 0.f;
#pragma unroll
    for (int j = 0; j < 8; ++j) {
        const float e = __expf(x[j] - mx);
        x[j] = e;
        sum += e;
    }
    __shared__ float reds[4];
#pragma unroll
    for (int off = 32; off > 0; off >>= 1)
        sum += __shfl_down(sum, off, 64);
    if (lane == 0) reds[wid] = sum;
    __syncthreads();
    sum = (reds[0] + reds[1]) + (reds[2] + reds[3]);

    const float inv = 1.0f / sum;
    unsigned short* __restrict__ prow = (unsigned short*)row;
#pragma unroll
    for (int j = 0; j < 8; ++j)
        prow[tid + j * 256] = f2b(x[j] * inv);
}

// ---------------------------------------------------------------------------
// O[b] = P[b] @ V[b]: single bf16 MFMA, double-buffered BK=32 with counted
// vmcnt (prefetch next K-step before computing current; vmcnt(4) waits only
// for the previous step's 4 loads). LDS unchanged (32 KB -> 2 blocks/CU).
// A = P rows (stride 4096 ushorts), B = Vt rows (n-major, k contiguous).
// ---------------------------------------------------------------------------
__global__ __launch_bounds__(256) void pv_mfma_kernel(
    const unsigned short* __restrict__ P, const unsigned short* __restrict__ Vt,
    float* __restrict__ O)
{
    __shared__ unsigned short As[2][128 * 32], Bs[2][128 * 32];

    const int tid = threadIdx.x;
    const int w = tid >> 6, lane = tid & 63;
    const int wm = (w >> 1) * 64, wn = (w & 1) * 64;
    const int m0 = blockIdx.y * 128, n0 = blockIdx.x * 128;
    const int b = blockIdx.z;

    const unsigned short* __restrict__ Ag = P + (size_t)b * SEQ * (2 * SEQ);
    const unsigned short* __restrict__ Bg = Vt + (size_t)b * DIM * SEQ;
    float* __restrict__ Ob = O + (size_t)b * SEQ * DIM;

    f32x4 acc[4][4];
#pragma unroll
    for (int i = 0; i < 4; ++i)
#pragma unroll
        for (int j = 0; j < 4; ++j) acc[i][j] = (f32x4){0.f, 0.f, 0.f, 0.f};

    const int fr = lane & 15, quad = lane >> 4;
    const int qsw = quad ^ ((fr >> 2) & 3);

    // prologue: stage K-step 0 into buffer 0
    stage_async(Ag, 2 * SEQ, m0, 0, As[0], tid);
    stage_async(Bg, SEQ,     n0, 0, Bs[0], tid);

    for (int it = 0; it < SEQ / 32 - 1; ++it) {
        const int cur = it & 1, nxt = cur ^ 1;
        const int k1 = it * 32 + 32;

        // prefetch next K-step, then wait only for the previous one
        stage_async(Ag, 2 * SEQ, m0, k1, As[nxt], tid);
        stage_async(Bg, SEQ,     n0, k1, Bs[nxt], tid);
        asm volatile("s_waitcnt vmcnt(4)" ::: "memory");
        __builtin_amdgcn_s_barrier();

        bf16x8 af[4];
#pragma unroll
        for (int mt = 0; mt < 4; ++mt)
            af[mt] = fragr(As[cur], wm + mt * 16 + fr, qsw);
        __builtin_amdgcn_s_setprio(1);
#pragma unroll
        for (int nt = 0; nt < 4; ++nt) {
            const bf16x8 bfg = fragr(Bs[cur], wn + nt * 16 + fr, qsw);
#pragma unroll
            for (int mt = 0; mt < 4; ++mt)
                acc[mt][nt] = __builtin_amdgcn_mfma_f32_16x16x32_bf16(af[mt], bfg, acc[mt][nt], 0, 0, 0);
        }
        __builtin_amdgcn_s_setprio(0);
        __builtin_amdgcn_s_barrier();   // guard cur slot against next prefetch
    }

    {   // peeled last K-step (cur = buffer 1)
        asm volatile("s_waitcnt vmcnt(0)" ::: "memory");
        __builtin_amdgcn_s_barrier();
        bf16x8 af[4];
#pragma unroll
        for (int mt = 0; mt < 4; ++mt)
            af[mt] = fragr(As[1], wm + mt * 16 + fr, qsw);
        __builtin_amdgcn_s_setprio(1);
#pragma unroll
        for (int nt = 0; nt < 4; ++nt) {
            const bf16x8 bfg = fragr(Bs[1], wn + nt * 16 + fr, qsw);
#pragma unroll
            for (int mt = 0; mt < 4; ++mt)
                acc[mt][nt] = __builtin_amdgcn_mfma_f32_16x16x32_bf16(af[mt], bfg, acc[mt][nt], 0, 0, 0);
        }
        __builtin_amdgcn_s_setprio(0);
    }

    const int col = lane & 15, rq = lane >> 4;
#pragma unroll
    for (int mt = 0; mt < 4; ++mt)
#pragma unroll
        for (int nt = 0; nt < 4; ++nt)
#pragma unroll
            for (int e = 0; e < 4; ++e) {
                const int m = m0 + wm + mt * 16 + rq * 4 + e;
                const int n = n0 + wn + nt * 16 + col;
                Ob[(size_t)m * DIM + n] = acc[mt][nt][e];
            }
}

// ---------------------------------------------------------------------------
// Workspace layout (bytes), ws = 167 772 160:
//   Xhi/Xlo/Yhi/Ylo/Vt : 5 x 16 777 216   (bf16 [8192][1024]-sized each)
//   Mthi/Mtlo          : 2 x  2 097 152   (bf16 [1024][1024])
//   Sc                 : 67 108 864       (fp32 [4][2048][2048])
//   Mbits              :    524 288       (u64  [2048][32])       -> 155.7 MB
// Transients aliased INSIDE Sc (consumed before s_gemm writes Sc):
//   Whi/Wlo (2x4.2 MB) + WvT (2.1 MB) + Mtp (4x4.2 MB fp32) = 27.3 MB
// P (bf16) written in place into Sc rows (row r at ushort offset r*4096).
// ---------------------------------------------------------------------------
extern "C" void kernel_launch(void* const* d_in, const int* in_sizes, int n_in,
                              void* d_out, int out_size, void* d_ws, size_t ws_size,
                              hipStream_t stream)
{
    const float* x    = (const float*)d_in[0];
    const int*   mask = (const int*)d_in[1];
    const float* wq   = (const float*)d_in[2];
    const float* wk   = (const float*)d_in[3];
    const float* wv   = (const float*)d_in[4];
    float* out = (float*)d_out;

    const size_t NQ = (size_t)BATCH * SEQ * DIM;     // 8 388 608
    const size_t NM = (size_t)DIM * DIM;             // 1 048 576
    unsigned short* Xhi  = (unsigned short*)d_ws;
    unsigned short* Xlo  = Xhi + NQ;
    unsigned short* Yhi  = Xlo + NQ;
    unsigned short* Ylo  = Yhi + NQ;
    unsigned short* Vt   = Ylo + NQ;
    unsigned short* Mthi = Vt + NQ;
    unsigned short* Mtlo = Mthi + NM;
    float* Sc = (float*)(Mtlo + NM);
    unsigned long long* Mb = (unsigned long long*)(Sc + (size_t)BATCH * SEQ * SEQ);

    unsigned short* Whi = (unsigned short*)Sc;       // transient aliases
    unsigned short* Wlo = Whi + 2 * NM;
    unsigned short* WvT = Wlo + 2 * NM;
    float* Mtp = (float*)(WvT + NM);

    // one-time: allow 128 KiB dynamic LDS for the 256^2 S-gemm
    static bool lds_attr_set = false;
    if (!lds_attr_set) {
        (void)hipFuncSetAttribute((const void*)s_gemm256_kernel,
                                  hipFuncAttributeMaxDynamicSharedMemorySize,
                                  131072);
        lds_attr_set = true;
    }

    // 1. X -> hi/lo bf16; mask -> bitmask
    convert_x_kernel<<<dim3(NQ / 4 / 256), 256, 0, stream>>>(x, Xhi, Xlo);
    mask_pack_kernel<<<dim3(SEQ), 256, 0, stream>>>(mask, Mb);
    // 2. Wq/Wk -> hi/lo bf16 (no transpose); Wv -> WvT hi bf16
    convert_wqk_kernel<<<dim3(NM / 4 / 256, 2), 256, 0, stream>>>(wq, wk, Whi, Wlo);
    convert_wv_kernel<<<dim3(32, 32), 256, 0, stream>>>(wv, WvT);
    // 3. Mt = Wk.Wq^T (K-split x4, fp32 partials), then reduce + hi/lo split
    m_gemm_kernel<<<dim3(8, 8, 4), 256, 0, stream>>>(Whi, Wlo, Mtp);
    m_reduce_kernel<<<dim3(NM / 4 / 256), 256, 0, stream>>>(Mtp, Mthi, Mtlo);
    // 4. z=0: Y = X.Mt^T (hi/lo out); z=1: V = X.WvT^T written as Vt[b][d][s]
    yv_gemm_kernel<<<dim3(DIM / 128, (BATCH * SEQ) / 128, 2), 256, 0, stream>>>(
        Xhi, Xlo, Mthi, Mtlo, WvT, Yhi, Ylo, Vt);
    // 5. S = masked, scaled Y.X^T per batch (fp32 scores), 256^2 6-phase
    s_gemm256_kernel<<<dim3(SEQ / 256, SEQ / 256, BATCH), 512, 131072, stream>>>(
        Yhi, Ylo, Xhi, Xlo, Mb, Sc);
    // 6. softmax; writes bf16 P in place
    softmax_kernel<<<dim3(BATCH * SEQ), 256, 0, stream>>>(Sc);
    // 7. O = P @ V (double-buffered, counted vmcnt)
    pv_mfma_kernel<<<dim3(DIM / 128, SEQ / 128, BATCH), 256, 0, stream>>>(
        (const unsigned short*)Sc, Vt, out);
}

// Round 4
// 390.887 us; speedup vs baseline: 1.0011x; 1.0011x over previous
//
#include <hip/hip_runtime.h>
#include <math.h>

static constexpr int BATCH = 4;
static constexpr int SEQ   = 2048;
static constexpr int DIM   = 1024;

typedef __attribute__((ext_vector_type(8))) short     bf16x8;  // MFMA A/B frag (4 VGPRs)
typedef __attribute__((ext_vector_type(4))) float     f32x4;   // MFMA C/D frag

// fp32 -> bf16 (RNE) and back, bit-exact helpers for hi/lo splitting
__device__ __forceinline__ unsigned short f2b(float v) {
    unsigned int u = __float_as_uint(v);
    u = u + 0x7fffu + ((u >> 16) & 1u);
    return (unsigned short)(u >> 16);
}
__device__ __forceinline__ float b2f(unsigned short h) {
    return __uint_as_float(((unsigned int)h) << 16);
}

// ---------------------------------------------------------------------------
// convert_x: fp32 -> (hi, lo) bf16, elementwise.
// ---------------------------------------------------------------------------
__global__ __launch_bounds__(256) void convert_x_kernel(
    const float* __restrict__ X, unsigned short* __restrict__ hi,
    unsigned short* __restrict__ lo)
{
    const int i = blockIdx.x * 256 + threadIdx.x;   // float4 index
    const float4 v = ((const float4*)X)[i];
    ushort4 h, l;
    h.x = f2b(v.x); l.x = f2b(v.x - b2f(h.x));
    h.y = f2b(v.y); l.y = f2b(v.y - b2f(h.y));
    h.z = f2b(v.z); l.z = f2b(v.z - b2f(h.z));
    h.w = f2b(v.w); l.w = f2b(v.w - b2f(h.w));
    ((ushort4*)hi)[i] = h;
    ((ushort4*)lo)[i] = l;
}

// ---------------------------------------------------------------------------
// convert_wqk: Wq (y=0) / Wk (y=1) fp32 -> hi/lo bf16, NO transpose.
// ---------------------------------------------------------------------------
__global__ __launch_bounds__(256) void convert_wqk_kernel(
    const float* __restrict__ Wq, const float* __restrict__ Wk,
    unsigned short* __restrict__ hi, unsigned short* __restrict__ lo)
{
    const int z = blockIdx.y;
    const float* __restrict__ W = z ? Wk : Wq;
    const int i = blockIdx.x * 256 + threadIdx.x;   // float4 index within matrix
    const int o = z * (DIM * DIM / 4) + i;
    const float4 v = ((const float4*)W)[i];
    ushort4 h, l;
    h.x = f2b(v.x); l.x = f2b(v.x - b2f(h.x));
    h.y = f2b(v.y); l.y = f2b(v.y - b2f(h.y));
    h.z = f2b(v.z); l.z = f2b(v.z - b2f(h.z));
    h.w = f2b(v.w); l.w = f2b(v.w - b2f(h.w));
    ((ushort4*)hi)[o] = h;
    ((ushort4*)lo)[o] = l;
}

// ---------------------------------------------------------------------------
// convert_wv: Wv[k][n] fp32 -> WvT[n][k] hi bf16 (V is single-term).
// ---------------------------------------------------------------------------
__global__ __launch_bounds__(256) void convert_wv_kernel(
    const float* __restrict__ W, unsigned short* __restrict__ WT)
{
    __shared__ float t[32][33];
    const int n0 = blockIdx.x * 32, k0 = blockIdx.y * 32;
    const int tx = threadIdx.x & 31, ty = threadIdx.x >> 5;  // ty: 0..7
#pragma unroll
    for (int i = 0; i < 4; ++i)
        t[ty + i * 8][tx] = W[(size_t)(k0 + ty + i * 8) * DIM + (n0 + tx)];
    __syncthreads();
#pragma unroll
    for (int i = 0; i < 4; ++i)
        WT[(size_t)(n0 + ty + i * 8) * DIM + (k0 + tx)] = f2b(t[tx][ty + i * 8]);
}

// ---------------------------------------------------------------------------
// mask_pack: int32 mask [2048][2048] -> bitmask [2048][32] u64 (bit=1: mask).
// ---------------------------------------------------------------------------
__global__ __launch_bounds__(256) void mask_pack_kernel(
    const int* __restrict__ mask, unsigned long long* __restrict__ Mb)
{
    const int row  = blockIdx.x;
    const int lane = threadIdx.x & 63, w = threadIdx.x >> 6;
#pragma unroll
    for (int c = w; c < SEQ / 64; c += 4) {
        const int v = mask[(size_t)row * SEQ + c * 64 + lane];
        const unsigned long long bits = __ballot(v != 0);
        if (lane == 0) Mb[(size_t)row * (SEQ / 64) + c] = bits;
    }
}

// ---------------------------------------------------------------------------
// Async staging of a (rows x 32)-elem bf16 tile via global_load_lds w=16.
// XOR-swizzled unpadded 64 B rows; wave-uniform LDS dest. Works for any
// block size that is a multiple of 64 (each wave stages 32 rows).
// ---------------------------------------------------------------------------
__device__ __forceinline__ void stage_async(
    const unsigned short* __restrict__ g, int gstride, int row0, int k0,
    unsigned short* lds, int tid)
{
    const int w = tid >> 6, lane = tid & 63;
    const int c = (lane & 3) ^ ((lane >> 4) & 3);   // global chunk this lane fetches
#pragma unroll
    for (int h = 0; h < 2; ++h) {
        const int row = 32 * w + 16 * h + (lane >> 2);
        const unsigned short* src = g + (size_t)(row0 + row) * gstride + k0 + 8 * c;
        unsigned short* dst = lds + (32 * w + 16 * h) * 32;   // wave-uniform
        __builtin_amdgcn_global_load_lds(
            (const __attribute__((address_space(1))) void*)src,
            (__attribute__((address_space(3))) void*)dst, 16, 0, 0);
    }
}

__device__ __forceinline__ bf16x8 fragr(const unsigned short* lds, int row, int qsw)
{
    return *(const bf16x8*)(lds + row * 32 + qsw * 8);
}

// ---------------------------------------------------------------------------
// m_gemm: Mt = Wk . Wq^T  (so Mt[j][i] = sum_o Wq[i][o] Wk[j][o]), 3-term
// split bf16, 128x128 tile, K-split over z (4 chunks of 256). fp32 partials.
// ---------------------------------------------------------------------------
__global__ __launch_bounds__(256) void m_gemm_kernel(
    const unsigned short* __restrict__ Whi, const unsigned short* __restrict__ Wlo,
    float* __restrict__ Mtp)
{
    __shared__ unsigned short Ah[128 * 32], Al[128 * 32];
    __shared__ unsigned short Bh[128 * 32], Bl[128 * 32];

    const int tid = threadIdx.x;
    const int w = tid >> 6, lane = tid & 63;
    const int wm = (w >> 1) * 64, wn = (w & 1) * 64;
    const int m0 = blockIdx.y * 128, n0 = blockIdx.x * 128;
    const int z = blockIdx.z;                        // K chunk

    const unsigned short* __restrict__ Ahg = Whi + (size_t)DIM * DIM;  // Wk hi
    const unsigned short* __restrict__ Alg = Wlo + (size_t)DIM * DIM;  // Wk lo
    const unsigned short* __restrict__ Bhg = Whi;                      // Wq hi
    const unsigned short* __restrict__ Blg = Wlo;                      // Wq lo
    float* __restrict__ Cp = Mtp + (size_t)z * DIM * DIM;

    f32x4 acc[4][4];
#pragma unroll
    for (int i = 0; i < 4; ++i)
#pragma unroll
        for (int j = 0; j < 4; ++j) acc[i][j] = (f32x4){0.f, 0.f, 0.f, 0.f};

    const int fr = lane & 15, quad = lane >> 4;
    const int qsw = quad ^ ((fr >> 2) & 3);

    for (int k0 = z * 256; k0 < z * 256 + 256; k0 += 32) {
        stage_async(Ahg, DIM, m0, k0, Ah, tid);
        stage_async(Alg, DIM, m0, k0, Al, tid);
        stage_async(Bhg, DIM, n0, k0, Bh, tid);
        stage_async(Blg, DIM, n0, k0, Bl, tid);
        __syncthreads();

        bf16x8 ah[4], al[4];
#pragma unroll
        for (int mt = 0; mt < 4; ++mt) {
            ah[mt] = fragr(Ah, wm + mt * 16 + fr, qsw);
            al[mt] = fragr(Al, wm + mt * 16 + fr, qsw);
        }
#pragma unroll
        for (int nt = 0; nt < 4; ++nt) {
            const bf16x8 bh = fragr(Bh, wn + nt * 16 + fr, qsw);
            const bf16x8 bl = fragr(Bl, wn + nt * 16 + fr, qsw);
#pragma unroll
            for (int mt = 0; mt < 4; ++mt) {
                acc[mt][nt] = __builtin_amdgcn_mfma_f32_16x16x32_bf16(ah[mt], bh, acc[mt][nt], 0, 0, 0);
                acc[mt][nt] = __builtin_amdgcn_mfma_f32_16x16x32_bf16(ah[mt], bl, acc[mt][nt], 0, 0, 0);
                acc[mt][nt] = __builtin_amdgcn_mfma_f32_16x16x32_bf16(al[mt], bh, acc[mt][nt], 0, 0, 0);
            }
        }
        __syncthreads();
    }

    const int col = lane & 15, rq = lane >> 4;
#pragma unroll
    for (int mt = 0; mt < 4; ++mt)
#pragma unroll
        for (int nt = 0; nt < 4; ++nt)
#pragma unroll
            for (int e = 0; e < 4; ++e) {
                const int m = m0 + wm + mt * 16 + rq * 4 + e;
                const int n = n0 + wn + nt * 16 + col;
                Cp[(size_t)m * DIM + n] = acc[mt][nt][e];
            }
}

// ---------------------------------------------------------------------------
// m_reduce: sum 4 K-split partials, split to hi/lo bf16.
// ---------------------------------------------------------------------------
__global__ __launch_bounds__(256) void m_reduce_kernel(
    const float* __restrict__ Mtp, unsigned short* __restrict__ Mthi,
    unsigned short* __restrict__ Mtlo)
{
    const int i = blockIdx.x * 256 + threadIdx.x;   // float4 index
    const size_t q = (size_t)DIM * DIM / 4;
    const float4 a = ((const float4*)Mtp)[i];
    const float4 b = ((const float4*)Mtp)[i + q];
    const float4 c = ((const float4*)Mtp)[i + 2 * q];
    const float4 d = ((const float4*)Mtp)[i + 3 * q];
    const float4 v = make_float4(a.x + b.x + c.x + d.x, a.y + b.y + c.y + d.y,
                                 a.z + b.z + c.z + d.z, a.w + b.w + c.w + d.w);
    ushort4 h, l;
    h.x = f2b(v.x); l.x = f2b(v.x - b2f(h.x));
    h.y = f2b(v.y); l.y = f2b(v.y - b2f(h.y));
    h.z = f2b(v.z); l.z = f2b(v.z - b2f(h.z));
    h.w = f2b(v.w); l.w = f2b(v.w - b2f(h.w));
    ((ushort4*)Mthi)[i] = h;
    ((ushort4*)Mtlo)[i] = l;
}

// ---------------------------------------------------------------------------
// yv_gemm: z=0 -> Y = X @ Mt^T (3-term, hi/lo out, [8192][1024])
//          z=1 -> V = X @ WvT^T (1-term), written TRANSPOSED as Vt[b][d][s]
// XCD-aware bijective block swizzle (T1): the 8 x-blocks sharing an A-panel
// run on the SAME XCD -> A-panel fetched once per XCD L2, not 8x from HBM.
// grid (8,64,2) = 1024 blocks, q=128.
// ---------------------------------------------------------------------------
__global__ __launch_bounds__(256) void yv_gemm_kernel(
    const unsigned short* __restrict__ Xhi, const unsigned short* __restrict__ Xlo,
    const unsigned short* __restrict__ Mthi, const unsigned short* __restrict__ Mtlo,
    const unsigned short* __restrict__ WvT,
    unsigned short* __restrict__ Yhi, unsigned short* __restrict__ Ylo,
    unsigned short* __restrict__ Vt)
{
    __shared__ unsigned short Ah[128 * 32], Al[128 * 32];
    __shared__ unsigned short Bh[128 * 32], Bl[128 * 32];

    const int tid = threadIdx.x;
    const int w = tid >> 6, lane = tid & 63;
    const int wm = (w >> 1) * 64, wn = (w & 1) * 64;

    const int flat = blockIdx.x + (blockIdx.y << 3) + (blockIdx.z << 9);
    const int lid  = ((flat & 7) << 7) | (flat >> 3);     // bijective, nwg=1024
    const int m0 = ((lid >> 3) & 63) * 128, n0 = (lid & 7) * 128;
    const int z = lid >> 9;
    const bool full = (z == 0);

    const unsigned short* __restrict__ Bhg = full ? Mthi : WvT;
    const unsigned short* __restrict__ Blg = Mtlo;

    f32x4 acc[4][4];
#pragma unroll
    for (int i = 0; i < 4; ++i)
#pragma unroll
        for (int j = 0; j < 4; ++j) acc[i][j] = (f32x4){0.f, 0.f, 0.f, 0.f};

    const int fr = lane & 15, quad = lane >> 4;
    const int qsw = quad ^ ((fr >> 2) & 3);

    for (int k0 = 0; k0 < DIM; k0 += 32) {
        stage_async(Xhi, DIM, m0, k0, Ah, tid);
        stage_async(Bhg, DIM, n0, k0, Bh, tid);
        if (full) {
            stage_async(Xlo, DIM, m0, k0, Al, tid);
            stage_async(Blg, DIM, n0, k0, Bl, tid);
        }
        __syncthreads();

        bf16x8 ah[4], al[4];
#pragma unroll
        for (int mt = 0; mt < 4; ++mt)
            ah[mt] = fragr(Ah, wm + mt * 16 + fr, qsw);
        if (full) {
#pragma unroll
            for (int mt = 0; mt < 4; ++mt)
                al[mt] = fragr(Al, wm + mt * 16 + fr, qsw);
        }
#pragma unroll
        for (int nt = 0; nt < 4; ++nt) {
            const bf16x8 bh = fragr(Bh, wn + nt * 16 + fr, qsw);
#pragma unroll
            for (int mt = 0; mt < 4; ++mt)
                acc[mt][nt] = __builtin_amdgcn_mfma_f32_16x16x32_bf16(ah[mt], bh, acc[mt][nt], 0, 0, 0);
            if (full) {
                const bf16x8 bl = fragr(Bl, wn + nt * 16 + fr, qsw);
#pragma unroll
                for (int mt = 0; mt < 4; ++mt) {
                    acc[mt][nt] = __builtin_amdgcn_mfma_f32_16x16x32_bf16(ah[mt], bl, acc[mt][nt], 0, 0, 0);
                    acc[mt][nt] = __builtin_amdgcn_mfma_f32_16x16x32_bf16(al[mt], bh, acc[mt][nt], 0, 0, 0);
                }
            }
        }
        __syncthreads();
    }

    const int col = lane & 15, rq = lane >> 4;
    if (full) {
#pragma unroll
        for (int mt = 0; mt < 4; ++mt)
#pragma unroll
            for (int nt = 0; nt < 4; ++nt)
#pragma unroll
                for (int e = 0; e < 4; ++e) {
                    const int m = m0 + wm + mt * 16 + rq * 4 + e;
                    const int n = n0 + wn + nt * 16 + col;
                    const float v = acc[mt][nt][e];
                    const unsigned short h = f2b(v);
                    Yhi[(size_t)m * DIM + n] = h;
                    Ylo[(size_t)m * DIM + n] = f2b(v - b2f(h));
                }
    } else {
        // V: write transposed, Vt[b][n][s], 4 consecutive s per ushort4
#pragma unroll
        for (int mt = 0; mt < 4; ++mt)
#pragma unroll
            for (int nt = 0; nt < 4; ++nt) {
                const int m = m0 + wm + mt * 16 + rq * 4;      // 4-aligned
                const int bb = m >> 11, s = m & (SEQ - 1);
                const int n = n0 + wn + nt * 16 + col;
                ushort4 pk;
                pk.x = f2b(acc[mt][nt][0]);
                pk.y = f2b(acc[mt][nt][1]);
                pk.z = f2b(acc[mt][nt][2]);
                pk.w = f2b(acc[mt][nt][3]);
                *(ushort4*)(Vt + (size_t)bb * DIM * SEQ + (size_t)n * SEQ + s) = pk;
            }
    }
}

// ---------------------------------------------------------------------------
// s_gemm256: S[b] = (Y[b] . X[b]^T) * 1/32, masked to -inf. fp32 output.
// 256x256 tile, BK=32, 512 threads (8 waves, 2Mx4N, 128x64 per wave).
// 6-PHASE term schedule, 16-MFMA clusters, counted vmcnt (T3+T4+T5).
// XCD-aware bijective block swizzle (T1): grid (8,8,4) = 256 blocks, q=32.
// ---------------------------------------------------------------------------
__global__ __launch_bounds__(512, 2) void s_gemm256_kernel(
    const unsigned short* __restrict__ Yhi, const unsigned short* __restrict__ Ylo,
    const unsigned short* __restrict__ Xhi, const unsigned short* __restrict__ Xlo,
    const unsigned long long* __restrict__ Mb, float* __restrict__ Sc)
{
    extern __shared__ unsigned short smem[];
    // layout (ushort offsets): buffer c at c*32768:
    //   Ah = +0, Al = +8192, Bh = +16384, Bl = +24576   (each 256x32)

    const int tid = threadIdx.x;
    const int w = tid >> 6, lane = tid & 63;
    const int wm = (w >> 2) * 128, wn = (w & 3) * 64;

    const int flat = blockIdx.x + (blockIdx.y << 3) + (blockIdx.z << 6);
    const int lid  = ((flat & 7) << 5) | (flat >> 3);     // bijective, nwg=256
    const int m0 = ((lid >> 3) & 7) * 256, n0 = (lid & 7) * 256;
    const int b  = lid >> 6;

    const unsigned short* __restrict__ Ahg = Yhi + (size_t)b * SEQ * DIM;
    const unsigned short* __restrict__ Alg = Ylo + (size_t)b * SEQ * DIM;
    const unsigned short* __restrict__ Bhg = Xhi + (size_t)b * SEQ * DIM;
    const unsigned short* __restrict__ Blg = Xlo + (size_t)b * SEQ * DIM;
    float* __restrict__ Sb = Sc + (size_t)b * SEQ * SEQ;

    f32x4 acc[8][4];
#pragma unroll
    for (int i = 0; i < 8; ++i)
#pragma unroll
        for (int j = 0; j < 4; ++j) acc[i][j] = (f32x4){0.f, 0.f, 0.f, 0.f};

    const int fr = lane & 15, quad = lane >> 4;
    const int qsw = quad ^ ((fr >> 2) & 3);

    // prologue: issue K-step 0 into buffer 0 in phase-consumption order.
    stage_async(Ahg, DIM, m0, 0, smem + 0,     tid);
    stage_async(Bhg, DIM, n0, 0, smem + 16384, tid);
    stage_async(Blg, DIM, n0, 0, smem + 24576, tid);
    stage_async(Alg, DIM, m0, 0, smem + 8192,  tid);

    for (int it = 0; it < DIM / 32 - 1; ++it) {
        const int cur = (it & 1) * 32768;
        const int nxt = cur ^ 32768;
        const unsigned short* Ah = smem + cur;
        const unsigned short* Al = smem + cur + 8192;
        const unsigned short* Bh = smem + cur + 16384;
        const unsigned short* Bl = smem + cur + 24576;
        const int k1 = it * 32 + 32;

        bf16x8 ah[8], al[8], bh[4], bl[4];

        // ---- ph0a (hh, m-half 0) ----
        stage_async(Ahg, DIM, m0, k1, smem + nxt, tid);
        asm volatile("s_waitcnt vmcnt(6)" ::: "memory");
        __builtin_amdgcn_s_barrier();
#pragma unroll
        for (int mt = 0; mt < 4; ++mt)
            ah[mt] = fragr(Ah, wm + mt * 16 + fr, qsw);
#pragma unroll
        for (int nt = 0; nt < 4; ++nt)
            bh[nt] = fragr(Bh, wn + nt * 16 + fr, qsw);
        __builtin_amdgcn_s_setprio(1);
#pragma unroll
        for (int nt = 0; nt < 4; ++nt)
#pragma unroll
            for (int mt = 0; mt < 4; ++mt)
                acc[mt][nt] = __builtin_amdgcn_mfma_f32_16x16x32_bf16(ah[mt], bh[nt], acc[mt][nt], 0, 0, 0);
        __builtin_amdgcn_s_setprio(0);

        // ---- ph0b (hh, m-half 1) ----
        stage_async(Bhg, DIM, n0, k1, smem + nxt + 16384, tid);
#pragma unroll
        for (int mt = 4; mt < 8; ++mt)
            ah[mt] = fragr(Ah, wm + mt * 16 + fr, qsw);
        __builtin_amdgcn_s_setprio(1);
#pragma unroll
        for (int nt = 0; nt < 4; ++nt)
#pragma unroll
            for (int mt = 4; mt < 8; ++mt)
                acc[mt][nt] = __builtin_amdgcn_mfma_f32_16x16x32_bf16(ah[mt], bh[nt], acc[mt][nt], 0, 0, 0);
        __builtin_amdgcn_s_setprio(0);

        // ---- ph1a (hl, m-half 0) ----
        stage_async(Blg, DIM, n0, k1, smem + nxt + 24576, tid);
        asm volatile("s_waitcnt vmcnt(8)" ::: "memory");
        __builtin_amdgcn_s_barrier();
#pragma unroll
        for (int nt = 0; nt < 4; ++nt)
            bl[nt] = fragr(Bl, wn + nt * 16 + fr, qsw);
        __builtin_amdgcn_s_setprio(1);
#pragma unroll
        for (int nt = 0; nt < 4; ++nt)
#pragma unroll
            for (int mt = 0; mt < 4; ++mt)
                acc[mt][nt] = __builtin_amdgcn_mfma_f32_16x16x32_bf16(ah[mt], bl[nt], acc[mt][nt], 0, 0, 0);
        __builtin_amdgcn_s_setprio(0);

        // ---- ph1b (hl, m-half 1) ----
        __builtin_amdgcn_s_setprio(1);
#pragma unroll
        for (int nt = 0; nt < 4; ++nt)
#pragma unroll
            for (int mt = 4; mt < 8; ++mt)
                acc[mt][nt] = __builtin_amdgcn_mfma_f32_16x16x32_bf16(ah[mt], bl[nt], acc[mt][nt], 0, 0, 0);
        __builtin_amdgcn_s_setprio(0);

        // ---- ph2a (lh, m-half 0) ----
        stage_async(Alg, DIM, m0, k1, smem + nxt + 8192, tid);
        asm volatile("s_waitcnt vmcnt(8)" ::: "memory");
        __builtin_amdgcn_s_barrier();
#pragma unroll
        for (int mt = 0; mt < 4; ++mt)
            al[mt] = fragr(Al, wm + mt * 16 + fr, qsw);
        __builtin_amdgcn_s_setprio(1);
#pragma unroll
        for (int nt = 0; nt < 4; ++nt)
#pragma unroll
            for (int mt = 0; mt < 4; ++mt)
                acc[mt][nt] = __builtin_amdgcn_mfma_f32_16x16x32_bf16(al[mt], bh[nt], acc[mt][nt], 0, 0, 0);
        __builtin_amdgcn_s_setprio(0);

        // ---- ph2b (lh, m-half 1) ----
#pragma unroll
        for (int mt = 4; mt < 8; ++mt)
            al[mt] = fragr(Al, wm + mt * 16 + fr, qsw);
        __builtin_amdgcn_s_setprio(1);
#pragma unroll
        for (int nt = 0; nt < 4; ++nt)
#pragma unroll
            for (int mt = 4; mt < 8; ++mt)
                acc[mt][nt] = __builtin_amdgcn_mfma_f32_16x16x32_bf16(al[mt], bh[nt], acc[mt][nt], 0, 0, 0);
        __builtin_amdgcn_s_setprio(0);
    }

    {   // ---- peeled last K-step (cur = buffer 1): no prefetch ----
        const unsigned short* Ah = smem + 32768;
        const unsigned short* Al = smem + 32768 + 8192;
        const unsigned short* Bh = smem + 32768 + 16384;
        const unsigned short* Bl = smem + 32768 + 24576;

        bf16x8 ah[8], al[8], bh[4], bl[4];

        asm volatile("s_waitcnt vmcnt(4)" ::: "memory");
        __builtin_amdgcn_s_barrier();
#pragma unroll
        for (int mt = 0; mt < 8; ++mt)
            ah[mt] = fragr(Ah, wm + mt * 16 + fr, qsw);
#pragma unroll
        for (int nt = 0; nt < 4; ++nt)
            bh[nt] = fragr(Bh, wn + nt * 16 + fr, qsw);
        __builtin_amdgcn_s_setprio(1);
#pragma unroll
        for (int nt = 0; nt < 4; ++nt)
#pragma unroll
            for (int mt = 0; mt < 8; ++mt)
                acc[mt][nt] = __builtin_amdgcn_mfma_f32_16x16x32_bf16(ah[mt], bh[nt], acc[mt][nt], 0, 0, 0);
        __builtin_amdgcn_s_setprio(0);

        asm volatile("s_waitcnt vmcnt(2)" ::: "memory");
        __builtin_amdgcn_s_barrier();
#pragma unroll
        for (int nt = 0; nt < 4; ++nt)
            bl[nt] = fragr(Bl, wn + nt * 16 + fr, qsw);
        __builtin_amdgcn_s_setprio(1);
#pragma unroll
        for (int nt = 0; nt < 4; ++nt)
#pragma unroll
            for (int mt = 0; mt < 8; ++mt)
                acc[mt][nt] = __builtin_amdgcn_mfma_f32_16x16x32_bf16(ah[mt], bl[nt], acc[mt][nt], 0, 0, 0);
        __builtin_amdgcn_s_setprio(0);

        asm volatile("s_waitcnt vmcnt(0)" ::: "memory");
        __builtin_amdgcn_s_barrier();
#pragma unroll
        for (int mt = 0; mt < 8; ++mt)
            al[mt] = fragr(Al, wm + mt * 16 + fr, qsw);
        __builtin_amdgcn_s_setprio(1);
#pragma unroll
        for (int nt = 0; nt < 4; ++nt)
#pragma unroll
            for (int mt = 0; mt < 8; ++mt)
                acc[mt][nt] = __builtin_amdgcn_mfma_f32_16x16x32_bf16(al[mt], bh[nt], acc[mt][nt], 0, 0, 0);
        __builtin_amdgcn_s_setprio(0);
    }

    const int col = lane & 15, rq = lane >> 4;
    const int wword = (n0 + wn) >> 6;             // one u64 covers nt*16+col
#pragma unroll
    for (int mt = 0; mt < 8; ++mt)
#pragma unroll
        for (int e = 0; e < 4; ++e) {
            const int m = m0 + wm + mt * 16 + rq * 4 + e;
            const unsigned long long word = Mb[(size_t)m * (SEQ / 64) + wword];
#pragma unroll
            for (int nt = 0; nt < 4; ++nt) {
                const int n = n0 + wn + nt * 16 + col;
                const float v = acc[mt][nt][e] * 0.03125f;
                const bool msk = (word >> (nt * 16 + col)) & 1ull;
                Sb[(size_t)m * SEQ + n] = msk ? -INFINITY : v;
            }
        }
}

// ---------------------------------------------------------------------------
// Row softmax on pre-masked, pre-scaled fp32 S; writes bf16 P in place
// (row r -> first 2048 ushorts of the row's 16 KB).
// ---------------------------------------------------------------------------
__global__ __launch_bounds__(256) void softmax_kernel(float* __restrict__ Sc)
{
    const int r = blockIdx.x;          // b*2048 + m
    float* __restrict__ row = Sc + (size_t)r * SEQ;

    const int tid  = threadIdx.x;
    const int lane = tid & 63;
    const int wid  = tid >> 6;

    float x[8];
    float mx = -INFINITY;
#pragma unroll
    for (int j = 0; j < 8; ++j) {
        x[j] = row[tid + j * 256];
        mx = fmaxf(mx, x[j]);
    }
    __shared__ float redm[4];
#pragma unroll
    for (int off = 32; off > 0; off >>= 1)
        mx = fmaxf(mx, __shfl_down(mx, off, 64));
    if (lane == 0) redm[wid] = mx;
    __syncthreads();
    mx = fmaxf(fmaxf(redm[0], redm[1]), fmaxf(redm[2], redm[3]));

    float sum = 0.f;
#pragma unroll
    for (int j = 0; j < 8; ++j) {
        const float e = __expf(x[j] - mx);
        x[j] = e;
        sum += e;
    }
    __shared__ float reds[4];
#pragma unroll
    for (int off = 32; off > 0; off >>= 1)
        sum += __shfl_down(sum, off, 64);
    if (lane == 0) reds[wid] = sum;
    __syncthreads();
    sum = (reds[0] + reds[1]) + (reds[2] + reds[3]);

    const float inv = 1.0f / sum;
    unsigned short* __restrict__ prow = (unsigned short*)row;
#pragma unroll
    for (int j = 0; j < 8; ++j)
        prow[tid + j * 256] = f2b(x[j] * inv);
}

// ---------------------------------------------------------------------------
// O[b] = P[b] @ V[b]: single bf16 MFMA, double-buffered BK=32 with counted
// vmcnt. XCD-aware bijective block swizzle (T1): grid (8,16,4)=512, q=64.
// A = P rows (stride 4096 ushorts), B = Vt rows (n-major, k contiguous).
// ---------------------------------------------------------------------------
__global__ __launch_bounds__(256) void pv_mfma_kernel(
    const unsigned short* __restrict__ P, const unsigned short* __restrict__ Vt,
    float* __restrict__ O)
{
    __shared__ unsigned short As[2][128 * 32], Bs[2][128 * 32];

    const int tid = threadIdx.x;
    const int w = tid >> 6, lane = tid & 63;
    const int wm = (w >> 1) * 64, wn = (w & 1) * 64;

    const int flat = blockIdx.x + (blockIdx.y << 3) + (blockIdx.z << 7);
    const int lid  = ((flat & 7) << 6) | (flat >> 3);     // bijective, nwg=512
    const int m0 = ((lid >> 3) & 15) * 128, n0 = (lid & 7) * 128;
    const int b  = lid >> 7;

    const unsigned short* __restrict__ Ag = P + (size_t)b * SEQ * (2 * SEQ);
    const unsigned short* __restrict__ Bg = Vt + (size_t)b * DIM * SEQ;
    float* __restrict__ Ob = O + (size_t)b * SEQ * DIM;

    f32x4 acc[4][4];
#pragma unroll
    for (int i = 0; i < 4; ++i)
#pragma unroll
        for (int j = 0; j < 4; ++j) acc[i][j] = (f32x4){0.f, 0.f, 0.f, 0.f};

    const int fr = lane & 15, quad = lane >> 4;
    const int qsw = quad ^ ((fr >> 2) & 3);

    // prologue: stage K-step 0 into buffer 0
    stage_async(Ag, 2 * SEQ, m0, 0, As[0], tid);
    stage_async(Bg, SEQ,     n0, 0, Bs[0], tid);

    for (int it = 0; it < SEQ / 32 - 1; ++it) {
        const int cur = it & 1, nxt = cur ^ 1;
        const int k1 = it * 32 + 32;

        // prefetch next K-step, then wait only for the previous one
        stage_async(Ag, 2 * SEQ, m0, k1, As[nxt], tid);
        stage_async(Bg, SEQ,     n0, k1, Bs[nxt], tid);
        asm volatile("s_waitcnt vmcnt(4)" ::: "memory");
        __builtin_amdgcn_s_barrier();

        bf16x8 af[4];
#pragma unroll
        for (int mt = 0; mt < 4; ++mt)
            af[mt] = fragr(As[cur], wm + mt * 16 + fr, qsw);
        __builtin_amdgcn_s_setprio(1);
#pragma unroll
        for (int nt = 0; nt < 4; ++nt) {
            const bf16x8 bfg = fragr(Bs[cur], wn + nt * 16 + fr, qsw);
#pragma unroll
            for (int mt = 0; mt < 4; ++mt)
                acc[mt][nt] = __builtin_amdgcn_mfma_f32_16x16x32_bf16(af[mt], bfg, acc[mt][nt], 0, 0, 0);
        }
        __builtin_amdgcn_s_setprio(0);
        __builtin_amdgcn_s_barrier();   // guard cur slot against next prefetch
    }

    {   // peeled last K-step (cur = buffer 1)
        asm volatile("s_waitcnt vmcnt(0)" ::: "memory");
        __builtin_amdgcn_s_barrier();
        bf16x8 af[4];
#pragma unroll
        for (int mt = 0; mt < 4; ++mt)
            af[mt] = fragr(As[1], wm + mt * 16 + fr, qsw);
        __builtin_amdgcn_s_setprio(1);
#pragma unroll
        for (int nt = 0; nt < 4; ++nt) {
            const bf16x8 bfg = fragr(Bs[1], wn + nt * 16 + fr, qsw);
#pragma unroll
            for (int mt = 0; mt < 4; ++mt)
                acc[mt][nt] = __builtin_amdgcn_mfma_f32_16x16x32_bf16(af[mt], bfg, acc[mt][nt], 0, 0, 0);
        }
        __builtin_amdgcn_s_setprio(0);
    }

    const int col = lane & 15, rq = lane >> 4;
#pragma unroll
    for (int mt = 0; mt < 4; ++mt)
#pragma unroll
        for (int nt = 0; nt < 4; ++nt)
#pragma unroll
            for (int e = 0; e < 4; ++e) {
                const int m = m0 + wm + mt * 16 + rq * 4 + e;
                const int n = n0 + wn + nt * 16 + col;
                Ob[(size_t)m * DIM + n] = acc[mt][nt][e];
            }
}

// ---------------------------------------------------------------------------
// Workspace layout (bytes), ws = 167 772 160:
//   Xhi/Xlo/Yhi/Ylo/Vt : 5 x 16 777 216   (bf16 [8192][1024]-sized each)
//   Mthi/Mtlo          : 2 x  2 097 152   (bf16 [1024][1024])
//   Sc                 : 67 108 864       (fp32 [4][2048][2048])
//   Mbits              :    524 288       (u64  [2048][32])       -> 155.7 MB
// Transients aliased INSIDE Sc (consumed before s_gemm writes Sc):
//   Whi/Wlo (2x4.2 MB) + WvT (2.1 MB) + Mtp (4x4.2 MB fp32) = 27.3 MB
// P (bf16) written in place into Sc rows (row r at ushort offset r*4096).
// ---------------------------------------------------------------------------
extern "C" void kernel_launch(void* const* d_in, const int* in_sizes, int n_in,
                              void* d_out, int out_size, void* d_ws, size_t ws_size,
                              hipStream_t stream)
{
    const float* x    = (const float*)d_in[0];
    const int*   mask = (const int*)d_in[1];
    const float* wq   = (const float*)d_in[2];
    const float* wk   = (const float*)d_in[3];
    const float* wv   = (const float*)d_in[4];
    float* out = (float*)d_out;

    const size_t NQ = (size_t)BATCH * SEQ * DIM;     // 8 388 608
    const size_t NM = (size_t)DIM * DIM;             // 1 048 576
    unsigned short* Xhi  = (unsigned short*)d_ws;
    unsigned short* Xlo  = Xhi + NQ;
    unsigned short* Yhi  = Xlo + NQ;
    unsigned short* Ylo  = Yhi + NQ;
    unsigned short* Vt   = Ylo + NQ;
    unsigned short* Mthi = Vt + NQ;
    unsigned short* Mtlo = Mthi + NM;
    float* Sc = (float*)(Mtlo + NM);
    unsigned long long* Mb = (unsigned long long*)(Sc + (size_t)BATCH * SEQ * SEQ);

    unsigned short* Whi = (unsigned short*)Sc;       // transient aliases
    unsigned short* Wlo = Whi + 2 * NM;
    unsigned short* WvT = Wlo + 2 * NM;
    float* Mtp = (float*)(WvT + NM);

    // one-time: allow 128 KiB dynamic LDS for the 256^2 S-gemm
    static bool lds_attr_set = false;
    if (!lds_attr_set) {
        (void)hipFuncSetAttribute((const void*)s_gemm256_kernel,
                                  hipFuncAttributeMaxDynamicSharedMemorySize,
                                  131072);
        lds_attr_set = true;
    }

    // 1. X -> hi/lo bf16; mask -> bitmask
    convert_x_kernel<<<dim3(NQ / 4 / 256), 256, 0, stream>>>(x, Xhi, Xlo);
    mask_pack_kernel<<<dim3(SEQ), 256, 0, stream>>>(mask, Mb);
    // 2. Wq/Wk -> hi/lo bf16 (no transpose); Wv -> WvT hi bf16
    convert_wqk_kernel<<<dim3(NM / 4 / 256, 2), 256, 0, stream>>>(wq, wk, Whi, Wlo);
    convert_wv_kernel<<<dim3(32, 32), 256, 0, stream>>>(wv, WvT);
    // 3. Mt = Wk.Wq^T (K-split x4, fp32 partials), then reduce + hi/lo split
    m_gemm_kernel<<<dim3(8, 8, 4), 256, 0, stream>>>(Whi, Wlo, Mtp);
    m_reduce_kernel<<<dim3(NM / 4 / 256), 256, 0, stream>>>(Mtp, Mthi, Mtlo);
    // 4. z=0: Y = X.Mt^T (hi/lo out); z=1: V = X.WvT^T written as Vt[b][d][s]
    yv_gemm_kernel<<<dim3(DIM / 128, (BATCH * SEQ) / 128, 2), 256, 0, stream>>>(
        Xhi, Xlo, Mthi, Mtlo, WvT, Yhi, Ylo, Vt);
    // 5. S = masked, scaled Y.X^T per batch (fp32 scores), 256^2 6-phase
    s_gemm256_kernel<<<dim3(SEQ / 256, SEQ / 256, BATCH), 512, 131072, stream>>>(
        Yhi, Ylo, Xhi, Xlo, Mb, Sc);
    // 6. softmax; writes bf16 P in place
    softmax_kernel<<<dim3(BATCH * SEQ), 256, 0, stream>>>(Sc);
    // 7. O = P @ V (double-buffered, counted vmcnt)
    pv_mfma_kernel<<<dim3(DIM / 128, SEQ / 128, BATCH), 256, 0, stream>>>(
        (const unsigned short*)Sc, Vt, out);
}

// Round 5
// 371.238 us; speedup vs baseline: 1.0541x; 1.0529x over previous
//
#include <hip/hip_runtime.h>
#include <math.h>

static constexpr int BATCH = 4;
static constexpr int SEQ   = 2048;
static constexpr int DIM   = 1024;

typedef __attribute__((ext_vector_type(8))) short     bf16x8;  // MFMA A/B frag (4 VGPRs)
typedef __attribute__((ext_vector_type(4))) float     f32x4;   // MFMA C/D frag

// fp32 -> bf16 (RNE) and back, bit-exact helpers for hi/lo splitting
__device__ __forceinline__ unsigned short f2b(float v) {
    unsigned int u = __float_as_uint(v);
    u = u + 0x7fffu + ((u >> 16) & 1u);
    return (unsigned short)(u >> 16);
}
__device__ __forceinline__ float b2f(unsigned short h) {
    return __uint_as_float(((unsigned int)h) << 16);
}

// ---------------------------------------------------------------------------
// convert_x: fp32 -> (hi, lo) bf16, elementwise.
// ---------------------------------------------------------------------------
__global__ __launch_bounds__(256) void convert_x_kernel(
    const float* __restrict__ X, unsigned short* __restrict__ hi,
    unsigned short* __restrict__ lo)
{
    const int i = blockIdx.x * 256 + threadIdx.x;   // float4 index
    const float4 v = ((const float4*)X)[i];
    ushort4 h, l;
    h.x = f2b(v.x); l.x = f2b(v.x - b2f(h.x));
    h.y = f2b(v.y); l.y = f2b(v.y - b2f(h.y));
    h.z = f2b(v.z); l.z = f2b(v.z - b2f(h.z));
    h.w = f2b(v.w); l.w = f2b(v.w - b2f(h.w));
    ((ushort4*)hi)[i] = h;
    ((ushort4*)lo)[i] = l;
}

// ---------------------------------------------------------------------------
// convert_wqk: Wq (y=0) / Wk (y=1) fp32 -> hi/lo bf16, NO transpose.
// ---------------------------------------------------------------------------
__global__ __launch_bounds__(256) void convert_wqk_kernel(
    const float* __restrict__ Wq, const float* __restrict__ Wk,
    unsigned short* __restrict__ hi, unsigned short* __restrict__ lo)
{
    const int z = blockIdx.y;
    const float* __restrict__ W = z ? Wk : Wq;
    const int i = blockIdx.x * 256 + threadIdx.x;   // float4 index within matrix
    const int o = z * (DIM * DIM / 4) + i;
    const float4 v = ((const float4*)W)[i];
    ushort4 h, l;
    h.x = f2b(v.x); l.x = f2b(v.x - b2f(h.x));
    h.y = f2b(v.y); l.y = f2b(v.y - b2f(h.y));
    h.z = f2b(v.z); l.z = f2b(v.z - b2f(h.z));
    h.w = f2b(v.w); l.w = f2b(v.w - b2f(h.w));
    ((ushort4*)hi)[o] = h;
    ((ushort4*)lo)[o] = l;
}

// ---------------------------------------------------------------------------
// convert_wv: Wv[k][n] fp32 -> WvT[n][k] hi bf16 (V is single-term).
// ---------------------------------------------------------------------------
__global__ __launch_bounds__(256) void convert_wv_kernel(
    const float* __restrict__ W, unsigned short* __restrict__ WT)
{
    __shared__ float t[32][33];
    const int n0 = blockIdx.x * 32, k0 = blockIdx.y * 32;
    const int tx = threadIdx.x & 31, ty = threadIdx.x >> 5;  // ty: 0..7
#pragma unroll
    for (int i = 0; i < 4; ++i)
        t[ty + i * 8][tx] = W[(size_t)(k0 + ty + i * 8) * DIM + (n0 + tx)];
    __syncthreads();
#pragma unroll
    for (int i = 0; i < 4; ++i)
        WT[(size_t)(n0 + ty + i * 8) * DIM + (k0 + tx)] = f2b(t[tx][ty + i * 8]);
}

// ---------------------------------------------------------------------------
// mask_pack: int32 mask [2048][2048] -> bitmask [2048][32] u64 (bit=1: mask).
// ---------------------------------------------------------------------------
__global__ __launch_bounds__(256) void mask_pack_kernel(
    const int* __restrict__ mask, unsigned long long* __restrict__ Mb)
{
    const int row  = blockIdx.x;
    const int lane = threadIdx.x & 63, w = threadIdx.x >> 6;
#pragma unroll
    for (int c = w; c < SEQ / 64; c += 4) {
        const int v = mask[(size_t)row * SEQ + c * 64 + lane];
        const unsigned long long bits = __ballot(v != 0);
        if (lane == 0) Mb[(size_t)row * (SEQ / 64) + c] = bits;
    }
}

// ---------------------------------------------------------------------------
// Async staging of a (rows x 32)-elem bf16 tile via global_load_lds w=16.
// XOR-swizzled unpadded 64 B rows; wave-uniform LDS dest. Works for any
// block size that is a multiple of 64 (each wave stages 32 rows).
// ---------------------------------------------------------------------------
__device__ __forceinline__ void stage_async(
    const unsigned short* __restrict__ g, int gstride, int row0, int k0,
    unsigned short* lds, int tid)
{
    const int w = tid >> 6, lane = tid & 63;
    const int c = (lane & 3) ^ ((lane >> 4) & 3);   // global chunk this lane fetches
#pragma unroll
    for (int h = 0; h < 2; ++h) {
        const int row = 32 * w + 16 * h + (lane >> 2);
        const unsigned short* src = g + (size_t)(row0 + row) * gstride + k0 + 8 * c;
        unsigned short* dst = lds + (32 * w + 16 * h) * 32;   // wave-uniform
        __builtin_amdgcn_global_load_lds(
            (const __attribute__((address_space(1))) void*)src,
            (__attribute__((address_space(3))) void*)dst, 16, 0, 0);
    }
}

__device__ __forceinline__ bf16x8 fragr(const unsigned short* lds, int row, int qsw)
{
    return *(const bf16x8*)(lds + row * 32 + qsw * 8);
}

// ---------------------------------------------------------------------------
// m_gemm: Mt = Wk . Wq^T  (so Mt[j][i] = sum_o Wq[i][o] Wk[j][o]), 3-term
// split bf16, 128x128 tile, K-split over z (4 chunks of 256). fp32 partials.
// ---------------------------------------------------------------------------
__global__ __launch_bounds__(256) void m_gemm_kernel(
    const unsigned short* __restrict__ Whi, const unsigned short* __restrict__ Wlo,
    float* __restrict__ Mtp)
{
    __shared__ unsigned short Ah[128 * 32], Al[128 * 32];
    __shared__ unsigned short Bh[128 * 32], Bl[128 * 32];

    const int tid = threadIdx.x;
    const int w = tid >> 6, lane = tid & 63;
    const int wm = (w >> 1) * 64, wn = (w & 1) * 64;
    const int m0 = blockIdx.y * 128, n0 = blockIdx.x * 128;
    const int z = blockIdx.z;                        // K chunk

    const unsigned short* __restrict__ Ahg = Whi + (size_t)DIM * DIM;  // Wk hi
    const unsigned short* __restrict__ Alg = Wlo + (size_t)DIM * DIM;  // Wk lo
    const unsigned short* __restrict__ Bhg = Whi;                      // Wq hi
    const unsigned short* __restrict__ Blg = Wlo;                      // Wq lo
    float* __restrict__ Cp = Mtp + (size_t)z * DIM * DIM;

    f32x4 acc[4][4];
#pragma unroll
    for (int i = 0; i < 4; ++i)
#pragma unroll
        for (int j = 0; j < 4; ++j) acc[i][j] = (f32x4){0.f, 0.f, 0.f, 0.f};

    const int fr = lane & 15, quad = lane >> 4;
    const int qsw = quad ^ ((fr >> 2) & 3);

    for (int k0 = z * 256; k0 < z * 256 + 256; k0 += 32) {
        stage_async(Ahg, DIM, m0, k0, Ah, tid);
        stage_async(Alg, DIM, m0, k0, Al, tid);
        stage_async(Bhg, DIM, n0, k0, Bh, tid);
        stage_async(Blg, DIM, n0, k0, Bl, tid);
        __syncthreads();

        bf16x8 ah[4], al[4];
#pragma unroll
        for (int mt = 0; mt < 4; ++mt) {
            ah[mt] = fragr(Ah, wm + mt * 16 + fr, qsw);
            al[mt] = fragr(Al, wm + mt * 16 + fr, qsw);
        }
#pragma unroll
        for (int nt = 0; nt < 4; ++nt) {
            const bf16x8 bh = fragr(Bh, wn + nt * 16 + fr, qsw);
            const bf16x8 bl = fragr(Bl, wn + nt * 16 + fr, qsw);
#pragma unroll
            for (int mt = 0; mt < 4; ++mt) {
                acc[mt][nt] = __builtin_amdgcn_mfma_f32_16x16x32_bf16(ah[mt], bh, acc[mt][nt], 0, 0, 0);
                acc[mt][nt] = __builtin_amdgcn_mfma_f32_16x16x32_bf16(ah[mt], bl, acc[mt][nt], 0, 0, 0);
                acc[mt][nt] = __builtin_amdgcn_mfma_f32_16x16x32_bf16(al[mt], bh, acc[mt][nt], 0, 0, 0);
            }
        }
        __syncthreads();
    }

    const int col = lane & 15, rq = lane >> 4;
#pragma unroll
    for (int mt = 0; mt < 4; ++mt)
#pragma unroll
        for (int nt = 0; nt < 4; ++nt)
#pragma unroll
            for (int e = 0; e < 4; ++e) {
                const int m = m0 + wm + mt * 16 + rq * 4 + e;
                const int n = n0 + wn + nt * 16 + col;
                Cp[(size_t)m * DIM + n] = acc[mt][nt][e];
            }
}

// ---------------------------------------------------------------------------
// m_reduce: sum 4 K-split partials, split to hi/lo bf16.
// ---------------------------------------------------------------------------
__global__ __launch_bounds__(256) void m_reduce_kernel(
    const float* __restrict__ Mtp, unsigned short* __restrict__ Mthi,
    unsigned short* __restrict__ Mtlo)
{
    const int i = blockIdx.x * 256 + threadIdx.x;   // float4 index
    const size_t q = (size_t)DIM * DIM / 4;
    const float4 a = ((const float4*)Mtp)[i];
    const float4 b = ((const float4*)Mtp)[i + q];
    const float4 c = ((const float4*)Mtp)[i + 2 * q];
    const float4 d = ((const float4*)Mtp)[i + 3 * q];
    const float4 v = make_float4(a.x + b.x + c.x + d.x, a.y + b.y + c.y + d.y,
                                 a.z + b.z + c.z + d.z, a.w + b.w + c.w + d.w);
    ushort4 h, l;
    h.x = f2b(v.x); l.x = f2b(v.x - b2f(h.x));
    h.y = f2b(v.y); l.y = f2b(v.y - b2f(h.y));
    h.z = f2b(v.z); l.z = f2b(v.z - b2f(h.z));
    h.w = f2b(v.w); l.w = f2b(v.w - b2f(h.w));
    ((ushort4*)Mthi)[i] = h;
    ((ushort4*)Mtlo)[i] = l;
}

// ---------------------------------------------------------------------------
// yv_gemm: z=0 -> Y = X @ Mt^T (3-term, hi/lo out, [8192][1024])
//          z=1 -> V = X @ WvT^T (1-term), written TRANSPOSED as Vt[b][d][s]
// XCD-aware Z-BALANCED block swizzle (T1, round-5 fix): chunk = 8 n-blocks
// sharing one (m,z) A-panel; chunk cg = xcd + 8*cl so every XCD gets
// 8 z=0 chunks + 8 z=1 chunks (balanced 3-term/1-term work), and panel m's
// z=0 and z=1 chunks land on the SAME XCD (m and m+64 are congruent mod 8)
// -> each X panel is fetched from HBM by exactly one XCD.
// grid (8,64,2) = 1024 blocks.
// ---------------------------------------------------------------------------
__global__ __launch_bounds__(256) void yv_gemm_kernel(
    const unsigned short* __restrict__ Xhi, const unsigned short* __restrict__ Xlo,
    const unsigned short* __restrict__ Mthi, const unsigned short* __restrict__ Mtlo,
    const unsigned short* __restrict__ WvT,
    unsigned short* __restrict__ Yhi, unsigned short* __restrict__ Ylo,
    unsigned short* __restrict__ Vt)
{
    __shared__ unsigned short Ah[128 * 32], Al[128 * 32];
    __shared__ unsigned short Bh[128 * 32], Bl[128 * 32];

    const int tid = threadIdx.x;
    const int w = tid >> 6, lane = tid & 63;
    const int wm = (w >> 1) * 64, wn = (w & 1) * 64;

    const int flat = blockIdx.x + (blockIdx.y << 3) + (blockIdx.z << 9);
    const int xcd = flat & 7, s = flat >> 3;         // s: 0..127 per XCD
    const int cg  = xcd + ((s >> 3) << 3);           // chunk 0..127, z-balanced
    const int n0 = (s & 7) * 128;
    const int m0 = (cg & 63) * 128;
    const int z  = cg >> 6;
    const bool full = (z == 0);

    const unsigned short* __restrict__ Bhg = full ? Mthi : WvT;
    const unsigned short* __restrict__ Blg = Mtlo;

    f32x4 acc[4][4];
#pragma unroll
    for (int i = 0; i < 4; ++i)
#pragma unroll
        for (int j = 0; j < 4; ++j) acc[i][j] = (f32x4){0.f, 0.f, 0.f, 0.f};

    const int fr = lane & 15, quad = lane >> 4;
    const int qsw = quad ^ ((fr >> 2) & 3);

    for (int k0 = 0; k0 < DIM; k0 += 32) {
        stage_async(Xhi, DIM, m0, k0, Ah, tid);
        stage_async(Bhg, DIM, n0, k0, Bh, tid);
        if (full) {
            stage_async(Xlo, DIM, m0, k0, Al, tid);
            stage_async(Blg, DIM, n0, k0, Bl, tid);
        }
        __syncthreads();

        bf16x8 ah[4], al[4];
#pragma unroll
        for (int mt = 0; mt < 4; ++mt)
            ah[mt] = fragr(Ah, wm + mt * 16 + fr, qsw);
        if (full) {
#pragma unroll
            for (int mt = 0; mt < 4; ++mt)
                al[mt] = fragr(Al, wm + mt * 16 + fr, qsw);
        }
#pragma unroll
        for (int nt = 0; nt < 4; ++nt) {
            const bf16x8 bh = fragr(Bh, wn + nt * 16 + fr, qsw);
#pragma unroll
            for (int mt = 0; mt < 4; ++mt)
                acc[mt][nt] = __builtin_amdgcn_mfma_f32_16x16x32_bf16(ah[mt], bh, acc[mt][nt], 0, 0, 0);
            if (full) {
                const bf16x8 bl = fragr(Bl, wn + nt * 16 + fr, qsw);
#pragma unroll
                for (int mt = 0; mt < 4; ++mt) {
                    acc[mt][nt] = __builtin_amdgcn_mfma_f32_16x16x32_bf16(ah[mt], bl, acc[mt][nt], 0, 0, 0);
                    acc[mt][nt] = __builtin_amdgcn_mfma_f32_16x16x32_bf16(al[mt], bh, acc[mt][nt], 0, 0, 0);
                }
            }
        }
        __syncthreads();
    }

    const int col = lane & 15, rq = lane >> 4;
    if (full) {
#pragma unroll
        for (int mt = 0; mt < 4; ++mt)
#pragma unroll
            for (int nt = 0; nt < 4; ++nt)
#pragma unroll
                for (int e = 0; e < 4; ++e) {
                    const int m = m0 + wm + mt * 16 + rq * 4 + e;
                    const int n = n0 + wn + nt * 16 + col;
                    const float v = acc[mt][nt][e];
                    const unsigned short h = f2b(v);
                    Yhi[(size_t)m * DIM + n] = h;
                    Ylo[(size_t)m * DIM + n] = f2b(v - b2f(h));
                }
    } else {
        // V: write transposed, Vt[b][n][s], 4 consecutive s per ushort4
#pragma unroll
        for (int mt = 0; mt < 4; ++mt)
#pragma unroll
            for (int nt = 0; nt < 4; ++nt) {
                const int m = m0 + wm + mt * 16 + rq * 4;      // 4-aligned
                const int bb = m >> 11, sr = m & (SEQ - 1);
                const int n = n0 + wn + nt * 16 + col;
                ushort4 pk;
                pk.x = f2b(acc[mt][nt][0]);
                pk.y = f2b(acc[mt][nt][1]);
                pk.z = f2b(acc[mt][nt][2]);
                pk.w = f2b(acc[mt][nt][3]);
                *(ushort4*)(Vt + (size_t)bb * DIM * SEQ + (size_t)n * SEQ + sr) = pk;
            }
    }
}

// ---------------------------------------------------------------------------
// s_gemm256: S[b] = (Y[b] . X[b]^T) * 1/32, masked to -inf. fp32 output.
// 256x256 tile, BK=32, 512 threads (8 waves, 2Mx4N, 128x64 per wave).
// 6-PHASE term schedule, 16-MFMA clusters, counted vmcnt (T3+T4+T5).
// XCD-aware bijective block swizzle (T1): grid (8,8,4) = 256 blocks, q=32.
// (Uniform per-block work -> no balance concern.)
// ---------------------------------------------------------------------------
__global__ __launch_bounds__(512, 2) void s_gemm256_kernel(
    const unsigned short* __restrict__ Yhi, const unsigned short* __restrict__ Ylo,
    const unsigned short* __restrict__ Xhi, const unsigned short* __restrict__ Xlo,
    const unsigned long long* __restrict__ Mb, float* __restrict__ Sc)
{
    extern __shared__ unsigned short smem[];
    // layout (ushort offsets): buffer c at c*32768:
    //   Ah = +0, Al = +8192, Bh = +16384, Bl = +24576   (each 256x32)

    const int tid = threadIdx.x;
    const int w = tid >> 6, lane = tid & 63;
    const int wm = (w >> 2) * 128, wn = (w & 3) * 64;

    const int flat = blockIdx.x + (blockIdx.y << 3) + (blockIdx.z << 6);
    const int lid  = ((flat & 7) << 5) | (flat >> 3);     // bijective, nwg=256
    const int m0 = ((lid >> 3) & 7) * 256, n0 = (lid & 7) * 256;
    const int b  = lid >> 6;

    const unsigned short* __restrict__ Ahg = Yhi + (size_t)b * SEQ * DIM;
    const unsigned short* __restrict__ Alg = Ylo + (size_t)b * SEQ * DIM;
    const unsigned short* __restrict__ Bhg = Xhi + (size_t)b * SEQ * DIM;
    const unsigned short* __restrict__ Blg = Xlo + (size_t)b * SEQ * DIM;
    float* __restrict__ Sb = Sc + (size_t)b * SEQ * SEQ;

    f32x4 acc[8][4];
#pragma unroll
    for (int i = 0; i < 8; ++i)
#pragma unroll
        for (int j = 0; j < 4; ++j) acc[i][j] = (f32x4){0.f, 0.f, 0.f, 0.f};

    const int fr = lane & 15, quad = lane >> 4;
    const int qsw = quad ^ ((fr >> 2) & 3);

    // prologue: issue K-step 0 into buffer 0 in phase-consumption order.
    stage_async(Ahg, DIM, m0, 0, smem + 0,     tid);
    stage_async(Bhg, DIM, n0, 0, smem + 16384, tid);
    stage_async(Blg, DIM, n0, 0, smem + 24576, tid);
    stage_async(Alg, DIM, m0, 0, smem + 8192,  tid);

    for (int it = 0; it < DIM / 32 - 1; ++it) {
        const int cur = (it & 1) * 32768;
        const int nxt = cur ^ 32768;
        const unsigned short* Ah = smem + cur;
        const unsigned short* Al = smem + cur + 8192;
        const unsigned short* Bh = smem + cur + 16384;
        const unsigned short* Bl = smem + cur + 24576;
        const int k1 = it * 32 + 32;

        bf16x8 ah[8], al[8], bh[4], bl[4];

        // ---- ph0a (hh, m-half 0) ----
        stage_async(Ahg, DIM, m0, k1, smem + nxt, tid);
        asm volatile("s_waitcnt vmcnt(6)" ::: "memory");
        __builtin_amdgcn_s_barrier();
#pragma unroll
        for (int mt = 0; mt < 4; ++mt)
            ah[mt] = fragr(Ah, wm + mt * 16 + fr, qsw);
#pragma unroll
        for (int nt = 0; nt < 4; ++nt)
            bh[nt] = fragr(Bh, wn + nt * 16 + fr, qsw);
        __builtin_amdgcn_s_setprio(1);
#pragma unroll
        for (int nt = 0; nt < 4; ++nt)
#pragma unroll
            for (int mt = 0; mt < 4; ++mt)
                acc[mt][nt] = __builtin_amdgcn_mfma_f32_16x16x32_bf16(ah[mt], bh[nt], acc[mt][nt], 0, 0, 0);
        __builtin_amdgcn_s_setprio(0);

        // ---- ph0b (hh, m-half 1) ----
        stage_async(Bhg, DIM, n0, k1, smem + nxt + 16384, tid);
#pragma unroll
        for (int mt = 4; mt < 8; ++mt)
            ah[mt] = fragr(Ah, wm + mt * 16 + fr, qsw);
        __builtin_amdgcn_s_setprio(1);
#pragma unroll
        for (int nt = 0; nt < 4; ++nt)
#pragma unroll
            for (int mt = 4; mt < 8; ++mt)
                acc[mt][nt] = __builtin_amdgcn_mfma_f32_16x16x32_bf16(ah[mt], bh[nt], acc[mt][nt], 0, 0, 0);
        __builtin_amdgcn_s_setprio(0);

        // ---- ph1a (hl, m-half 0) ----
        stage_async(Blg, DIM, n0, k1, smem + nxt + 24576, tid);
        asm volatile("s_waitcnt vmcnt(8)" ::: "memory");
        __builtin_amdgcn_s_barrier();
#pragma unroll
        for (int nt = 0; nt < 4; ++nt)
            bl[nt] = fragr(Bl, wn + nt * 16 + fr, qsw);
        __builtin_amdgcn_s_setprio(1);
#pragma unroll
        for (int nt = 0; nt < 4; ++nt)
#pragma unroll
            for (int mt = 0; mt < 4; ++mt)
                acc[mt][nt] = __builtin_amdgcn_mfma_f32_16x16x32_bf16(ah[mt], bl[nt], acc[mt][nt], 0, 0, 0);
        __builtin_amdgcn_s_setprio(0);

        // ---- ph1b (hl, m-half 1) ----
        __builtin_amdgcn_s_setprio(1);
#pragma unroll
        for (int nt = 0; nt < 4; ++nt)
#pragma unroll
            for (int mt = 4; mt < 8; ++mt)
                acc[mt][nt] = __builtin_amdgcn_mfma_f32_16x16x32_bf16(ah[mt], bl[nt], acc[mt][nt], 0, 0, 0);
        __builtin_amdgcn_s_setprio(0);

        // ---- ph2a (lh, m-half 0) ----
        stage_async(Alg, DIM, m0, k1, smem + nxt + 8192, tid);
        asm volatile("s_waitcnt vmcnt(8)" ::: "memory");
        __builtin_amdgcn_s_barrier();
#pragma unroll
        for (int mt = 0; mt < 4; ++mt)
            al[mt] = fragr(Al, wm + mt * 16 + fr, qsw);
        __builtin_amdgcn_s_setprio(1);
#pragma unroll
        for (int nt = 0; nt < 4; ++nt)
#pragma unroll
            for (int mt = 0; mt < 4; ++mt)
                acc[mt][nt] = __builtin_amdgcn_mfma_f32_16x16x32_bf16(al[mt], bh[nt], acc[mt][nt], 0, 0, 0);
        __builtin_amdgcn_s_setprio(0);

        // ---- ph2b (lh, m-half 1) ----
#pragma unroll
        for (int mt = 4; mt < 8; ++mt)
            al[mt] = fragr(Al, wm + mt * 16 + fr, qsw);
        __builtin_amdgcn_s_setprio(1);
#pragma unroll
        for (int nt = 0; nt < 4; ++nt)
#pragma unroll
            for (int mt = 4; mt < 8; ++mt)
                acc[mt][nt] = __builtin_amdgcn_mfma_f32_16x16x32_bf16(al[mt], bh[nt], acc[mt][nt], 0, 0, 0);
        __builtin_amdgcn_s_setprio(0);
    }

    {   // ---- peeled last K-step (cur = buffer 1): no prefetch ----
        const unsigned short* Ah = smem + 32768;
        const unsigned short* Al = smem + 32768 + 8192;
        const unsigned short* Bh = smem + 32768 + 16384;
        const unsigned short* Bl = smem + 32768 + 24576;

        bf16x8 ah[8], al[8], bh[4], bl[4];

        asm volatile("s_waitcnt vmcnt(4)" ::: "memory");
        __builtin_amdgcn_s_barrier();
#pragma unroll
        for (int mt = 0; mt < 8; ++mt)
            ah[mt] = fragr(Ah, wm + mt * 16 + fr, qsw);
#pragma unroll
        for (int nt = 0; nt < 4; ++nt)
            bh[nt] = fragr(Bh, wn + nt * 16 + fr, qsw);
        __builtin_amdgcn_s_setprio(1);
#pragma unroll
        for (int nt = 0; nt < 4; ++nt)
#pragma unroll
            for (int mt = 0; mt < 8; ++mt)
                acc[mt][nt] = __builtin_amdgcn_mfma_f32_16x16x32_bf16(ah[mt], bh[nt], acc[mt][nt], 0, 0, 0);
        __builtin_amdgcn_s_setprio(0);

        asm volatile("s_waitcnt vmcnt(2)" ::: "memory");
        __builtin_amdgcn_s_barrier();
#pragma unroll
        for (int nt = 0; nt < 4; ++nt)
            bl[nt] = fragr(Bl, wn + nt * 16 + fr, qsw);
        __builtin_amdgcn_s_setprio(1);
#pragma unroll
        for (int nt = 0; nt < 4; ++nt)
#pragma unroll
            for (int mt = 0; mt < 8; ++mt)
                acc[mt][nt] = __builtin_amdgcn_mfma_f32_16x16x32_bf16(ah[mt], bl[nt], acc[mt][nt], 0, 0, 0);
        __builtin_amdgcn_s_setprio(0);

        asm volatile("s_waitcnt vmcnt(0)" ::: "memory");
        __builtin_amdgcn_s_barrier();
#pragma unroll
        for (int mt = 0; mt < 8; ++mt)
            al[mt] = fragr(Al, wm + mt * 16 + fr, qsw);
        __builtin_amdgcn_s_setprio(1);
#pragma unroll
        for (int nt = 0; nt < 4; ++nt)
#pragma unroll
            for (int mt = 0; mt < 8; ++mt)
                acc[mt][nt] = __builtin_amdgcn_mfma_f32_16x16x32_bf16(al[mt], bh[nt], acc[mt][nt], 0, 0, 0);
        __builtin_amdgcn_s_setprio(0);
    }

    const int col = lane & 15, rq = lane >> 4;
    const int wword = (n0 + wn) >> 6;             // one u64 covers nt*16+col
#pragma unroll
    for (int mt = 0; mt < 8; ++mt)
#pragma unroll
        for (int e = 0; e < 4; ++e) {
            const int m = m0 + wm + mt * 16 + rq * 4 + e;
            const unsigned long long word = Mb[(size_t)m * (SEQ / 64) + wword];
#pragma unroll
            for (int nt = 0; nt < 4; ++nt) {
                const int n = n0 + wn + nt * 16 + col;
                const float v = acc[mt][nt][e] * 0.03125f;
                const bool msk = (word >> (nt * 16 + col)) & 1ull;
                Sb[(size_t)m * SEQ + n] = msk ? -INFINITY : v;
            }
        }
}

// ---------------------------------------------------------------------------
// Row softmax on pre-masked, pre-scaled fp32 S; writes bf16 P in place
// (row r -> first 2048 ushorts of the row's 16 KB).
// ---------------------------------------------------------------------------
__global__ __launch_bounds__(256) void softmax_kernel(float* __restrict__ Sc)
{
    const int r = blockIdx.x;          // b*2048 + m
    float* __restrict__ row = Sc + (size_t)r * SEQ;

    const int tid  = threadIdx.x;
    const int lane = tid & 63;
    const int wid  = tid >> 6;

    float x[8];
    float mx = -INFINITY;
#pragma unroll
    for (int j = 0; j < 8; ++j) {
        x[j] = row[tid + j * 256];
        mx = fmaxf(mx, x[j]);
    }
    __shared__ float redm[4];
#pragma unroll
    for (int off = 32; off > 0; off >>= 1)
        mx = fmaxf(mx, __shfl_down(mx, off, 64));
    if (lane == 0) redm[wid] = mx;
    __syncthreads();
    mx = fmaxf(fmaxf(redm[0], redm[1]), fmaxf(redm[2], redm[3]));

    float sum = 0.f;
#pragma unroll
    for (int j = 0; j < 8; ++j) {
        const float e = __expf(x[j] - mx);
        x[j] = e;
        sum += e;
    }
    __shared__ float reds[4];
#pragma unroll
    for (int off = 32; off > 0; off >>= 1)
        sum += __shfl_down(sum, off, 64);
    if (lane == 0) reds[wid] = sum;
    __syncthreads();
    sum = (reds[0] + reds[1]) + (reds[2] + reds[3]);

    const float inv = 1.0f / sum;
    unsigned short* __restrict__ prow = (unsigned short*)row;
#pragma unroll
    for (int j = 0; j < 8; ++j)
        prow[tid + j * 256] = f2b(x[j] * inv);
}

// ---------------------------------------------------------------------------
// O[b] = P[b] @ V[b]: single bf16 MFMA, double-buffered BK=32 with counted
// vmcnt. XCD-aware bijective block swizzle (T1): grid (8,16,4)=512, q=64.
// A = P rows (stride 4096 ushorts), B = Vt rows (n-major, k contiguous).
// ---------------------------------------------------------------------------
__global__ __launch_bounds__(256) void pv_mfma_kernel(
    const unsigned short* __restrict__ P, const unsigned short* __restrict__ Vt,
    float* __restrict__ O)
{
    __shared__ unsigned short As[2][128 * 32], Bs[2][128 * 32];

    const int tid = threadIdx.x;
    const int w = tid >> 6, lane = tid & 63;
    const int wm = (w >> 1) * 64, wn = (w & 1) * 64;

    const int flat = blockIdx.x + (blockIdx.y << 3) + (blockIdx.z << 7);
    const int lid  = ((flat & 7) << 6) | (flat >> 3);     // bijective, nwg=512
    const int m0 = ((lid >> 3) & 15) * 128, n0 = (lid & 7) * 128;
    const int b  = lid >> 7;

    const unsigned short* __restrict__ Ag = P + (size_t)b * SEQ * (2 * SEQ);
    const unsigned short* __restrict__ Bg = Vt + (size_t)b * DIM * SEQ;
    float* __restrict__ Ob = O + (size_t)b * SEQ * DIM;

    f32x4 acc[4][4];
#pragma unroll
    for (int i = 0; i < 4; ++i)
#pragma unroll
        for (int j = 0; j < 4; ++j) acc[i][j] = (f32x4){0.f, 0.f, 0.f, 0.f};

    const int fr = lane & 15, quad = lane >> 4;
    const int qsw = quad ^ ((fr >> 2) & 3);

    // prologue: stage K-step 0 into buffer 0
    stage_async(Ag, 2 * SEQ, m0, 0, As[0], tid);
    stage_async(Bg, SEQ,     n0, 0, Bs[0], tid);

    for (int it = 0; it < SEQ / 32 - 1; ++it) {
        const int cur = it & 1, nxt = cur ^ 1;
        const int k1 = it * 32 + 32;

        // prefetch next K-step, then wait only for the previous one
        stage_async(Ag, 2 * SEQ, m0, k1, As[nxt], tid);
        stage_async(Bg, SEQ,     n0, k1, Bs[nxt], tid);
        asm volatile("s_waitcnt vmcnt(4)" ::: "memory");
        __builtin_amdgcn_s_barrier();

        bf16x8 af[4];
#pragma unroll
        for (int mt = 0; mt < 4; ++mt)
            af[mt] = fragr(As[cur], wm + mt * 16 + fr, qsw);
        __builtin_amdgcn_s_setprio(1);
#pragma unroll
        for (int nt = 0; nt < 4; ++nt) {
            const bf16x8 bfg = fragr(Bs[cur], wn + nt * 16 + fr, qsw);
#pragma unroll
            for (int mt = 0; mt < 4; ++mt)
                acc[mt][nt] = __builtin_amdgcn_mfma_f32_16x16x32_bf16(af[mt], bfg, acc[mt][nt], 0, 0, 0);
        }
        __builtin_amdgcn_s_setprio(0);
        __builtin_amdgcn_s_barrier();   // guard cur slot against next prefetch
    }

    {   // peeled last K-step (cur = buffer 1)
        asm volatile("s_waitcnt vmcnt(0)" ::: "memory");
        __builtin_amdgcn_s_barrier();
        bf16x8 af[4];
#pragma unroll
        for (int mt = 0; mt < 4; ++mt)
            af[mt] = fragr(As[1], wm + mt * 16 + fr, qsw);
        __builtin_amdgcn_s_setprio(1);
#pragma unroll
        for (int nt = 0; nt < 4; ++nt) {
            const bf16x8 bfg = fragr(Bs[1], wn + nt * 16 + fr, qsw);
#pragma unroll
            for (int mt = 0; mt < 4; ++mt)
                acc[mt][nt] = __builtin_amdgcn_mfma_f32_16x16x32_bf16(af[mt], bfg, acc[mt][nt], 0, 0, 0);
        }
        __builtin_amdgcn_s_setprio(0);
    }

    const int col = lane & 15, rq = lane >> 4;
#pragma unroll
    for (int mt = 0; mt < 4; ++mt)
#pragma unroll
        for (int nt = 0; nt < 4; ++nt)
#pragma unroll
            for (int e = 0; e < 4; ++e) {
                const int m = m0 + wm + mt * 16 + rq * 4 + e;
                const int n = n0 + wn + nt * 16 + col;
                Ob[(size_t)m * DIM + n] = acc[mt][nt][e];
            }
}

// ---------------------------------------------------------------------------
// Workspace layout (bytes), ws = 167 772 160:
//   Xhi/Xlo/Yhi/Ylo/Vt : 5 x 16 777 216   (bf16 [8192][1024]-sized each)
//   Mthi/Mtlo          : 2 x  2 097 152   (bf16 [1024][1024])
//   Sc                 : 67 108 864       (fp32 [4][2048][2048])
//   Mbits              :    524 288       (u64  [2048][32])       -> 155.7 MB
// Transients aliased INSIDE Sc (consumed before s_gemm writes Sc):
//   Whi/Wlo (2x4.2 MB) + WvT (2.1 MB) + Mtp (4x4.2 MB fp32) = 27.3 MB
// P (bf16) written in place into Sc rows (row r at ushort offset r*4096).
// ---------------------------------------------------------------------------
extern "C" void kernel_launch(void* const* d_in, const int* in_sizes, int n_in,
                              void* d_out, int out_size, void* d_ws, size_t ws_size,
                              hipStream_t stream)
{
    const float* x    = (const float*)d_in[0];
    const int*   mask = (const int*)d_in[1];
    const float* wq   = (const float*)d_in[2];
    const float* wk   = (const float*)d_in[3];
    const float* wv   = (const float*)d_in[4];
    float* out = (float*)d_out;

    const size_t NQ = (size_t)BATCH * SEQ * DIM;     // 8 388 608
    const size_t NM = (size_t)DIM * DIM;             // 1 048 576
    unsigned short* Xhi  = (unsigned short*)d_ws;
    unsigned short* Xlo  = Xhi + NQ;
    unsigned short* Yhi  = Xlo + NQ;
    unsigned short* Ylo  = Yhi + NQ;
    unsigned short* Vt   = Ylo + NQ;
    unsigned short* Mthi = Vt + NQ;
    unsigned short* Mtlo = Mthi + NM;
    float* Sc = (float*)(Mtlo + NM);
    unsigned long long* Mb = (unsigned long long*)(Sc + (size_t)BATCH * SEQ * SEQ);

    unsigned short* Whi = (unsigned short*)Sc;       // transient aliases
    unsigned short* Wlo = Whi + 2 * NM;
    unsigned short* WvT = Wlo + 2 * NM;
    float* Mtp = (float*)(WvT + NM);

    // one-time: allow 128 KiB dynamic LDS for the 256^2 S-gemm
    static bool lds_attr_set = false;
    if (!lds_attr_set) {
        (void)hipFuncSetAttribute((const void*)s_gemm256_kernel,
                                  hipFuncAttributeMaxDynamicSharedMemorySize,
                                  131072);
        lds_attr_set = true;
    }

    // 1. X -> hi/lo bf16; mask -> bitmask
    convert_x_kernel<<<dim3(NQ / 4 / 256), 256, 0, stream>>>(x, Xhi, Xlo);
    mask_pack_kernel<<<dim3(SEQ), 256, 0, stream>>>(mask, Mb);
    // 2. Wq/Wk -> hi/lo bf16 (no transpose); Wv -> WvT hi bf16
    convert_wqk_kernel<<<dim3(NM / 4 / 256, 2), 256, 0, stream>>>(wq, wk, Whi, Wlo);
    convert_wv_kernel<<<dim3(32, 32), 256, 0, stream>>>(wv, WvT);
    // 3. Mt = Wk.Wq^T (K-split x4, fp32 partials), then reduce + hi/lo split
    m_gemm_kernel<<<dim3(8, 8, 4), 256, 0, stream>>>(Whi, Wlo, Mtp);
    m_reduce_kernel<<<dim3(NM / 4 / 256), 256, 0, stream>>>(Mtp, Mthi, Mtlo);
    // 4. z=0: Y = X.Mt^T (hi/lo out); z=1: V = X.WvT^T written as Vt[b][d][s]
    yv_gemm_kernel<<<dim3(DIM / 128, (BATCH * SEQ) / 128, 2), 256, 0, stream>>>(
        Xhi, Xlo, Mthi, Mtlo, WvT, Yhi, Ylo, Vt);
    // 5. S = masked, scaled Y.X^T per batch (fp32 scores), 256^2 6-phase
    s_gemm256_kernel<<<dim3(SEQ / 256, SEQ / 256, BATCH), 512, 131072, stream>>>(
        Yhi, Ylo, Xhi, Xlo, Mb, Sc);
    // 6. softmax; writes bf16 P in place
    softmax_kernel<<<dim3(BATCH * SEQ), 256, 0, stream>>>(Sc);
    // 7. O = P @ V (double-buffered, counted vmcnt)
    pv_mfma_kernel<<<dim3(DIM / 128, SEQ / 128, BATCH), 256, 0, stream>>>(
        (const unsigned short*)Sc, Vt, out);
}

// Round 6
// 354.303 us; speedup vs baseline: 1.1045x; 1.0478x over previous
//
#include <hip/hip_runtime.h>
#include <math.h>

static constexpr int BATCH = 4;
static constexpr int SEQ   = 2048;
static constexpr int DIM   = 1024;

typedef __attribute__((ext_vector_type(8))) short     bf16x8;  // MFMA A/B frag (4 VGPRs)
typedef __attribute__((ext_vector_type(4))) float     f32x4;   // MFMA C/D frag

// fp32 -> bf16 (RNE) and back, bit-exact helpers for hi/lo splitting
__device__ __forceinline__ unsigned short f2b(float v) {
    unsigned int u = __float_as_uint(v);
    u = u + 0x7fffu + ((u >> 16) & 1u);
    return (unsigned short)(u >> 16);
}
__device__ __forceinline__ float b2f(unsigned short h) {
    return __uint_as_float(((unsigned int)h) << 16);
}

// ---------------------------------------------------------------------------
// convert_x: fp32 -> (hi, lo) bf16, elementwise.
// ---------------------------------------------------------------------------
__global__ __launch_bounds__(256) void convert_x_kernel(
    const float* __restrict__ X, unsigned short* __restrict__ hi,
    unsigned short* __restrict__ lo)
{
    const int i = blockIdx.x * 256 + threadIdx.x;   // float4 index
    const float4 v = ((const float4*)X)[i];
    ushort4 h, l;
    h.x = f2b(v.x); l.x = f2b(v.x - b2f(h.x));
    h.y = f2b(v.y); l.y = f2b(v.y - b2f(h.y));
    h.z = f2b(v.z); l.z = f2b(v.z - b2f(h.z));
    h.w = f2b(v.w); l.w = f2b(v.w - b2f(h.w));
    ((ushort4*)hi)[i] = h;
    ((ushort4*)lo)[i] = l;
}

// ---------------------------------------------------------------------------
// convert_wqk: Wq (y=0) / Wk (y=1) fp32 -> hi/lo bf16, NO transpose.
// ---------------------------------------------------------------------------
__global__ __launch_bounds__(256) void convert_wqk_kernel(
    const float* __restrict__ Wq, const float* __restrict__ Wk,
    unsigned short* __restrict__ hi, unsigned short* __restrict__ lo)
{
    const int z = blockIdx.y;
    const float* __restrict__ W = z ? Wk : Wq;
    const int i = blockIdx.x * 256 + threadIdx.x;   // float4 index within matrix
    const int o = z * (DIM * DIM / 4) + i;
    const float4 v = ((const float4*)W)[i];
    ushort4 h, l;
    h.x = f2b(v.x); l.x = f2b(v.x - b2f(h.x));
    h.y = f2b(v.y); l.y = f2b(v.y - b2f(h.y));
    h.z = f2b(v.z); l.z = f2b(v.z - b2f(h.z));
    h.w = f2b(v.w); l.w = f2b(v.w - b2f(h.w));
    ((ushort4*)hi)[o] = h;
    ((ushort4*)lo)[o] = l;
}

// ---------------------------------------------------------------------------
// convert_wv: Wv[k][n] fp32 -> WvT[n][k] hi bf16 (V is single-term).
// ---------------------------------------------------------------------------
__global__ __launch_bounds__(256) void convert_wv_kernel(
    const float* __restrict__ W, unsigned short* __restrict__ WT)
{
    __shared__ float t[32][33];
    const int n0 = blockIdx.x * 32, k0 = blockIdx.y * 32;
    const int tx = threadIdx.x & 31, ty = threadIdx.x >> 5;  // ty: 0..7
#pragma unroll
    for (int i = 0; i < 4; ++i)
        t[ty + i * 8][tx] = W[(size_t)(k0 + ty + i * 8) * DIM + (n0 + tx)];
    __syncthreads();
#pragma unroll
    for (int i = 0; i < 4; ++i)
        WT[(size_t)(n0 + ty + i * 8) * DIM + (k0 + tx)] = f2b(t[tx][ty + i * 8]);
}

// ---------------------------------------------------------------------------
// mask_pack: int32 mask [2048][2048] -> bitmask [2048][32] u64 (bit=1: mask).
// ---------------------------------------------------------------------------
__global__ __launch_bounds__(256) void mask_pack_kernel(
    const int* __restrict__ mask, unsigned long long* __restrict__ Mb)
{
    const int row  = blockIdx.x;
    const int lane = threadIdx.x & 63, w = threadIdx.x >> 6;
#pragma unroll
    for (int c = w; c < SEQ / 64; c += 4) {
        const int v = mask[(size_t)row * SEQ + c * 64 + lane];
        const unsigned long long bits = __ballot(v != 0);
        if (lane == 0) Mb[(size_t)row * (SEQ / 64) + c] = bits;
    }
}

// ---------------------------------------------------------------------------
// Async staging of a (rows x 32)-elem bf16 tile via global_load_lds w=16.
// XOR-swizzled unpadded 64 B rows; wave-uniform LDS dest. stage_async stages
// 32 rows/wave (128 rows @256thr, 256 rows @512thr); stage128 stages
// 16 rows/wave (128 rows @512thr).
// ---------------------------------------------------------------------------
__device__ __forceinline__ void stage_async(
    const unsigned short* __restrict__ g, int gstride, int row0, int k0,
    unsigned short* lds, int tid)
{
    const int w = tid >> 6, lane = tid & 63;
    const int c = (lane & 3) ^ ((lane >> 4) & 3);   // global chunk this lane fetches
#pragma unroll
    for (int h = 0; h < 2; ++h) {
        const int row = 32 * w + 16 * h + (lane >> 2);
        const unsigned short* src = g + (size_t)(row0 + row) * gstride + k0 + 8 * c;
        unsigned short* dst = lds + (32 * w + 16 * h) * 32;   // wave-uniform
        __builtin_amdgcn_global_load_lds(
            (const __attribute__((address_space(1))) void*)src,
            (__attribute__((address_space(3))) void*)dst, 16, 0, 0);
    }
}

__device__ __forceinline__ void stage128(
    const unsigned short* __restrict__ g, int gstride, int row0, int k0,
    unsigned short* lds, int tid)
{
    const int w = tid >> 6, lane = tid & 63;
    const int c = (lane & 3) ^ ((lane >> 4) & 3);
    const int row = 16 * w + (lane >> 2);
    const unsigned short* src = g + (size_t)(row0 + row) * gstride + k0 + 8 * c;
    unsigned short* dst = lds + (16 * w) * 32;            // wave-uniform
    __builtin_amdgcn_global_load_lds(
        (const __attribute__((address_space(1))) void*)src,
        (__attribute__((address_space(3))) void*)dst, 16, 0, 0);
}

__device__ __forceinline__ bf16x8 fragr(const unsigned short* lds, int row, int qsw)
{
    return *(const bf16x8*)(lds + row * 32 + qsw * 8);
}

// ---------------------------------------------------------------------------
// m_gemm: Mt = Wk . Wq^T  (so Mt[j][i] = sum_o Wq[i][o] Wk[j][o]), 3-term
// split bf16, 128x128 tile, K-split over z (4 chunks of 256). fp32 partials.
// ---------------------------------------------------------------------------
__global__ __launch_bounds__(256) void m_gemm_kernel(
    const unsigned short* __restrict__ Whi, const unsigned short* __restrict__ Wlo,
    float* __restrict__ Mtp)
{
    __shared__ unsigned short Ah[128 * 32], Al[128 * 32];
    __shared__ unsigned short Bh[128 * 32], Bl[128 * 32];

    const int tid = threadIdx.x;
    const int w = tid >> 6, lane = tid & 63;
    const int wm = (w >> 1) * 64, wn = (w & 1) * 64;
    const int m0 = blockIdx.y * 128, n0 = blockIdx.x * 128;
    const int z = blockIdx.z;                        // K chunk

    const unsigned short* __restrict__ Ahg = Whi + (size_t)DIM * DIM;  // Wk hi
    const unsigned short* __restrict__ Alg = Wlo + (size_t)DIM * DIM;  // Wk lo
    const unsigned short* __restrict__ Bhg = Whi;                      // Wq hi
    const unsigned short* __restrict__ Blg = Wlo;                      // Wq lo
    float* __restrict__ Cp = Mtp + (size_t)z * DIM * DIM;

    f32x4 acc[4][4];
#pragma unroll
    for (int i = 0; i < 4; ++i)
#pragma unroll
        for (int j = 0; j < 4; ++j) acc[i][j] = (f32x4){0.f, 0.f, 0.f, 0.f};

    const int fr = lane & 15, quad = lane >> 4;
    const int qsw = quad ^ ((fr >> 2) & 3);

    for (int k0 = z * 256; k0 < z * 256 + 256; k0 += 32) {
        stage_async(Ahg, DIM, m0, k0, Ah, tid);
        stage_async(Alg, DIM, m0, k0, Al, tid);
        stage_async(Bhg, DIM, n0, k0, Bh, tid);
        stage_async(Blg, DIM, n0, k0, Bl, tid);
        __syncthreads();

        bf16x8 ah[4], al[4];
#pragma unroll
        for (int mt = 0; mt < 4; ++mt) {
            ah[mt] = fragr(Ah, wm + mt * 16 + fr, qsw);
            al[mt] = fragr(Al, wm + mt * 16 + fr, qsw);
        }
#pragma unroll
        for (int nt = 0; nt < 4; ++nt) {
            const bf16x8 bh = fragr(Bh, wn + nt * 16 + fr, qsw);
            const bf16x8 bl = fragr(Bl, wn + nt * 16 + fr, qsw);
#pragma unroll
            for (int mt = 0; mt < 4; ++mt) {
                acc[mt][nt] = __builtin_amdgcn_mfma_f32_16x16x32_bf16(ah[mt], bh, acc[mt][nt], 0, 0, 0);
                acc[mt][nt] = __builtin_amdgcn_mfma_f32_16x16x32_bf16(ah[mt], bl, acc[mt][nt], 0, 0, 0);
                acc[mt][nt] = __builtin_amdgcn_mfma_f32_16x16x32_bf16(al[mt], bh, acc[mt][nt], 0, 0, 0);
            }
        }
        __syncthreads();
    }

    const int col = lane & 15, rq = lane >> 4;
#pragma unroll
    for (int mt = 0; mt < 4; ++mt)
#pragma unroll
        for (int nt = 0; nt < 4; ++nt)
#pragma unroll
            for (int e = 0; e < 4; ++e) {
                const int m = m0 + wm + mt * 16 + rq * 4 + e;
                const int n = n0 + wn + nt * 16 + col;
                Cp[(size_t)m * DIM + n] = acc[mt][nt][e];
            }
}

// ---------------------------------------------------------------------------
// m_reduce: sum 4 K-split partials, split to hi/lo bf16.
// ---------------------------------------------------------------------------
__global__ __launch_bounds__(256) void m_reduce_kernel(
    const float* __restrict__ Mtp, unsigned short* __restrict__ Mthi,
    unsigned short* __restrict__ Mtlo)
{
    const int i = blockIdx.x * 256 + threadIdx.x;   // float4 index
    const size_t q = (size_t)DIM * DIM / 4;
    const float4 a = ((const float4*)Mtp)[i];
    const float4 b = ((const float4*)Mtp)[i + q];
    const float4 c = ((const float4*)Mtp)[i + 2 * q];
    const float4 d = ((const float4*)Mtp)[i + 3 * q];
    const float4 v = make_float4(a.x + b.x + c.x + d.x, a.y + b.y + c.y + d.y,
                                 a.z + b.z + c.z + d.z, a.w + b.w + c.w + d.w);
    ushort4 h, l;
    h.x = f2b(v.x); l.x = f2b(v.x - b2f(h.x));
    h.y = f2b(v.y); l.y = f2b(v.y - b2f(h.y));
    h.z = f2b(v.z); l.z = f2b(v.z - b2f(h.z));
    h.w = f2b(v.w); l.w = f2b(v.w - b2f(h.w));
    ((ushort4*)Mthi)[i] = h;
    ((ushort4*)Mtlo)[i] = l;
}

// ---------------------------------------------------------------------------
// yv_gemm (MERGED, round 6): one 256x128 tile computes BOTH
//   Y[m0:+256][n0:+128] = X @ Mt^T   (3-term hi/lo, fp32 acc)
//   V[m0:+256][n0:+128] = Xhi @ WvT^T (1-term, written transposed to Vt)
// A (X hi/lo) staged ONCE for all 4 MFMA terms; V reuses the ah register
// fragments. 512 threads, 8 waves (4Mx2N, 64x64 Y + 64x64 V each).
// 4-phase term schedule, 16-MFMA clusters, counted vmcnt:
//   ph0 Y-hh (needs Ah,BYh) | issues Ah'x2          | vmcnt(6)
//   ph1 Y-hl (needs BYl)    | issues BYh'+BYl'      | vmcnt(7)
//   ph2 V-h  (needs BVh)    | issues Al'x2          | vmcnt(6)
//   ph3 Y-lh (needs Al)     | issues BVh'           | vmcnt(8)
// (7 loads/lane/iter; every tile >=3-phase issue-to-use gap; prologue issues
// in steady-state order so iter-0 counts are identical; peel = 4/3/0/-.)
// Per-element Y order stays hh->hl->lh per K-step (bit-exact).
// LDS: 2 x 56 KiB (Ah 16K | Al 16K | BYh 8K | BYl 8K | BVh 8K).
// Grid (8,32)=256 uniform blocks; XCD swizzle: 8 n-blocks sharing an m-panel
// land on one XCD (m-chunk = xcd + 8*(s>>3)).
// ---------------------------------------------------------------------------
__global__ __launch_bounds__(512, 2) void yv_gemm_kernel(
    const unsigned short* __restrict__ Xhi, const unsigned short* __restrict__ Xlo,
    const unsigned short* __restrict__ Mthi, const unsigned short* __restrict__ Mtlo,
    const unsigned short* __restrict__ WvT,
    unsigned short* __restrict__ Yhi, unsigned short* __restrict__ Ylo,
    unsigned short* __restrict__ Vt)
{
    extern __shared__ unsigned short smem[];
    // per-buffer ushort offsets: Ah=0, Al=8192, BYh=16384, BYl=20480, BVh=24576
    // buffer stride = 28672 ushorts (56 KiB)

    const int tid = threadIdx.x;
    const int w = tid >> 6, lane = tid & 63;
    const int wm = (w >> 1) * 64, wn = (w & 1) * 64;

    const int flat = blockIdx.x + (blockIdx.y << 3);   // grid (8, 32)
    const int xcd = flat & 7, s = flat >> 3;           // s: 0..31
    const int m0 = (xcd + ((s >> 3) << 3)) * 256;      // m-chunk == xcd (mod 8)
    const int n0 = (s & 7) * 128;

    f32x4 accY[4][4], accV[4][4];
#pragma unroll
    for (int i = 0; i < 4; ++i)
#pragma unroll
        for (int j = 0; j < 4; ++j) {
            accY[i][j] = (f32x4){0.f, 0.f, 0.f, 0.f};
            accV[i][j] = (f32x4){0.f, 0.f, 0.f, 0.f};
        }

    const int fr = lane & 15, quad = lane >> 4;
    const int qsw = quad ^ ((fr >> 2) & 3);

    // prologue: K-step 0 into buffer 0, steady-state issue order
    stage_async(Xhi, DIM, m0, 0, smem + 0,     tid);   // Ah x2
    stage128(Mthi, DIM, n0, 0, smem + 16384, tid);     // BYh
    stage128(Mtlo, DIM, n0, 0, smem + 20480, tid);     // BYl
    stage_async(Xlo, DIM, m0, 0, smem + 8192,  tid);   // Al x2
    stage128(WvT,  DIM, n0, 0, smem + 24576, tid);     // BVh

    bf16x8 ah[4], al[4], bh[4], bl[4], bv[4];

    for (int it = 0; it < DIM / 32 - 1; ++it) {
        const int cur = (it & 1) * 28672;
        const int nxt = 28672 - cur;
        const int k1 = it * 32 + 32;

        // ---- ph0: Y-hh ----
        stage_async(Xhi, DIM, m0, k1, smem + nxt, tid);
        asm volatile("s_waitcnt vmcnt(6)" ::: "memory");
        __builtin_amdgcn_s_barrier();
#pragma unroll
        for (int mt = 0; mt < 4; ++mt)
            ah[mt] = fragr(smem + cur, wm + mt * 16 + fr, qsw);
#pragma unroll
        for (int nt = 0; nt < 4; ++nt)
            bh[nt] = fragr(smem + cur + 16384, wn + nt * 16 + fr, qsw);
        __builtin_amdgcn_s_setprio(1);
#pragma unroll
        for (int nt = 0; nt < 4; ++nt)
#pragma unroll
            for (int mt = 0; mt < 4; ++mt)
                accY[mt][nt] = __builtin_amdgcn_mfma_f32_16x16x32_bf16(ah[mt], bh[nt], accY[mt][nt], 0, 0, 0);
        __builtin_amdgcn_s_setprio(0);

        // ---- ph1: Y-hl (ah held) ----
        stage128(Mthi, DIM, n0, k1, smem + nxt + 16384, tid);
        stage128(Mtlo, DIM, n0, k1, smem + nxt + 20480, tid);
        asm volatile("s_waitcnt vmcnt(7)" ::: "memory");
        __builtin_amdgcn_s_barrier();
#pragma unroll
        for (int nt = 0; nt < 4; ++nt)
            bl[nt] = fragr(smem + cur + 20480, wn + nt * 16 + fr, qsw);
        __builtin_amdgcn_s_setprio(1);
#pragma unroll
        for (int nt = 0; nt < 4; ++nt)
#pragma unroll
            for (int mt = 0; mt < 4; ++mt)
                accY[mt][nt] = __builtin_amdgcn_mfma_f32_16x16x32_bf16(ah[mt], bl[nt], accY[mt][nt], 0, 0, 0);
        __builtin_amdgcn_s_setprio(0);

        // ---- ph2: V-h (ah held) ----
        stage_async(Xlo, DIM, m0, k1, smem + nxt + 8192, tid);
        asm volatile("s_waitcnt vmcnt(6)" ::: "memory");
        __builtin_amdgcn_s_barrier();
#pragma unroll
        for (int nt = 0; nt < 4; ++nt)
            bv[nt] = fragr(smem + cur + 24576, wn + nt * 16 + fr, qsw);
        __builtin_amdgcn_s_setprio(1);
#pragma unroll
        for (int nt = 0; nt < 4; ++nt)
#pragma unroll
            for (int mt = 0; mt < 4; ++mt)
                accV[mt][nt] = __builtin_amdgcn_mfma_f32_16x16x32_bf16(ah[mt], bv[nt], accV[mt][nt], 0, 0, 0);
        __builtin_amdgcn_s_setprio(0);

        // ---- ph3: Y-lh (bh held) ----
        stage128(WvT, DIM, n0, k1, smem + nxt + 24576, tid);
        asm volatile("s_waitcnt vmcnt(8)" ::: "memory");
        __builtin_amdgcn_s_barrier();
#pragma unroll
        for (int mt = 0; mt < 4; ++mt)
            al[mt] = fragr(smem + cur + 8192, wm + mt * 16 + fr, qsw);
        __builtin_amdgcn_s_setprio(1);
#pragma unroll
        for (int nt = 0; nt < 4; ++nt)
#pragma unroll
            for (int mt = 0; mt < 4; ++mt)
                accY[mt][nt] = __builtin_amdgcn_mfma_f32_16x16x32_bf16(al[mt], bh[nt], accY[mt][nt], 0, 0, 0);
        __builtin_amdgcn_s_setprio(0);
    }

    {   // ---- peeled last K-step (cur = buffer 1): no prefetch ----
        const int cur = 28672;

        asm volatile("s_waitcnt vmcnt(4)" ::: "memory");
        __builtin_amdgcn_s_barrier();
#pragma unroll
        for (int mt = 0; mt < 4; ++mt)
            ah[mt] = fragr(smem + cur, wm + mt * 16 + fr, qsw);
#pragma unroll
        for (int nt = 0; nt < 4; ++nt)
            bh[nt] = fragr(smem + cur + 16384, wn + nt * 16 + fr, qsw);
        __builtin_amdgcn_s_setprio(1);
#pragma unroll
        for (int nt = 0; nt < 4; ++nt)
#pragma unroll
            for (int mt = 0; mt < 4; ++mt)
                accY[mt][nt] = __builtin_amdgcn_mfma_f32_16x16x32_bf16(ah[mt], bh[nt], accY[mt][nt], 0, 0, 0);
        __builtin_amdgcn_s_setprio(0);

        asm volatile("s_waitcnt vmcnt(3)" ::: "memory");
        __builtin_amdgcn_s_barrier();
#pragma unroll
        for (int nt = 0; nt < 4; ++nt)
            bl[nt] = fragr(smem + cur + 20480, wn + nt * 16 + fr, qsw);
        __builtin_amdgcn_s_setprio(1);
#pragma unroll
        for (int nt = 0; nt < 4; ++nt)
#pragma unroll
            for (int mt = 0; mt < 4; ++mt)
                accY[mt][nt] = __builtin_amdgcn_mfma_f32_16x16x32_bf16(ah[mt], bl[nt], accY[mt][nt], 0, 0, 0);
        __builtin_amdgcn_s_setprio(0);

        asm volatile("s_waitcnt vmcnt(0)" ::: "memory");
        __builtin_amdgcn_s_barrier();
#pragma unroll
        for (int nt = 0; nt < 4; ++nt)
            bv[nt] = fragr(smem + cur + 24576, wn + nt * 16 + fr, qsw);
        __builtin_amdgcn_s_setprio(1);
#pragma unroll
        for (int nt = 0; nt < 4; ++nt)
#pragma unroll
            for (int mt = 0; mt < 4; ++mt)
                accV[mt][nt] = __builtin_amdgcn_mfma_f32_16x16x32_bf16(ah[mt], bv[nt], accV[mt][nt], 0, 0, 0);
        __builtin_amdgcn_s_setprio(0);

        // Al already drained (older than BVh) and LDS valid after the barrier
#pragma unroll
        for (int mt = 0; mt < 4; ++mt)
            al[mt] = fragr(smem + cur + 8192, wm + mt * 16 + fr, qsw);
        __builtin_amdgcn_s_setprio(1);
#pragma unroll
        for (int nt = 0; nt < 4; ++nt)
#pragma unroll
            for (int mt = 0; mt < 4; ++mt)
                accY[mt][nt] = __builtin_amdgcn_mfma_f32_16x16x32_bf16(al[mt], bh[nt], accY[mt][nt], 0, 0, 0);
        __builtin_amdgcn_s_setprio(0);
    }

    const int col = lane & 15, rq = lane >> 4;
    // Y epilogue (hi/lo split)
#pragma unroll
    for (int mt = 0; mt < 4; ++mt)
#pragma unroll
        for (int nt = 0; nt < 4; ++nt)
#pragma unroll
            for (int e = 0; e < 4; ++e) {
                const int m = m0 + wm + mt * 16 + rq * 4 + e;
                const int n = n0 + wn + nt * 16 + col;
                const float v = accY[mt][nt][e];
                const unsigned short h = f2b(v);
                Yhi[(size_t)m * DIM + n] = h;
                Ylo[(size_t)m * DIM + n] = f2b(v - b2f(h));
            }
    // V epilogue: write transposed, Vt[b][n][s], 4 consecutive s per ushort4
#pragma unroll
    for (int mt = 0; mt < 4; ++mt)
#pragma unroll
        for (int nt = 0; nt < 4; ++nt) {
            const int m = m0 + wm + mt * 16 + rq * 4;      // 4-aligned
            const int bb = m >> 11, sr = m & (SEQ - 1);
            const int n = n0 + wn + nt * 16 + col;
            ushort4 pk;
            pk.x = f2b(accV[mt][nt][0]);
            pk.y = f2b(accV[mt][nt][1]);
            pk.z = f2b(accV[mt][nt][2]);
            pk.w = f2b(accV[mt][nt][3]);
            *(ushort4*)(Vt + (size_t)bb * DIM * SEQ + (size_t)n * SEQ + sr) = pk;
        }
}

// ---------------------------------------------------------------------------
// s_gemm256: S[b] = (Y[b] . X[b]^T) * 1/32, masked to -inf. fp32 output.
// 256x256 tile, BK=32, 512 threads (8 waves, 2Mx4N, 128x64 per wave).
// 6-PHASE term schedule, 16-MFMA clusters, counted vmcnt (T3+T4+T5).
// XCD-aware bijective block swizzle (T1): grid (8,8,4) = 256 blocks, q=32.
// ---------------------------------------------------------------------------
__global__ __launch_bounds__(512, 2) void s_gemm256_kernel(
    const unsigned short* __restrict__ Yhi, const unsigned short* __restrict__ Ylo,
    const unsigned short* __restrict__ Xhi, const unsigned short* __restrict__ Xlo,
    const unsigned long long* __restrict__ Mb, float* __restrict__ Sc)
{
    extern __shared__ unsigned short smem[];
    // layout (ushort offsets): buffer c at c*32768:
    //   Ah = +0, Al = +8192, Bh = +16384, Bl = +24576   (each 256x32)

    const int tid = threadIdx.x;
    const int w = tid >> 6, lane = tid & 63;
    const int wm = (w >> 2) * 128, wn = (w & 3) * 64;

    const int flat = blockIdx.x + (blockIdx.y << 3) + (blockIdx.z << 6);
    const int lid  = ((flat & 7) << 5) | (flat >> 3);     // bijective, nwg=256
    const int m0 = ((lid >> 3) & 7) * 256, n0 = (lid & 7) * 256;
    const int b  = lid >> 6;

    const unsigned short* __restrict__ Ahg = Yhi + (size_t)b * SEQ * DIM;
    const unsigned short* __restrict__ Alg = Ylo + (size_t)b * SEQ * DIM;
    const unsigned short* __restrict__ Bhg = Xhi + (size_t)b * SEQ * DIM;
    const unsigned short* __restrict__ Blg = Xlo + (size_t)b * SEQ * DIM;
    float* __restrict__ Sb = Sc + (size_t)b * SEQ * SEQ;

    f32x4 acc[8][4];
#pragma unroll
    for (int i = 0; i < 8; ++i)
#pragma unroll
        for (int j = 0; j < 4; ++j) acc[i][j] = (f32x4){0.f, 0.f, 0.f, 0.f};

    const int fr = lane & 15, quad = lane >> 4;
    const int qsw = quad ^ ((fr >> 2) & 3);

    // prologue: issue K-step 0 into buffer 0 in phase-consumption order.
    stage_async(Ahg, DIM, m0, 0, smem + 0,     tid);
    stage_async(Bhg, DIM, n0, 0, smem + 16384, tid);
    stage_async(Blg, DIM, n0, 0, smem + 24576, tid);
    stage_async(Alg, DIM, m0, 0, smem + 8192,  tid);

    for (int it = 0; it < DIM / 32 - 1; ++it) {
        const int cur = (it & 1) * 32768;
        const int nxt = cur ^ 32768;
        const unsigned short* Ah = smem + cur;
        const unsigned short* Al = smem + cur + 8192;
        const unsigned short* Bh = smem + cur + 16384;
        const unsigned short* Bl = smem + cur + 24576;
        const int k1 = it * 32 + 32;

        bf16x8 ah[8], al[8], bh[4], bl[4];

        // ---- ph0a (hh, m-half 0) ----
        stage_async(Ahg, DIM, m0, k1, smem + nxt, tid);
        asm volatile("s_waitcnt vmcnt(6)" ::: "memory");
        __builtin_amdgcn_s_barrier();
#pragma unroll
        for (int mt = 0; mt < 4; ++mt)
            ah[mt] = fragr(Ah, wm + mt * 16 + fr, qsw);
#pragma unroll
        for (int nt = 0; nt < 4; ++nt)
            bh[nt] = fragr(Bh, wn + nt * 16 + fr, qsw);
        __builtin_amdgcn_s_setprio(1);
#pragma unroll
        for (int nt = 0; nt < 4; ++nt)
#pragma unroll
            for (int mt = 0; mt < 4; ++mt)
                acc[mt][nt] = __builtin_amdgcn_mfma_f32_16x16x32_bf16(ah[mt], bh[nt], acc[mt][nt], 0, 0, 0);
        __builtin_amdgcn_s_setprio(0);

        // ---- ph0b (hh, m-half 1) ----
        stage_async(Bhg, DIM, n0, k1, smem + nxt + 16384, tid);
#pragma unroll
        for (int mt = 4; mt < 8; ++mt)
            ah[mt] = fragr(Ah, wm + mt * 16 + fr, qsw);
        __builtin_amdgcn_s_setprio(1);
#pragma unroll
        for (int nt = 0; nt < 4; ++nt)
#pragma unroll
            for (int mt = 4; mt < 8; ++mt)
                acc[mt][nt] = __builtin_amdgcn_mfma_f32_16x16x32_bf16(ah[mt], bh[nt], acc[mt][nt], 0, 0, 0);
        __builtin_amdgcn_s_setprio(0);

        // ---- ph1a (hl, m-half 0) ----
        stage_async(Blg, DIM, n0, k1, smem + nxt + 24576, tid);
        asm volatile("s_waitcnt vmcnt(8)" ::: "memory");
        __builtin_amdgcn_s_barrier();
#pragma unroll
        for (int nt = 0; nt < 4; ++nt)
            bl[nt] = fragr(Bl, wn + nt * 16 + fr, qsw);
        __builtin_amdgcn_s_setprio(1);
#pragma unroll
        for (int nt = 0; nt < 4; ++nt)
#pragma unroll
            for (int mt = 0; mt < 4; ++mt)
                acc[mt][nt] = __builtin_amdgcn_mfma_f32_16x16x32_bf16(ah[mt], bl[nt], acc[mt][nt], 0, 0, 0);
        __builtin_amdgcn_s_setprio(0);

        // ---- ph1b (hl, m-half 1) ----
        __builtin_amdgcn_s_setprio(1);
#pragma unroll
        for (int nt = 0; nt < 4; ++nt)
#pragma unroll
            for (int mt = 4; mt < 8; ++mt)
                acc[mt][nt] = __builtin_amdgcn_mfma_f32_16x16x32_bf16(ah[mt], bl[nt], acc[mt][nt], 0, 0, 0);
        __builtin_amdgcn_s_setprio(0);

        // ---- ph2a (lh, m-half 0) ----
        stage_async(Alg, DIM, m0, k1, smem + nxt + 8192, tid);
        asm volatile("s_waitcnt vmcnt(8)" ::: "memory");
        __builtin_amdgcn_s_barrier();
#pragma unroll
        for (int mt = 0; mt < 4; ++mt)
            al[mt] = fragr(Al, wm + mt * 16 + fr, qsw);
        __builtin_amdgcn_s_setprio(1);
#pragma unroll
        for (int nt = 0; nt < 4; ++nt)
#pragma unroll
            for (int mt = 0; mt < 4; ++mt)
                acc[mt][nt] = __builtin_amdgcn_mfma_f32_16x16x32_bf16(al[mt], bh[nt], acc[mt][nt], 0, 0, 0);
        __builtin_amdgcn_s_setprio(0);

        // ---- ph2b (lh, m-half 1) ----
#pragma unroll
        for (int mt = 4; mt < 8; ++mt)
            al[mt] = fragr(Al, wm + mt * 16 + fr, qsw);
        __builtin_amdgcn_s_setprio(1);
#pragma unroll
        for (int nt = 0; nt < 4; ++nt)
#pragma unroll
            for (int mt = 4; mt < 8; ++mt)
                acc[mt][nt] = __builtin_amdgcn_mfma_f32_16x16x32_bf16(al[mt], bh[nt], acc[mt][nt], 0, 0, 0);
        __builtin_amdgcn_s_setprio(0);
    }

    {   // ---- peeled last K-step (cur = buffer 1): no prefetch ----
        const unsigned short* Ah = smem + 32768;
        const unsigned short* Al = smem + 32768 + 8192;
        const unsigned short* Bh = smem + 32768 + 16384;
        const unsigned short* Bl = smem + 32768 + 24576;

        bf16x8 ah[8], al[8], bh[4], bl[4];

        asm volatile("s_waitcnt vmcnt(4)" ::: "memory");
        __builtin_amdgcn_s_barrier();
#pragma unroll
        for (int mt = 0; mt < 8; ++mt)
            ah[mt] = fragr(Ah, wm + mt * 16 + fr, qsw);
#pragma unroll
        for (int nt = 0; nt < 4; ++nt)
            bh[nt] = fragr(Bh, wn + nt * 16 + fr, qsw);
        __builtin_amdgcn_s_setprio(1);
#pragma unroll
        for (int nt = 0; nt < 4; ++nt)
#pragma unroll
            for (int mt = 0; mt < 8; ++mt)
                acc[mt][nt] = __builtin_amdgcn_mfma_f32_16x16x32_bf16(ah[mt], bh[nt], acc[mt][nt], 0, 0, 0);
        __builtin_amdgcn_s_setprio(0);

        asm volatile("s_waitcnt vmcnt(2)" ::: "memory");
        __builtin_amdgcn_s_barrier();
#pragma unroll
        for (int nt = 0; nt < 4; ++nt)
            bl[nt] = fragr(Bl, wn + nt * 16 + fr, qsw);
        __builtin_amdgcn_s_setprio(1);
#pragma unroll
        for (int nt = 0; nt < 4; ++nt)
#pragma unroll
            for (int mt = 0; mt < 8; ++mt)
                acc[mt][nt] = __builtin_amdgcn_mfma_f32_16x16x32_bf16(ah[mt], bl[nt], acc[mt][nt], 0, 0, 0);
        __builtin_amdgcn_s_setprio(0);

        asm volatile("s_waitcnt vmcnt(0)" ::: "memory");
        __builtin_amdgcn_s_barrier();
#pragma unroll
        for (int mt = 0; mt < 8; ++mt)
            al[mt] = fragr(Al, wm + mt * 16 + fr, qsw);
        __builtin_amdgcn_s_setprio(1);
#pragma unroll
        for (int nt = 0; nt < 4; ++nt)
#pragma unroll
            for (int mt = 0; mt < 8; ++mt)
                acc[mt][nt] = __builtin_amdgcn_mfma_f32_16x16x32_bf16(al[mt], bh[nt], acc[mt][nt], 0, 0, 0);
        __builtin_amdgcn_s_setprio(0);
    }

    const int col = lane & 15, rq = lane >> 4;
    const int wword = (n0 + wn) >> 6;             // one u64 covers nt*16+col
#pragma unroll
    for (int mt = 0; mt < 8; ++mt)
#pragma unroll
        for (int e = 0; e < 4; ++e) {
            const int m = m0 + wm + mt * 16 + rq * 4 + e;
            const unsigned long long word = Mb[(size_t)m * (SEQ / 64) + wword];
#pragma unroll
            for (int nt = 0; nt < 4; ++nt) {
                const int n = n0 + wn + nt * 16 + col;
                const float v = acc[mt][nt][e] * 0.03125f;
                const bool msk = (word >> (nt * 16 + col)) & 1ull;
                Sb[(size_t)m * SEQ + n] = msk ? -INFINITY : v;
            }
        }
}

// ---------------------------------------------------------------------------
// Row softmax on pre-masked, pre-scaled fp32 S; writes bf16 P in place
// (row r -> first 2048 ushorts of the row's 16 KB).
// ---------------------------------------------------------------------------
__global__ __launch_bounds__(256) void softmax_kernel(float* __restrict__ Sc)
{
    const int r = blockIdx.x;          // b*2048 + m
    float* __restrict__ row = Sc + (size_t)r * SEQ;

    const int tid  = threadIdx.x;
    const int lane = tid & 63;
    const int wid  = tid >> 6;

    float x[8];
    float mx = -INFINITY;
#pragma unroll
    for (int j = 0; j < 8; ++j) {
        x[j] = row[tid + j * 256];
        mx = fmaxf(mx, x[j]);
    }
    __shared__ float redm[4];
#pragma unroll
    for (int off = 32; off > 0; off >>= 1)
        mx = fmaxf(mx, __shfl_down(mx, off, 64));
    if (lane == 0) redm[wid] = mx;
    __syncthreads();
    mx = fmaxf(fmaxf(redm[0], redm[1]), fmaxf(redm[2], redm[3]));

    float sum = 0.f;
#pragma unroll
    for (int j = 0; j < 8; ++j) {
        const float e = __expf(x[j] - mx);
        x[j] = e;
        sum += e;
    }
    __shared__ float reds[4];
#pragma unroll
    for (int off = 32; off > 0; off >>= 1)
        sum += __shfl_down(sum, off, 64);
    if (lane == 0) reds[wid] = sum;
    __syncthreads();
    sum = (reds[0] + reds[1]) + (reds[2] + reds[3]);

    const float inv = 1.0f / sum;
    unsigned short* __restrict__ prow = (unsigned short*)row;
#pragma unroll
    for (int j = 0; j < 8; ++j)
        prow[tid + j * 256] = f2b(x[j] * inv);
}

// ---------------------------------------------------------------------------
// O[b] = P[b] @ V[b]: single bf16 MFMA, double-buffered BK=32 with counted
// vmcnt. XCD-aware bijective block swizzle (T1): grid (8,16,4)=512, q=64.
// A = P rows (stride 4096 ushorts), B = Vt rows (n-major, k contiguous).
// ---------------------------------------------------------------------------
__global__ __launch_bounds__(256) void pv_mfma_kernel(
    const unsigned short* __restrict__ P, const unsigned short* __restrict__ Vt,
    float* __restrict__ O)
{
    __shared__ unsigned short As[2][128 * 32], Bs[2][128 * 32];

    const int tid = threadIdx.x;
    const int w = tid >> 6, lane = tid & 63;
    const int wm = (w >> 1) * 64, wn = (w & 1) * 64;

    const int flat = blockIdx.x + (blockIdx.y << 3) + (blockIdx.z << 7);
    const int lid  = ((flat & 7) << 6) | (flat >> 3);     // bijective, nwg=512
    const int m0 = ((lid >> 3) & 15) * 128, n0 = (lid & 7) * 128;
    const int b  = lid >> 7;

    const unsigned short* __restrict__ Ag = P + (size_t)b * SEQ * (2 * SEQ);
    const unsigned short* __restrict__ Bg = Vt + (size_t)b * DIM * SEQ;
    float* __restrict__ Ob = O + (size_t)b * SEQ * DIM;

    f32x4 acc[4][4];
#pragma unroll
    for (int i = 0; i < 4; ++i)
#pragma unroll
        for (int j = 0; j < 4; ++j) acc[i][j] = (f32x4){0.f, 0.f, 0.f, 0.f};

    const int fr = lane & 15, quad = lane >> 4;
    const int qsw = quad ^ ((fr >> 2) & 3);

    // prologue: stage K-step 0 into buffer 0
    stage_async(Ag, 2 * SEQ, m0, 0, As[0], tid);
    stage_async(Bg, SEQ,     n0, 0, Bs[0], tid);

    for (int it = 0; it < SEQ / 32 - 1; ++it) {
        const int cur = it & 1, nxt = cur ^ 1;
        const int k1 = it * 32 + 32;

        // prefetch next K-step, then wait only for the previous one
        stage_async(Ag, 2 * SEQ, m0, k1, As[nxt], tid);
        stage_async(Bg, SEQ,     n0, k1, Bs[nxt], tid);
        asm volatile("s_waitcnt vmcnt(4)" ::: "memory");
        __builtin_amdgcn_s_barrier();

        bf16x8 af[4];
#pragma unroll
        for (int mt = 0; mt < 4; ++mt)
            af[mt] = fragr(As[cur], wm + mt * 16 + fr, qsw);
        __builtin_amdgcn_s_setprio(1);
#pragma unroll
        for (int nt = 0; nt < 4; ++nt) {
            const bf16x8 bfg = fragr(Bs[cur], wn + nt * 16 + fr, qsw);
#pragma unroll
            for (int mt = 0; mt < 4; ++mt)
                acc[mt][nt] = __builtin_amdgcn_mfma_f32_16x16x32_bf16(af[mt], bfg, acc[mt][nt], 0, 0, 0);
        }
        __builtin_amdgcn_s_setprio(0);
        __builtin_amdgcn_s_barrier();   // guard cur slot against next prefetch
    }

    {   // peeled last K-step (cur = buffer 1)
        asm volatile("s_waitcnt vmcnt(0)" ::: "memory");
        __builtin_amdgcn_s_barrier();
        bf16x8 af[4];
#pragma unroll
        for (int mt = 0; mt < 4; ++mt)
            af[mt] = fragr(As[1], wm + mt * 16 + fr, qsw);
        __builtin_amdgcn_s_setprio(1);
#pragma unroll
        for (int nt = 0; nt < 4; ++nt) {
            const bf16x8 bfg = fragr(Bs[1], wn + nt * 16 + fr, qsw);
#pragma unroll
            for (int mt = 0; mt < 4; ++mt)
                acc[mt][nt] = __builtin_amdgcn_mfma_f32_16x16x32_bf16(af[mt], bfg, acc[mt][nt], 0, 0, 0);
        }
        __builtin_amdgcn_s_setprio(0);
    }

    const int col = lane & 15, rq = lane >> 4;
#pragma unroll
    for (int mt = 0; mt < 4; ++mt)
#pragma unroll
        for (int nt = 0; nt < 4; ++nt)
#pragma unroll
            for (int e = 0; e < 4; ++e) {
                const int m = m0 + wm + mt * 16 + rq * 4 + e;
                const int n = n0 + wn + nt * 16 + col;
                Ob[(size_t)m * DIM + n] = acc[mt][nt][e];
            }
}

// ---------------------------------------------------------------------------
// Workspace layout (bytes), ws = 167 772 160:
//   Xhi/Xlo/Yhi/Ylo/Vt : 5 x 16 777 216   (bf16 [8192][1024]-sized each)
//   Mthi/Mtlo          : 2 x  2 097 152   (bf16 [1024][1024])
//   Sc                 : 67 108 864       (fp32 [4][2048][2048])
//   Mbits              :    524 288       (u64  [2048][32])       -> 155.7 MB
// Transients aliased INSIDE Sc (consumed before s_gemm writes Sc):
//   Whi/Wlo (2x4.2 MB) + WvT (2.1 MB) + Mtp (4x4.2 MB fp32) = 27.3 MB
// P (bf16) written in place into Sc rows (row r at ushort offset r*4096).
// ---------------------------------------------------------------------------
extern "C" void kernel_launch(void* const* d_in, const int* in_sizes, int n_in,
                              void* d_out, int out_size, void* d_ws, size_t ws_size,
                              hipStream_t stream)
{
    const float* x    = (const float*)d_in[0];
    const int*   mask = (const int*)d_in[1];
    const float* wq   = (const float*)d_in[2];
    const float* wk   = (const float*)d_in[3];
    const float* wv   = (const float*)d_in[4];
    float* out = (float*)d_out;

    const size_t NQ = (size_t)BATCH * SEQ * DIM;     // 8 388 608
    const size_t NM = (size_t)DIM * DIM;             // 1 048 576
    unsigned short* Xhi  = (unsigned short*)d_ws;
    unsigned short* Xlo  = Xhi + NQ;
    unsigned short* Yhi  = Xlo + NQ;
    unsigned short* Ylo  = Yhi + NQ;
    unsigned short* Vt   = Ylo + NQ;
    unsigned short* Mthi = Vt + NQ;
    unsigned short* Mtlo = Mthi + NM;
    float* Sc = (float*)(Mtlo + NM);
    unsigned long long* Mb = (unsigned long long*)(Sc + (size_t)BATCH * SEQ * SEQ);

    unsigned short* Whi = (unsigned short*)Sc;       // transient aliases
    unsigned short* Wlo = Whi + 2 * NM;
    unsigned short* WvT = Wlo + 2 * NM;
    float* Mtp = (float*)(WvT + NM);

    // one-time: dynamic-LDS caps (128 KiB s_gemm, 112 KiB merged yv)
    static bool lds_attr_set = false;
    if (!lds_attr_set) {
        (void)hipFuncSetAttribute((const void*)s_gemm256_kernel,
                                  hipFuncAttributeMaxDynamicSharedMemorySize,
                                  131072);
        (void)hipFuncSetAttribute((const void*)yv_gemm_kernel,
                                  hipFuncAttributeMaxDynamicSharedMemorySize,
                                  114688);
        lds_attr_set = true;
    }

    // 1. X -> hi/lo bf16; mask -> bitmask
    convert_x_kernel<<<dim3(NQ / 4 / 256), 256, 0, stream>>>(x, Xhi, Xlo);
    mask_pack_kernel<<<dim3(SEQ), 256, 0, stream>>>(mask, Mb);
    // 2. Wq/Wk -> hi/lo bf16 (no transpose); Wv -> WvT hi bf16
    convert_wqk_kernel<<<dim3(NM / 4 / 256, 2), 256, 0, stream>>>(wq, wk, Whi, Wlo);
    convert_wv_kernel<<<dim3(32, 32), 256, 0, stream>>>(wv, WvT);
    // 3. Mt = Wk.Wq^T (K-split x4, fp32 partials), then reduce + hi/lo split
    m_gemm_kernel<<<dim3(8, 8, 4), 256, 0, stream>>>(Whi, Wlo, Mtp);
    m_reduce_kernel<<<dim3(NM / 4 / 256), 256, 0, stream>>>(Mtp, Mthi, Mtlo);
    // 4. MERGED: Y = X.Mt^T (3-term hi/lo) AND V = Xhi.WvT^T -> Vt[b][d][s]
    yv_gemm_kernel<<<dim3(DIM / 128, (BATCH * SEQ) / 256), 512, 114688, stream>>>(
        Xhi, Xlo, Mthi, Mtlo, WvT, Yhi, Ylo, Vt);
    // 5. S = masked, scaled Y.X^T per batch (fp32 scores), 256^2 6-phase
    s_gemm256_kernel<<<dim3(SEQ / 256, SEQ / 256, BATCH), 512, 131072, stream>>>(
        Yhi, Ylo, Xhi, Xlo, Mb, Sc);
    // 6. softmax; writes bf16 P in place
    softmax_kernel<<<dim3(BATCH * SEQ), 256, 0, stream>>>(Sc);
    // 7. O = P @ V (double-buffered, counted vmcnt)
    pv_mfma_kernel<<<dim3(DIM / 128, SEQ / 128, BATCH), 256, 0, stream>>>(
        (const unsigned short*)Sc, Vt, out);
}

// Round 8
// 351.983 us; speedup vs baseline: 1.1118x; 1.0066x over previous
//
#include <hip/hip_runtime.h>
#include <math.h>

static constexpr int BATCH = 4;
static constexpr int SEQ   = 2048;
static constexpr int DIM   = 1024;

typedef __attribute__((ext_vector_type(8))) short     bf16x8;  // MFMA A/B frag (4 VGPRs)
typedef __attribute__((ext_vector_type(4))) float     f32x4;   // MFMA C/D frag

// fp32 -> bf16 (RNE) and back, bit-exact helpers for hi/lo splitting
__device__ __forceinline__ unsigned short f2b(float v) {
    unsigned int u = __float_as_uint(v);
    u = u + 0x7fffu + ((u >> 16) & 1u);
    return (unsigned short)(u >> 16);
}
__device__ __forceinline__ float b2f(unsigned short h) {
    return __uint_as_float(((unsigned int)h) << 16);
}

// ---------------------------------------------------------------------------
// convert_x: fp32 -> (hi, lo) bf16, elementwise.
// ---------------------------------------------------------------------------
__global__ __launch_bounds__(256) void convert_x_kernel(
    const float* __restrict__ X, unsigned short* __restrict__ hi,
    unsigned short* __restrict__ lo)
{
    const int i = blockIdx.x * 256 + threadIdx.x;   // float4 index
    const float4 v = ((const float4*)X)[i];
    ushort4 h, l;
    h.x = f2b(v.x); l.x = f2b(v.x - b2f(h.x));
    h.y = f2b(v.y); l.y = f2b(v.y - b2f(h.y));
    h.z = f2b(v.z); l.z = f2b(v.z - b2f(h.z));
    h.w = f2b(v.w); l.w = f2b(v.w - b2f(h.w));
    ((ushort4*)hi)[i] = h;
    ((ushort4*)lo)[i] = l;
}

// ---------------------------------------------------------------------------
// convert_wqk: Wq (y=0) / Wk (y=1) fp32 -> hi/lo bf16, NO transpose.
// ---------------------------------------------------------------------------
__global__ __launch_bounds__(256) void convert_wqk_kernel(
    const float* __restrict__ Wq, const float* __restrict__ Wk,
    unsigned short* __restrict__ hi, unsigned short* __restrict__ lo)
{
    const int z = blockIdx.y;
    const float* __restrict__ W = z ? Wk : Wq;
    const int i = blockIdx.x * 256 + threadIdx.x;   // float4 index within matrix
    const int o = z * (DIM * DIM / 4) + i;
    const float4 v = ((const float4*)W)[i];
    ushort4 h, l;
    h.x = f2b(v.x); l.x = f2b(v.x - b2f(h.x));
    h.y = f2b(v.y); l.y = f2b(v.y - b2f(h.y));
    h.z = f2b(v.z); l.z = f2b(v.z - b2f(h.z));
    h.w = f2b(v.w); l.w = f2b(v.w - b2f(h.w));
    ((ushort4*)hi)[o] = h;
    ((ushort4*)lo)[o] = l;
}

// ---------------------------------------------------------------------------
// convert_wv: Wv[k][n] fp32 -> WvT[n][k] hi bf16 (V is single-term).
// ---------------------------------------------------------------------------
__global__ __launch_bounds__(256) void convert_wv_kernel(
    const float* __restrict__ W, unsigned short* __restrict__ WT)
{
    __shared__ float t[32][33];
    const int n0 = blockIdx.x * 32, k0 = blockIdx.y * 32;
    const int tx = threadIdx.x & 31, ty = threadIdx.x >> 5;  // ty: 0..7
#pragma unroll
    for (int i = 0; i < 4; ++i)
        t[ty + i * 8][tx] = W[(size_t)(k0 + ty + i * 8) * DIM + (n0 + tx)];
    __syncthreads();
#pragma unroll
    for (int i = 0; i < 4; ++i)
        WT[(size_t)(n0 + ty + i * 8) * DIM + (k0 + tx)] = f2b(t[tx][ty + i * 8]);
}

// ---------------------------------------------------------------------------
// mask_pack: int32 mask [2048][2048] -> bitmask [2048][32] u64 (bit=1: mask).
// ---------------------------------------------------------------------------
__global__ __launch_bounds__(256) void mask_pack_kernel(
    const int* __restrict__ mask, unsigned long long* __restrict__ Mb)
{
    const int row  = blockIdx.x;
    const int lane = threadIdx.x & 63, w = threadIdx.x >> 6;
#pragma unroll
    for (int c = w; c < SEQ / 64; c += 4) {
        const int v = mask[(size_t)row * SEQ + c * 64 + lane];
        const unsigned long long bits = __ballot(v != 0);
        if (lane == 0) Mb[(size_t)row * (SEQ / 64) + c] = bits;
    }
}

// ---------------------------------------------------------------------------
// Async staging of a (rows x 32)-elem bf16 tile via global_load_lds w=16.
// XOR-swizzled unpadded 64 B rows; wave-uniform LDS dest. stage_async stages
// 32 rows/wave (128 rows @256thr, 256 rows @512thr); stage128 stages
// 16 rows/wave (128 rows @512thr).
// ---------------------------------------------------------------------------
__device__ __forceinline__ void stage_async(
    const unsigned short* __restrict__ g, int gstride, int row0, int k0,
    unsigned short* lds, int tid)
{
    const int w = tid >> 6, lane = tid & 63;
    const int c = (lane & 3) ^ ((lane >> 4) & 3);   // global chunk this lane fetches
#pragma unroll
    for (int h = 0; h < 2; ++h) {
        const int row = 32 * w + 16 * h + (lane >> 2);
        const unsigned short* src = g + (size_t)(row0 + row) * gstride + k0 + 8 * c;
        unsigned short* dst = lds + (32 * w + 16 * h) * 32;   // wave-uniform
        __builtin_amdgcn_global_load_lds(
            (const __attribute__((address_space(1))) void*)src,
            (__attribute__((address_space(3))) void*)dst, 16, 0, 0);
    }
}

__device__ __forceinline__ void stage128(
    const unsigned short* __restrict__ g, int gstride, int row0, int k0,
    unsigned short* lds, int tid)
{
    const int w = tid >> 6, lane = tid & 63;
    const int c = (lane & 3) ^ ((lane >> 4) & 3);
    const int row = 16 * w + (lane >> 2);
    const unsigned short* src = g + (size_t)(row0 + row) * gstride + k0 + 8 * c;
    unsigned short* dst = lds + (16 * w) * 32;            // wave-uniform
    __builtin_amdgcn_global_load_lds(
        (const __attribute__((address_space(1))) void*)src,
        (__attribute__((address_space(3))) void*)dst, 16, 0, 0);
}

__device__ __forceinline__ bf16x8 fragr(const unsigned short* lds, int row, int qsw)
{
    return *(const bf16x8*)(lds + row * 32 + qsw * 8);
}

// ---------------------------------------------------------------------------
// m_gemm: Mt = Wk . Wq^T  (so Mt[j][i] = sum_o Wq[i][o] Wk[j][o]), 3-term
// split bf16, 128x128 tile, K-split over z (4 chunks of 256). fp32 partials.
// ---------------------------------------------------------------------------
__global__ __launch_bounds__(256) void m_gemm_kernel(
    const unsigned short* __restrict__ Whi, const unsigned short* __restrict__ Wlo,
    float* __restrict__ Mtp)
{
    __shared__ unsigned short Ah[128 * 32], Al[128 * 32];
    __shared__ unsigned short Bh[128 * 32], Bl[128 * 32];

    const int tid = threadIdx.x;
    const int w = tid >> 6, lane = tid & 63;
    const int wm = (w >> 1) * 64, wn = (w & 1) * 64;
    const int m0 = blockIdx.y * 128, n0 = blockIdx.x * 128;
    const int z = blockIdx.z;                        // K chunk

    const unsigned short* __restrict__ Ahg = Whi + (size_t)DIM * DIM;  // Wk hi
    const unsigned short* __restrict__ Alg = Wlo + (size_t)DIM * DIM;  // Wk lo
    const unsigned short* __restrict__ Bhg = Whi;                      // Wq hi
    const unsigned short* __restrict__ Blg = Wlo;                      // Wq lo
    float* __restrict__ Cp = Mtp + (size_t)z * DIM * DIM;

    f32x4 acc[4][4];
#pragma unroll
    for (int i = 0; i < 4; ++i)
#pragma unroll
        for (int j = 0; j < 4; ++j) acc[i][j] = (f32x4){0.f, 0.f, 0.f, 0.f};

    const int fr = lane & 15, quad = lane >> 4;
    const int qsw = quad ^ ((fr >> 2) & 3);

    for (int k0 = z * 256; k0 < z * 256 + 256; k0 += 32) {
        stage_async(Ahg, DIM, m0, k0, Ah, tid);
        stage_async(Alg, DIM, m0, k0, Al, tid);
        stage_async(Bhg, DIM, n0, k0, Bh, tid);
        stage_async(Blg, DIM, n0, k0, Bl, tid);
        __syncthreads();

        bf16x8 ah[4], al[4];
#pragma unroll
        for (int mt = 0; mt < 4; ++mt) {
            ah[mt] = fragr(Ah, wm + mt * 16 + fr, qsw);
            al[mt] = fragr(Al, wm + mt * 16 + fr, qsw);
        }
#pragma unroll
        for (int nt = 0; nt < 4; ++nt) {
            const bf16x8 bh = fragr(Bh, wn + nt * 16 + fr, qsw);
            const bf16x8 bl = fragr(Bl, wn + nt * 16 + fr, qsw);
#pragma unroll
            for (int mt = 0; mt < 4; ++mt) {
                acc[mt][nt] = __builtin_amdgcn_mfma_f32_16x16x32_bf16(ah[mt], bh, acc[mt][nt], 0, 0, 0);
                acc[mt][nt] = __builtin_amdgcn_mfma_f32_16x16x32_bf16(ah[mt], bl, acc[mt][nt], 0, 0, 0);
                acc[mt][nt] = __builtin_amdgcn_mfma_f32_16x16x32_bf16(al[mt], bh, acc[mt][nt], 0, 0, 0);
            }
        }
        __syncthreads();
    }

    const int col = lane & 15, rq = lane >> 4;
#pragma unroll
    for (int mt = 0; mt < 4; ++mt)
#pragma unroll
        for (int nt = 0; nt < 4; ++nt)
#pragma unroll
            for (int e = 0; e < 4; ++e) {
                const int m = m0 + wm + mt * 16 + rq * 4 + e;
                const int n = n0 + wn + nt * 16 + col;
                Cp[(size_t)m * DIM + n] = acc[mt][nt][e];
            }
}

// ---------------------------------------------------------------------------
// m_reduce: sum 4 K-split partials, split to hi/lo bf16.
// ---------------------------------------------------------------------------
__global__ __launch_bounds__(256) void m_reduce_kernel(
    const float* __restrict__ Mtp, unsigned short* __restrict__ Mthi,
    unsigned short* __restrict__ Mtlo)
{
    const int i = blockIdx.x * 256 + threadIdx.x;   // float4 index
    const size_t q = (size_t)DIM * DIM / 4;
    const float4 a = ((const float4*)Mtp)[i];
    const float4 b = ((const float4*)Mtp)[i + q];
    const float4 c = ((const float4*)Mtp)[i + 2 * q];
    const float4 d = ((const float4*)Mtp)[i + 3 * q];
    const float4 v = make_float4(a.x + b.x + c.x + d.x, a.y + b.y + c.y + d.y,
                                 a.z + b.z + c.z + d.z, a.w + b.w + c.w + d.w);
    ushort4 h, l;
    h.x = f2b(v.x); l.x = f2b(v.x - b2f(h.x));
    h.y = f2b(v.y); l.y = f2b(v.y - b2f(h.y));
    h.z = f2b(v.z); l.z = f2b(v.z - b2f(h.z));
    h.w = f2b(v.w); l.w = f2b(v.w - b2f(h.w));
    ((ushort4*)Mthi)[i] = h;
    ((ushort4*)Mtlo)[i] = l;
}

// ---------------------------------------------------------------------------
// yv_gemm (MERGED): one 256x128 tile computes BOTH
//   Y[m0:+256][n0:+128] = X @ Mt^T   (3-term hi/lo, fp32 acc)
//   V[m0:+256][n0:+128] = Xhi @ WvT^T (1-term, written transposed to Vt)
// 4-phase term schedule, 16-MFMA clusters, counted vmcnt. See round-6 notes.
// ---------------------------------------------------------------------------
__global__ __launch_bounds__(512, 2) void yv_gemm_kernel(
    const unsigned short* __restrict__ Xhi, const unsigned short* __restrict__ Xlo,
    const unsigned short* __restrict__ Mthi, const unsigned short* __restrict__ Mtlo,
    const unsigned short* __restrict__ WvT,
    unsigned short* __restrict__ Yhi, unsigned short* __restrict__ Ylo,
    unsigned short* __restrict__ Vt)
{
    extern __shared__ unsigned short smem[];
    // per-buffer ushort offsets: Ah=0, Al=8192, BYh=16384, BYl=20480, BVh=24576
    // buffer stride = 28672 ushorts (56 KiB)

    const int tid = threadIdx.x;
    const int w = tid >> 6, lane = tid & 63;
    const int wm = (w >> 1) * 64, wn = (w & 1) * 64;

    const int flat = blockIdx.x + (blockIdx.y << 3);   // grid (8, 32)
    const int xcd = flat & 7, s = flat >> 3;           // s: 0..31
    const int m0 = (xcd + ((s >> 3) << 3)) * 256;      // m-chunk == xcd (mod 8)
    const int n0 = (s & 7) * 128;

    f32x4 accY[4][4], accV[4][4];
#pragma unroll
    for (int i = 0; i < 4; ++i)
#pragma unroll
        for (int j = 0; j < 4; ++j) {
            accY[i][j] = (f32x4){0.f, 0.f, 0.f, 0.f};
            accV[i][j] = (f32x4){0.f, 0.f, 0.f, 0.f};
        }

    const int fr = lane & 15, quad = lane >> 4;
    const int qsw = quad ^ ((fr >> 2) & 3);

    // prologue: K-step 0 into buffer 0, steady-state issue order
    stage_async(Xhi, DIM, m0, 0, smem + 0,     tid);   // Ah x2
    stage128(Mthi, DIM, n0, 0, smem + 16384, tid);     // BYh
    stage128(Mtlo, DIM, n0, 0, smem + 20480, tid);     // BYl
    stage_async(Xlo, DIM, m0, 0, smem + 8192,  tid);   // Al x2
    stage128(WvT,  DIM, n0, 0, smem + 24576, tid);     // BVh

    bf16x8 ah[4], al[4], bh[4], bl[4], bv[4];

    for (int it = 0; it < DIM / 32 - 1; ++it) {
        const int cur = (it & 1) * 28672;
        const int nxt = 28672 - cur;
        const int k1 = it * 32 + 32;

        // ---- ph0: Y-hh ----
        stage_async(Xhi, DIM, m0, k1, smem + nxt, tid);
        asm volatile("s_waitcnt vmcnt(6)" ::: "memory");
        __builtin_amdgcn_s_barrier();
#pragma unroll
        for (int mt = 0; mt < 4; ++mt)
            ah[mt] = fragr(smem + cur, wm + mt * 16 + fr, qsw);
#pragma unroll
        for (int nt = 0; nt < 4; ++nt)
            bh[nt] = fragr(smem + cur + 16384, wn + nt * 16 + fr, qsw);
        __builtin_amdgcn_s_setprio(1);
#pragma unroll
        for (int nt = 0; nt < 4; ++nt)
#pragma unroll
            for (int mt = 0; mt < 4; ++mt)
                accY[mt][nt] = __builtin_amdgcn_mfma_f32_16x16x32_bf16(ah[mt], bh[nt], accY[mt][nt], 0, 0, 0);
        __builtin_amdgcn_s_setprio(0);

        // ---- ph1: Y-hl (ah held) ----
        stage128(Mthi, DIM, n0, k1, smem + nxt + 16384, tid);
        stage128(Mtlo, DIM, n0, k1, smem + nxt + 20480, tid);
        asm volatile("s_waitcnt vmcnt(7)" ::: "memory");
        __builtin_amdgcn_s_barrier();
#pragma unroll
        for (int nt = 0; nt < 4; ++nt)
            bl[nt] = fragr(smem + cur + 20480, wn + nt * 16 + fr, qsw);
        __builtin_amdgcn_s_setprio(1);
#pragma unroll
        for (int nt = 0; nt < 4; ++nt)
#pragma unroll
            for (int mt = 0; mt < 4; ++mt)
                accY[mt][nt] = __builtin_amdgcn_mfma_f32_16x16x32_bf16(ah[mt], bl[nt], accY[mt][nt], 0, 0, 0);
        __builtin_amdgcn_s_setprio(0);

        // ---- ph2: V-h (ah held) ----
        stage_async(Xlo, DIM, m0, k1, smem + nxt + 8192, tid);
        asm volatile("s_waitcnt vmcnt(6)" ::: "memory");
        __builtin_amdgcn_s_barrier();
#pragma unroll
        for (int nt = 0; nt < 4; ++nt)
            bv[nt] = fragr(smem + cur + 24576, wn + nt * 16 + fr, qsw);
        __builtin_amdgcn_s_setprio(1);
#pragma unroll
        for (int nt = 0; nt < 4; ++nt)
#pragma unroll
            for (int mt = 0; mt < 4; ++mt)
                accV[mt][nt] = __builtin_amdgcn_mfma_f32_16x16x32_bf16(ah[mt], bv[nt], accV[mt][nt], 0, 0, 0);
        __builtin_amdgcn_s_setprio(0);

        // ---- ph3: Y-lh (bh held) ----
        stage128(WvT, DIM, n0, k1, smem + nxt + 24576, tid);
        asm volatile("s_waitcnt vmcnt(8)" ::: "memory");
        __builtin_amdgcn_s_barrier();
#pragma unroll
        for (int mt = 0; mt < 4; ++mt)
            al[mt] = fragr(smem + cur + 8192, wm + mt * 16 + fr, qsw);
        __builtin_amdgcn_s_setprio(1);
#pragma unroll
        for (int nt = 0; nt < 4; ++nt)
#pragma unroll
            for (int mt = 0; mt < 4; ++mt)
                accY[mt][nt] = __builtin_amdgcn_mfma_f32_16x16x32_bf16(al[mt], bh[nt], accY[mt][nt], 0, 0, 0);
        __builtin_amdgcn_s_setprio(0);
    }

    {   // ---- peeled last K-step (cur = buffer 1): no prefetch ----
        const int cur = 28672;

        asm volatile("s_waitcnt vmcnt(4)" ::: "memory");
        __builtin_amdgcn_s_barrier();
#pragma unroll
        for (int mt = 0; mt < 4; ++mt)
            ah[mt] = fragr(smem + cur, wm + mt * 16 + fr, qsw);
#pragma unroll
        for (int nt = 0; nt < 4; ++nt)
            bh[nt] = fragr(smem + cur + 16384, wn + nt * 16 + fr, qsw);
        __builtin_amdgcn_s_setprio(1);
#pragma unroll
        for (int nt = 0; nt < 4; ++nt)
#pragma unroll
            for (int mt = 0; mt < 4; ++mt)
                accY[mt][nt] = __builtin_amdgcn_mfma_f32_16x16x32_bf16(ah[mt], bh[nt], accY[mt][nt], 0, 0, 0);
        __builtin_amdgcn_s_setprio(0);

        asm volatile("s_waitcnt vmcnt(3)" ::: "memory");
        __builtin_amdgcn_s_barrier();
#pragma unroll
        for (int nt = 0; nt < 4; ++nt)
            bl[nt] = fragr(smem + cur + 20480, wn + nt * 16 + fr, qsw);
        __builtin_amdgcn_s_setprio(1);
#pragma unroll
        for (int nt = 0; nt < 4; ++nt)
#pragma unroll
            for (int mt = 0; mt < 4; ++mt)
                accY[mt][nt] = __builtin_amdgcn_mfma_f32_16x16x32_bf16(ah[mt], bl[nt], accY[mt][nt], 0, 0, 0);
        __builtin_amdgcn_s_setprio(0);

        asm volatile("s_waitcnt vmcnt(0)" ::: "memory");
        __builtin_amdgcn_s_barrier();
#pragma unroll
        for (int nt = 0; nt < 4; ++nt)
            bv[nt] = fragr(smem + cur + 24576, wn + nt * 16 + fr, qsw);
        __builtin_amdgcn_s_setprio(1);
#pragma unroll
        for (int nt = 0; nt < 4; ++nt)
#pragma unroll
            for (int mt = 0; mt < 4; ++mt)
                accV[mt][nt] = __builtin_amdgcn_mfma_f32_16x16x32_bf16(ah[mt], bv[nt], accV[mt][nt], 0, 0, 0);
        __builtin_amdgcn_s_setprio(0);

        // Al already drained (older than BVh) and LDS valid after the barrier
#pragma unroll
        for (int mt = 0; mt < 4; ++mt)
            al[mt] = fragr(smem + cur + 8192, wm + mt * 16 + fr, qsw);
        __builtin_amdgcn_s_setprio(1);
#pragma unroll
        for (int nt = 0; nt < 4; ++nt)
#pragma unroll
            for (int mt = 0; mt < 4; ++mt)
                accY[mt][nt] = __builtin_amdgcn_mfma_f32_16x16x32_bf16(al[mt], bh[nt], accY[mt][nt], 0, 0, 0);
        __builtin_amdgcn_s_setprio(0);
    }

    const int col = lane & 15, rq = lane >> 4;
    // Y epilogue (hi/lo split)
#pragma unroll
    for (int mt = 0; mt < 4; ++mt)
#pragma unroll
        for (int nt = 0; nt < 4; ++nt)
#pragma unroll
            for (int e = 0; e < 4; ++e) {
                const int m = m0 + wm + mt * 16 + rq * 4 + e;
                const int n = n0 + wn + nt * 16 + col;
                const float v = accY[mt][nt][e];
                const unsigned short h = f2b(v);
                Yhi[(size_t)m * DIM + n] = h;
                Ylo[(size_t)m * DIM + n] = f2b(v - b2f(h));
            }
    // V epilogue: write transposed, Vt[b][n][s], 4 consecutive s per ushort4
#pragma unroll
    for (int mt = 0; mt < 4; ++mt)
#pragma unroll
        for (int nt = 0; nt < 4; ++nt) {
            const int m = m0 + wm + mt * 16 + rq * 4;      // 4-aligned
            const int bb = m >> 11, sr = m & (SEQ - 1);
            const int n = n0 + wn + nt * 16 + col;
            ushort4 pk;
            pk.x = f2b(accV[mt][nt][0]);
            pk.y = f2b(accV[mt][nt][1]);
            pk.z = f2b(accV[mt][nt][2]);
            pk.w = f2b(accV[mt][nt][3]);
            *(ushort4*)(Vt + (size_t)bb * DIM * SEQ + (size_t)n * SEQ + sr) = pk;
        }
}

// ---------------------------------------------------------------------------
// s_gemm256: S[b] = (Y[b] . X[b]^T) * 1/32, masked to -inf. fp32 output.
// 256x256 tile, BK=32, 512 threads (8 waves, 2Mx4N, 128x64 per wave).
// 6-PHASE term schedule, 16-MFMA clusters, counted vmcnt (T3+T4+T5).
// XCD-aware bijective block swizzle (T1): grid (8,8,4) = 256 blocks, q=32.
// ---------------------------------------------------------------------------
__global__ __launch_bounds__(512, 2) void s_gemm256_kernel(
    const unsigned short* __restrict__ Yhi, const unsigned short* __restrict__ Ylo,
    const unsigned short* __restrict__ Xhi, const unsigned short* __restrict__ Xlo,
    const unsigned long long* __restrict__ Mb, float* __restrict__ Sc)
{
    extern __shared__ unsigned short smem[];
    // layout (ushort offsets): buffer c at c*32768:
    //   Ah = +0, Al = +8192, Bh = +16384, Bl = +24576   (each 256x32)

    const int tid = threadIdx.x;
    const int w = tid >> 6, lane = tid & 63;
    const int wm = (w >> 2) * 128, wn = (w & 3) * 64;

    const int flat = blockIdx.x + (blockIdx.y << 3) + (blockIdx.z << 6);
    const int lid  = ((flat & 7) << 5) | (flat >> 3);     // bijective, nwg=256
    const int m0 = ((lid >> 3) & 7) * 256, n0 = (lid & 7) * 256;
    const int b  = lid >> 6;

    const unsigned short* __restrict__ Ahg = Yhi + (size_t)b * SEQ * DIM;
    const unsigned short* __restrict__ Alg = Ylo + (size_t)b * SEQ * DIM;
    const unsigned short* __restrict__ Bhg = Xhi + (size_t)b * SEQ * DIM;
    const unsigned short* __restrict__ Blg = Xlo + (size_t)b * SEQ * DIM;
    float* __restrict__ Sb = Sc + (size_t)b * SEQ * SEQ;

    f32x4 acc[8][4];
#pragma unroll
    for (int i = 0; i < 8; ++i)
#pragma unroll
        for (int j = 0; j < 4; ++j) acc[i][j] = (f32x4){0.f, 0.f, 0.f, 0.f};

    const int fr = lane & 15, quad = lane >> 4;
    const int qsw = quad ^ ((fr >> 2) & 3);

    // prologue: issue K-step 0 into buffer 0 in phase-consumption order.
    stage_async(Ahg, DIM, m0, 0, smem + 0,     tid);
    stage_async(Bhg, DIM, n0, 0, smem + 16384, tid);
    stage_async(Blg, DIM, n0, 0, smem + 24576, tid);
    stage_async(Alg, DIM, m0, 0, smem + 8192,  tid);

    for (int it = 0; it < DIM / 32 - 1; ++it) {
        const int cur = (it & 1) * 32768;
        const int nxt = cur ^ 32768;
        const unsigned short* Ah = smem + cur;
        const unsigned short* Al = smem + cur + 8192;
        const unsigned short* Bh = smem + cur + 16384;
        const unsigned short* Bl = smem + cur + 24576;
        const int k1 = it * 32 + 32;

        bf16x8 ah[8], al[8], bh[4], bl[4];

        // ---- ph0a (hh, m-half 0) ----
        stage_async(Ahg, DIM, m0, k1, smem + nxt, tid);
        asm volatile("s_waitcnt vmcnt(6)" ::: "memory");
        __builtin_amdgcn_s_barrier();
#pragma unroll
        for (int mt = 0; mt < 4; ++mt)
            ah[mt] = fragr(Ah, wm + mt * 16 + fr, qsw);
#pragma unroll
        for (int nt = 0; nt < 4; ++nt)
            bh[nt] = fragr(Bh, wn + nt * 16 + fr, qsw);
        __builtin_amdgcn_s_setprio(1);
#pragma unroll
        for (int nt = 0; nt < 4; ++nt)
#pragma unroll
            for (int mt = 0; mt < 4; ++mt)
                acc[mt][nt] = __builtin_amdgcn_mfma_f32_16x16x32_bf16(ah[mt], bh[nt], acc[mt][nt], 0, 0, 0);
        __builtin_amdgcn_s_setprio(0);

        // ---- ph0b (hh, m-half 1) ----
        stage_async(Bhg, DIM, n0, k1, smem + nxt + 16384, tid);
#pragma unroll
        for (int mt = 4; mt < 8; ++mt)
            ah[mt] = fragr(Ah, wm + mt * 16 + fr, qsw);
        __builtin_amdgcn_s_setprio(1);
#pragma unroll
        for (int nt = 0; nt < 4; ++nt)
#pragma unroll
            for (int mt = 4; mt < 8; ++mt)
                acc[mt][nt] = __builtin_amdgcn_mfma_f32_16x16x32_bf16(ah[mt], bh[nt], acc[mt][nt], 0, 0, 0);
        __builtin_amdgcn_s_setprio(0);

        // ---- ph1a (hl, m-half 0) ----
        stage_async(Blg, DIM, n0, k1, smem + nxt + 24576, tid);
        asm volatile("s_waitcnt vmcnt(8)" ::: "memory");
        __builtin_amdgcn_s_barrier();
#pragma unroll
        for (int nt = 0; nt < 4; ++nt)
            bl[nt] = fragr(Bl, wn + nt * 16 + fr, qsw);
        __builtin_amdgcn_s_setprio(1);
#pragma unroll
        for (int nt = 0; nt < 4; ++nt)
#pragma unroll
            for (int mt = 0; mt < 4; ++mt)
                acc[mt][nt] = __builtin_amdgcn_mfma_f32_16x16x32_bf16(ah[mt], bl[nt], acc[mt][nt], 0, 0, 0);
        __builtin_amdgcn_s_setprio(0);

        // ---- ph1b (hl, m-half 1) ----
        __builtin_amdgcn_s_setprio(1);
#pragma unroll
        for (int nt = 0; nt < 4; ++nt)
#pragma unroll
            for (int mt = 4; mt < 8; ++mt)
                acc[mt][nt] = __builtin_amdgcn_mfma_f32_16x16x32_bf16(ah[mt], bl[nt], acc[mt][nt], 0, 0, 0);
        __builtin_amdgcn_s_setprio(0);

        // ---- ph2a (lh, m-half 0) ----
        stage_async(Alg, DIM, m0, k1, smem + nxt + 8192, tid);
        asm volatile("s_waitcnt vmcnt(8)" ::: "memory");
        __builtin_amdgcn_s_barrier();
#pragma unroll
        for (int mt = 0; mt < 4; ++mt)
            al[mt] = fragr(Al, wm + mt * 16 + fr, qsw);
        __builtin_amdgcn_s_setprio(1);
#pragma unroll
        for (int nt = 0; nt < 4; ++nt)
#pragma unroll
            for (int mt = 0; mt < 4; ++mt)
                acc[mt][nt] = __builtin_amdgcn_mfma_f32_16x16x32_bf16(al[mt], bh[nt], acc[mt][nt], 0, 0, 0);
        __builtin_amdgcn_s_setprio(0);

        // ---- ph2b (lh, m-half 1) ----
#pragma unroll
        for (int mt = 4; mt < 8; ++mt)
            al[mt] = fragr(Al, wm + mt * 16 + fr, qsw);
        __builtin_amdgcn_s_setprio(1);
#pragma unroll
        for (int nt = 0; nt < 4; ++nt)
#pragma unroll
            for (int mt = 4; mt < 8; ++mt)
                acc[mt][nt] = __builtin_amdgcn_mfma_f32_16x16x32_bf16(al[mt], bh[nt], acc[mt][nt], 0, 0, 0);
        __builtin_amdgcn_s_setprio(0);
    }

    {   // ---- peeled last K-step (cur = buffer 1): no prefetch ----
        const unsigned short* Ah = smem + 32768;
        const unsigned short* Al = smem + 32768 + 8192;
        const unsigned short* Bh = smem + 32768 + 16384;
        const unsigned short* Bl = smem + 32768 + 24576;

        bf16x8 ah[8], al[8], bh[4], bl[4];

        asm volatile("s_waitcnt vmcnt(4)" ::: "memory");
        __builtin_amdgcn_s_barrier();
#pragma unroll
        for (int mt = 0; mt < 8; ++mt)
            ah[mt] = fragr(Ah, wm + mt * 16 + fr, qsw);
#pragma unroll
        for (int nt = 0; nt < 4; ++nt)
            bh[nt] = fragr(Bh, wn + nt * 16 + fr, qsw);
        __builtin_amdgcn_s_setprio(1);
#pragma unroll
        for (int nt = 0; nt < 4; ++nt)
#pragma unroll
            for (int mt = 0; mt < 8; ++mt)
                acc[mt][nt] = __builtin_amdgcn_mfma_f32_16x16x32_bf16(ah[mt], bh[nt], acc[mt][nt], 0, 0, 0);
        __builtin_amdgcn_s_setprio(0);

        asm volatile("s_waitcnt vmcnt(2)" ::: "memory");
        __builtin_amdgcn_s_barrier();
#pragma unroll
        for (int nt = 0; nt < 4; ++nt)
            bl[nt] = fragr(Bl, wn + nt * 16 + fr, qsw);
        __builtin_amdgcn_s_setprio(1);
#pragma unroll
        for (int nt = 0; nt < 4; ++nt)
#pragma unroll
            for (int mt = 0; mt < 8; ++mt)
                acc[mt][nt] = __builtin_amdgcn_mfma_f32_16x16x32_bf16(ah[mt], bl[nt], acc[mt][nt], 0, 0, 0);
        __builtin_amdgcn_s_setprio(0);

        asm volatile("s_waitcnt vmcnt(0)" ::: "memory");
        __builtin_amdgcn_s_barrier();
#pragma unroll
        for (int mt = 0; mt < 8; ++mt)
            al[mt] = fragr(Al, wm + mt * 16 + fr, qsw);
        __builtin_amdgcn_s_setprio(1);
#pragma unroll
        for (int nt = 0; nt < 4; ++nt)
#pragma unroll
            for (int mt = 0; mt < 8; ++mt)
                acc[mt][nt] = __builtin_amdgcn_mfma_f32_16x16x32_bf16(al[mt], bh[nt], acc[mt][nt], 0, 0, 0);
        __builtin_amdgcn_s_setprio(0);
    }

    const int col = lane & 15, rq = lane >> 4;
    const int wword = (n0 + wn) >> 6;             // one u64 covers nt*16+col
#pragma unroll
    for (int mt = 0; mt < 8; ++mt)
#pragma unroll
        for (int e = 0; e < 4; ++e) {
            const int m = m0 + wm + mt * 16 + rq * 4 + e;
            const unsigned long long word = Mb[(size_t)m * (SEQ / 64) + wword];
#pragma unroll
            for (int nt = 0; nt < 4; ++nt) {
                const int n = n0 + wn + nt * 16 + col;
                const float v = acc[mt][nt][e] * 0.03125f;
                const bool msk = (word >> (nt * 16 + col)) & 1ull;
                Sb[(size_t)m * SEQ + n] = msk ? -INFINITY : v;
            }
        }
}

// ---------------------------------------------------------------------------
// Row softmax on pre-masked, pre-scaled fp32 S; writes bf16 P in place.
// VECTORIZED: 2x float4 loads + one 16B bf16x8 store per thread. Safe:
// all reads complete before the first __syncthreads; all writes after the
// second; write range (floats 0..1023) never overlaps another thread's
// pre-sync read window.
// ---------------------------------------------------------------------------
__global__ __launch_bounds__(256) void softmax_kernel(float* __restrict__ Sc)
{
    const int r = blockIdx.x;          // b*2048 + m
    float* __restrict__ row = Sc + (size_t)r * SEQ;

    const int tid  = threadIdx.x;
    const int lane = tid & 63;
    const int wid  = tid >> 6;

    const float4 v0 = ((const float4*)row)[2 * tid];
    const float4 v1 = ((const float4*)row)[2 * tid + 1];
    float x[8] = {v0.x, v0.y, v0.z, v0.w, v1.x, v1.y, v1.z, v1.w};

    float mx = -INFINITY;
#pragma unroll
    for (int j = 0; j < 8; ++j) mx = fmaxf(mx, x[j]);
    __shared__ float redm[4];
#pragma unroll
    for (int off = 32; off > 0; off >>= 1)
        mx = fmaxf(mx, __shfl_down(mx, off, 64));
    if (lane == 0) redm[wid] = mx;
    __syncthreads();
    mx = fmaxf(fmaxf(redm[0], redm[1]), fmaxf(redm[2], redm[3]));

    float sum = 0.f;
#pragma unroll
    for (int j = 0; j < 8; ++j) {
        const float e = __expf(x[j] - mx);
        x[j] = e;
        sum += e;
    }
    __shared__ float reds[4];
#pragma unroll
    for (int off = 32; off > 0; off >>= 1)
        sum += __shfl_down(sum, off, 64);
    if (lane == 0) reds[wid] = sum;
    __syncthreads();
    sum = (reds[0] + reds[1]) + (reds[2] + reds[3]);

    const float inv = 1.0f / sum;
    unsigned short* __restrict__ prow = (unsigned short*)row;
    bf16x8 pk;
#pragma unroll
    for (int j = 0; j < 8; ++j)
        pk[j] = (short)f2b(x[j] * inv);
    *(bf16x8*)(prow + 8 * tid) = pk;
}

// ---------------------------------------------------------------------------
// O[b] = P[b] @ V[b] (round 8, race-fixed): 256x128 tile, 512 threads
// (8 waves 4Mx2N, 64x64 each). TRIPLE-buffered BK=32, ONE barrier per iter:
//   iter it: stage buf[(it+1)%3] (3 loads) -> vmcnt(3) -> barrier ->
//            ds_read buf[it%3] -> 16 MFMA.
// Slot-reuse safety: write-issue into buf b happens at iter b+2, which is
// AFTER barrier_{b+1}; every wave passes barrier_{b+1} only after its
// iter-b ds_reads completed (ds_read -> lgkmcnt-gated MFMA -> barrier in
// program order). Round-7's double-buffer had NO barrier between last read
// and next write-issue -> race (absmax 192). LDS 72 KiB -> 2 blocks/CU.
// XCD z-grouped swizzle: the 8 n-blocks sharing an m-panel on one XCD.
// A = P rows (stride 4096 ushorts), B = Vt rows (n-major, k contiguous).
// ---------------------------------------------------------------------------
__global__ __launch_bounds__(512, 2) void pv_mfma_kernel(
    const unsigned short* __restrict__ P, const unsigned short* __restrict__ Vt,
    float* __restrict__ O)
{
    __shared__ unsigned short As[3][256 * 32], Bs[3][128 * 32];  // 72 KiB

    const int tid = threadIdx.x;
    const int w = tid >> 6, lane = tid & 63;
    const int wm = (w >> 1) * 64, wn = (w & 1) * 64;

    // grid (8, 8, 4) = 256 blocks; m-chunk c == xcd (mod 8)
    const int flat = blockIdx.x + (blockIdx.y << 3) + (blockIdx.z << 6);
    const int xcd = flat & 7, s = flat >> 3;          // s: 0..31
    const int c  = xcd + ((s >> 3) << 3);             // m-chunk 0..31
    const int n0 = (s & 7) * 128;
    const int m0 = (c & 7) * 256;
    const int b  = c >> 3;

    const unsigned short* __restrict__ Ag = P + (size_t)b * SEQ * (2 * SEQ);
    const unsigned short* __restrict__ Bg = Vt + (size_t)b * DIM * SEQ;
    float* __restrict__ Ob = O + (size_t)b * SEQ * DIM;

    f32x4 acc[4][4];
#pragma unroll
    for (int i = 0; i < 4; ++i)
#pragma unroll
        for (int j = 0; j < 4; ++j) acc[i][j] = (f32x4){0.f, 0.f, 0.f, 0.f};

    const int fr = lane & 15, quad = lane >> 4;
    const int qsw = quad ^ ((fr >> 2) & 3);

    // prologue: stage K-step 0 into buffer 0 (3 loads/thread outstanding)
    stage_async(Ag, 2 * SEQ, m0, 0, As[0], tid);
    stage128 (Bg, SEQ,      n0, 0, Bs[0], tid);

    for (int it = 0; it < SEQ / 32 - 1; ++it) {
        const int cur = it % 3, nxt = (it + 1) % 3;
        const int k1 = it * 32 + 32;

        stage_async(Ag, 2 * SEQ, m0, k1, As[nxt], tid);
        stage128 (Bg, SEQ,      n0, k1, Bs[nxt], tid);
        asm volatile("s_waitcnt vmcnt(3)" ::: "memory");
        __builtin_amdgcn_s_barrier();

        bf16x8 af[4], bfv[4];
#pragma unroll
        for (int mt = 0; mt < 4; ++mt)
            af[mt] = fragr(As[cur], wm + mt * 16 + fr, qsw);
#pragma unroll
        for (int nt = 0; nt < 4; ++nt)
            bfv[nt] = fragr(Bs[cur], wn + nt * 16 + fr, qsw);
        __builtin_amdgcn_s_setprio(1);
#pragma unroll
        for (int nt = 0; nt < 4; ++nt)
#pragma unroll
            for (int mt = 0; mt < 4; ++mt)
                acc[mt][nt] = __builtin_amdgcn_mfma_f32_16x16x32_bf16(af[mt], bfv[nt], acc[mt][nt], 0, 0, 0);
        __builtin_amdgcn_s_setprio(0);
    }

    {   // peeled last K-step: it = 63, cur = 63 % 3 = 0 (staged at it=62)
        asm volatile("s_waitcnt vmcnt(0)" ::: "memory");
        __builtin_amdgcn_s_barrier();
        bf16x8 af[4], bfv[4];
#pragma unroll
        for (int mt = 0; mt < 4; ++mt)
            af[mt] = fragr(As[0], wm + mt * 16 + fr, qsw);
#pragma unroll
        for (int nt = 0; nt < 4; ++nt)
            bfv[nt] = fragr(Bs[0], wn + nt * 16 + fr, qsw);
        __builtin_amdgcn_s_setprio(1);
#pragma unroll
        for (int nt = 0; nt < 4; ++nt)
#pragma unroll
            for (int mt = 0; mt < 4; ++mt)
                acc[mt][nt] = __builtin_amdgcn_mfma_f32_16x16x32_bf16(af[mt], bfv[nt], acc[mt][nt], 0, 0, 0);
        __builtin_amdgcn_s_setprio(0);
    }

    const int col = lane & 15, rq = lane >> 4;
#pragma unroll
    for (int mt = 0; mt < 4; ++mt)
#pragma unroll
        for (int nt = 0; nt < 4; ++nt)
#pragma unroll
            for (int e = 0; e < 4; ++e) {
                const int m = m0 + wm + mt * 16 + rq * 4 + e;
                const int n = n0 + wn + nt * 16 + col;
                Ob[(size_t)m * DIM + n] = acc[mt][nt][e];
            }
}

// ---------------------------------------------------------------------------
// Workspace layout (bytes), ws = 167 772 160:
//   Xhi/Xlo/Yhi/Ylo/Vt : 5 x 16 777 216   (bf16 [8192][1024]-sized each)
//   Mthi/Mtlo          : 2 x  2 097 152   (bf16 [1024][1024])
//   Sc                 : 67 108 864       (fp32 [4][2048][2048])
//   Mbits              :    524 288       (u64  [2048][32])       -> 155.7 MB
// Transients aliased INSIDE Sc (consumed before s_gemm writes Sc):
//   Whi/Wlo (2x4.2 MB) + WvT (2.1 MB) + Mtp (4x4.2 MB fp32) = 27.3 MB
// P (bf16) written in place into Sc rows (row r at ushort offset r*4096).
// ---------------------------------------------------------------------------
extern "C" void kernel_launch(void* const* d_in, const int* in_sizes, int n_in,
                              void* d_out, int out_size, void* d_ws, size_t ws_size,
                              hipStream_t stream)
{
    const float* x    = (const float*)d_in[0];
    const int*   mask = (const int*)d_in[1];
    const float* wq   = (const float*)d_in[2];
    const float* wk   = (const float*)d_in[3];
    const float* wv   = (const float*)d_in[4];
    float* out = (float*)d_out;

    const size_t NQ = (size_t)BATCH * SEQ * DIM;     // 8 388 608
    const size_t NM = (size_t)DIM * DIM;             // 1 048 576
    unsigned short* Xhi  = (unsigned short*)d_ws;
    unsigned short* Xlo  = Xhi + NQ;
    unsigned short* Yhi  = Xlo + NQ;
    unsigned short* Ylo  = Yhi + NQ;
    unsigned short* Vt   = Ylo + NQ;
    unsigned short* Mthi = Vt + NQ;
    unsigned short* Mtlo = Mthi + NM;
    float* Sc = (float*)(Mtlo + NM);
    unsigned long long* Mb = (unsigned long long*)(Sc + (size_t)BATCH * SEQ * SEQ);

    unsigned short* Whi = (unsigned short*)Sc;       // transient aliases
    unsigned short* Wlo = Whi + 2 * NM;
    unsigned short* WvT = Wlo + 2 * NM;
    float* Mtp = (float*)(WvT + NM);

    // one-time: dynamic-LDS caps (128 KiB s_gemm, 112 KiB merged yv)
    static bool lds_attr_set = false;
    if (!lds_attr_set) {
        (void)hipFuncSetAttribute((const void*)s_gemm256_kernel,
                                  hipFuncAttributeMaxDynamicSharedMemorySize,
                                  131072);
        (void)hipFuncSetAttribute((const void*)yv_gemm_kernel,
                                  hipFuncAttributeMaxDynamicSharedMemorySize,
                                  114688);
        lds_attr_set = true;
    }

    // 1. X -> hi/lo bf16; mask -> bitmask
    convert_x_kernel<<<dim3(NQ / 4 / 256), 256, 0, stream>>>(x, Xhi, Xlo);
    mask_pack_kernel<<<dim3(SEQ), 256, 0, stream>>>(mask, Mb);
    // 2. Wq/Wk -> hi/lo bf16 (no transpose); Wv -> WvT hi bf16
    convert_wqk_kernel<<<dim3(NM / 4 / 256, 2), 256, 0, stream>>>(wq, wk, Whi, Wlo);
    convert_wv_kernel<<<dim3(32, 32), 256, 0, stream>>>(wv, WvT);
    // 3. Mt = Wk.Wq^T (K-split x4, fp32 partials), then reduce + hi/lo split
    m_gemm_kernel<<<dim3(8, 8, 4), 256, 0, stream>>>(Whi, Wlo, Mtp);
    m_reduce_kernel<<<dim3(NM / 4 / 256), 256, 0, stream>>>(Mtp, Mthi, Mtlo);
    // 4. MERGED: Y = X.Mt^T (3-term hi/lo) AND V = Xhi.WvT^T -> Vt[b][d][s]
    yv_gemm_kernel<<<dim3(DIM / 128, (BATCH * SEQ) / 256), 512, 114688, stream>>>(
        Xhi, Xlo, Mthi, Mtlo, WvT, Yhi, Ylo, Vt);
    // 5. S = masked, scaled Y.X^T per batch (fp32 scores), 256^2 6-phase
    s_gemm256_kernel<<<dim3(SEQ / 256, SEQ / 256, BATCH), 512, 131072, stream>>>(
        Yhi, Ylo, Xhi, Xlo, Mb, Sc);
    // 6. softmax (vectorized); writes bf16 P in place
    softmax_kernel<<<dim3(BATCH * SEQ), 256, 0, stream>>>(Sc);
    // 7. O = P @ V (256x128 tile, triple-buffered single-barrier pipeline)
    pv_mfma_kernel<<<dim3(DIM / 128, SEQ / 256, BATCH), 512, 0, stream>>>(
        (const unsigned short*)Sc, Vt, out);
}

// Round 9
// 339.487 us; speedup vs baseline: 1.1527x; 1.0368x over previous
//
#include <hip/hip_runtime.h>
#include <math.h>

static constexpr int BATCH = 4;
static constexpr int SEQ   = 2048;
static constexpr int DIM   = 1024;

typedef __attribute__((ext_vector_type(8))) short     bf16x8;  // MFMA A/B frag (4 VGPRs)
typedef __attribute__((ext_vector_type(4))) float     f32x4;   // MFMA C/D frag

// fp32 -> bf16 (RNE) and back, bit-exact helpers for hi/lo splitting
__device__ __forceinline__ unsigned short f2b(float v) {
    unsigned int u = __float_as_uint(v);
    u = u + 0x7fffu + ((u >> 16) & 1u);
    return (unsigned short)(u >> 16);
}
__device__ __forceinline__ float b2f(unsigned short h) {
    return __uint_as_float(((unsigned int)h) << 16);
}

// ---------------------------------------------------------------------------
// prep_kernel (round 9): the four independent input-prep passes fused into
// ONE launch, partitioned by blockIdx.x range (all segments 256 threads):
//   [0, 8192)       convert_x   : X fp32 -> Xhi/Xlo bf16
//   [8192, 10240)   convert_wqk : Wq (z=0) / Wk (z=1) -> Whi/Wlo
//   [10240, 11264)  convert_wv  : Wv -> WvT (transposed, hi only)
//   [11264, 13312)  mask_pack   : int32 mask -> u64 bitmask
// Removes 3 launches; memory-bound segments overlap across CUs.
// ---------------------------------------------------------------------------
__global__ __launch_bounds__(256) void prep_kernel(
    const float* __restrict__ X, const float* __restrict__ Wq,
    const float* __restrict__ Wk, const float* __restrict__ Wv,
    const int* __restrict__ mask,
    unsigned short* __restrict__ Xhi, unsigned short* __restrict__ Xlo,
    unsigned short* __restrict__ Whi, unsigned short* __restrict__ Wlo,
    unsigned short* __restrict__ WvT, unsigned long long* __restrict__ Mb)
{
    __shared__ float t[32][33];
    const int blk = blockIdx.x;
    const int tid = threadIdx.x;

    if (blk < 8192) {
        // ---- convert_x ----
        const int i = blk * 256 + tid;                 // float4 index
        const float4 v = ((const float4*)X)[i];
        ushort4 h, l;
        h.x = f2b(v.x); l.x = f2b(v.x - b2f(h.x));
        h.y = f2b(v.y); l.y = f2b(v.y - b2f(h.y));
        h.z = f2b(v.z); l.z = f2b(v.z - b2f(h.z));
        h.w = f2b(v.w); l.w = f2b(v.w - b2f(h.w));
        ((ushort4*)Xhi)[i] = h;
        ((ushort4*)Xlo)[i] = l;
    } else if (blk < 10240) {
        // ---- convert_wqk ----
        const int lcl = blk - 8192;
        const int z = lcl >> 10;                       // 1024 blocks each
        const float* __restrict__ W = z ? Wk : Wq;
        const int i = (lcl & 1023) * 256 + tid;        // float4 index in matrix
        const int o = z * (DIM * DIM / 4) + i;
        const float4 v = ((const float4*)W)[i];
        ushort4 h, l;
        h.x = f2b(v.x); l.x = f2b(v.x - b2f(h.x));
        h.y = f2b(v.y); l.y = f2b(v.y - b2f(h.y));
        h.z = f2b(v.z); l.z = f2b(v.z - b2f(h.z));
        h.w = f2b(v.w); l.w = f2b(v.w - b2f(h.w));
        ((ushort4*)Whi)[o] = h;
        ((ushort4*)Wlo)[o] = l;
    } else if (blk < 11264) {
        // ---- convert_wv (transpose via LDS) ----
        const int lcl = blk - 10240;
        const int n0 = (lcl & 31) * 32, k0 = (lcl >> 5) * 32;
        const int tx = tid & 31, ty = tid >> 5;        // ty: 0..7
#pragma unroll
        for (int i = 0; i < 4; ++i)
            t[ty + i * 8][tx] = Wv[(size_t)(k0 + ty + i * 8) * DIM + (n0 + tx)];
        __syncthreads();
#pragma unroll
        for (int i = 0; i < 4; ++i)
            WvT[(size_t)(n0 + ty + i * 8) * DIM + (k0 + tx)] = f2b(t[tx][ty + i * 8]);
    } else {
        // ---- mask_pack ----
        const int row  = blk - 11264;
        const int lane = tid & 63, w = tid >> 6;
#pragma unroll
        for (int c = w; c < SEQ / 64; c += 4) {
            const int v = mask[(size_t)row * SEQ + c * 64 + lane];
            const unsigned long long bits = __ballot(v != 0);
            if (lane == 0) Mb[(size_t)row * (SEQ / 64) + c] = bits;
        }
    }
}

// ---------------------------------------------------------------------------
// Async staging of a (rows x 32)-elem bf16 tile via global_load_lds w=16.
// XOR-swizzled unpadded 64 B rows; wave-uniform LDS dest. stage_async stages
// 32 rows/wave (128 rows @256thr, 256 rows @512thr); stage128 stages
// 16 rows/wave (128 rows @512thr).
// ---------------------------------------------------------------------------
__device__ __forceinline__ void stage_async(
    const unsigned short* __restrict__ g, int gstride, int row0, int k0,
    unsigned short* lds, int tid)
{
    const int w = tid >> 6, lane = tid & 63;
    const int c = (lane & 3) ^ ((lane >> 4) & 3);   // global chunk this lane fetches
#pragma unroll
    for (int h = 0; h < 2; ++h) {
        const int row = 32 * w + 16 * h + (lane >> 2);
        const unsigned short* src = g + (size_t)(row0 + row) * gstride + k0 + 8 * c;
        unsigned short* dst = lds + (32 * w + 16 * h) * 32;   // wave-uniform
        __builtin_amdgcn_global_load_lds(
            (const __attribute__((address_space(1))) void*)src,
            (__attribute__((address_space(3))) void*)dst, 16, 0, 0);
    }
}

__device__ __forceinline__ void stage128(
    const unsigned short* __restrict__ g, int gstride, int row0, int k0,
    unsigned short* lds, int tid)
{
    const int w = tid >> 6, lane = tid & 63;
    const int c = (lane & 3) ^ ((lane >> 4) & 3);
    const int row = 16 * w + (lane >> 2);
    const unsigned short* src = g + (size_t)(row0 + row) * gstride + k0 + 8 * c;
    unsigned short* dst = lds + (16 * w) * 32;            // wave-uniform
    __builtin_amdgcn_global_load_lds(
        (const __attribute__((address_space(1))) void*)src,
        (__attribute__((address_space(3))) void*)dst, 16, 0, 0);
}

__device__ __forceinline__ bf16x8 fragr(const unsigned short* lds, int row, int qsw)
{
    return *(const bf16x8*)(lds + row * 32 + qsw * 8);
}

// ---------------------------------------------------------------------------
// m_gemm: Mt = Wk . Wq^T  (so Mt[j][i] = sum_o Wq[i][o] Wk[j][o]), 3-term
// split bf16, 128x128 tile, K-split over z (4 chunks of 256). fp32 partials.
// ---------------------------------------------------------------------------
__global__ __launch_bounds__(256) void m_gemm_kernel(
    const unsigned short* __restrict__ Whi, const unsigned short* __restrict__ Wlo,
    float* __restrict__ Mtp)
{
    __shared__ unsigned short Ah[128 * 32], Al[128 * 32];
    __shared__ unsigned short Bh[128 * 32], Bl[128 * 32];

    const int tid = threadIdx.x;
    const int w = tid >> 6, lane = tid & 63;
    const int wm = (w >> 1) * 64, wn = (w & 1) * 64;
    const int m0 = blockIdx.y * 128, n0 = blockIdx.x * 128;
    const int z = blockIdx.z;                        // K chunk

    const unsigned short* __restrict__ Ahg = Whi + (size_t)DIM * DIM;  // Wk hi
    const unsigned short* __restrict__ Alg = Wlo + (size_t)DIM * DIM;  // Wk lo
    const unsigned short* __restrict__ Bhg = Whi;                      // Wq hi
    const unsigned short* __restrict__ Blg = Wlo;                      // Wq lo
    float* __restrict__ Cp = Mtp + (size_t)z * DIM * DIM;

    f32x4 acc[4][4];
#pragma unroll
    for (int i = 0; i < 4; ++i)
#pragma unroll
        for (int j = 0; j < 4; ++j) acc[i][j] = (f32x4){0.f, 0.f, 0.f, 0.f};

    const int fr = lane & 15, quad = lane >> 4;
    const int qsw = quad ^ ((fr >> 2) & 3);

    for (int k0 = z * 256; k0 < z * 256 + 256; k0 += 32) {
        stage_async(Ahg, DIM, m0, k0, Ah, tid);
        stage_async(Alg, DIM, m0, k0, Al, tid);
        stage_async(Bhg, DIM, n0, k0, Bh, tid);
        stage_async(Blg, DIM, n0, k0, Bl, tid);
        __syncthreads();

        bf16x8 ah[4], al[4];
#pragma unroll
        for (int mt = 0; mt < 4; ++mt) {
            ah[mt] = fragr(Ah, wm + mt * 16 + fr, qsw);
            al[mt] = fragr(Al, wm + mt * 16 + fr, qsw);
        }
#pragma unroll
        for (int nt = 0; nt < 4; ++nt) {
            const bf16x8 bh = fragr(Bh, wn + nt * 16 + fr, qsw);
            const bf16x8 bl = fragr(Bl, wn + nt * 16 + fr, qsw);
#pragma unroll
            for (int mt = 0; mt < 4; ++mt) {
                acc[mt][nt] = __builtin_amdgcn_mfma_f32_16x16x32_bf16(ah[mt], bh, acc[mt][nt], 0, 0, 0);
                acc[mt][nt] = __builtin_amdgcn_mfma_f32_16x16x32_bf16(ah[mt], bl, acc[mt][nt], 0, 0, 0);
                acc[mt][nt] = __builtin_amdgcn_mfma_f32_16x16x32_bf16(al[mt], bh, acc[mt][nt], 0, 0, 0);
            }
        }
        __syncthreads();
    }

    const int col = lane & 15, rq = lane >> 4;
#pragma unroll
    for (int mt = 0; mt < 4; ++mt)
#pragma unroll
        for (int nt = 0; nt < 4; ++nt)
#pragma unroll
            for (int e = 0; e < 4; ++e) {
                const int m = m0 + wm + mt * 16 + rq * 4 + e;
                const int n = n0 + wn + nt * 16 + col;
                Cp[(size_t)m * DIM + n] = acc[mt][nt][e];
            }
}

// ---------------------------------------------------------------------------
// m_reduce: sum 4 K-split partials, split to hi/lo bf16.
// ---------------------------------------------------------------------------
__global__ __launch_bounds__(256) void m_reduce_kernel(
    const float* __restrict__ Mtp, unsigned short* __restrict__ Mthi,
    unsigned short* __restrict__ Mtlo)
{
    const int i = blockIdx.x * 256 + threadIdx.x;   // float4 index
    const size_t q = (size_t)DIM * DIM / 4;
    const float4 a = ((const float4*)Mtp)[i];
    const float4 b = ((const float4*)Mtp)[i + q];
    const float4 c = ((const float4*)Mtp)[i + 2 * q];
    const float4 d = ((const float4*)Mtp)[i + 3 * q];
    const float4 v = make_float4(a.x + b.x + c.x + d.x, a.y + b.y + c.y + d.y,
                                 a.z + b.z + c.z + d.z, a.w + b.w + c.w + d.w);
    ushort4 h, l;
    h.x = f2b(v.x); l.x = f2b(v.x - b2f(h.x));
    h.y = f2b(v.y); l.y = f2b(v.y - b2f(h.y));
    h.z = f2b(v.z); l.z = f2b(v.z - b2f(h.z));
    h.w = f2b(v.w); l.w = f2b(v.w - b2f(h.w));
    ((ushort4*)Mthi)[i] = h;
    ((ushort4*)Mtlo)[i] = l;
}

// ---------------------------------------------------------------------------
// yv_gemm (MERGED): one 256x128 tile computes BOTH
//   Y[m0:+256][n0:+128] = X @ Mt^T   (3-term hi/lo, fp32 acc)
//   V[m0:+256][n0:+128] = Xhi @ WvT^T (1-term, written transposed to Vt)
// 4-phase term schedule, 16-MFMA clusters, counted vmcnt. See round-6 notes.
// ---------------------------------------------------------------------------
__global__ __launch_bounds__(512, 2) void yv_gemm_kernel(
    const unsigned short* __restrict__ Xhi, const unsigned short* __restrict__ Xlo,
    const unsigned short* __restrict__ Mthi, const unsigned short* __restrict__ Mtlo,
    const unsigned short* __restrict__ WvT,
    unsigned short* __restrict__ Yhi, unsigned short* __restrict__ Ylo,
    unsigned short* __restrict__ Vt)
{
    extern __shared__ unsigned short smem[];
    // per-buffer ushort offsets: Ah=0, Al=8192, BYh=16384, BYl=20480, BVh=24576
    // buffer stride = 28672 ushorts (56 KiB)

    const int tid = threadIdx.x;
    const int w = tid >> 6, lane = tid & 63;
    const int wm = (w >> 1) * 64, wn = (w & 1) * 64;

    const int flat = blockIdx.x + (blockIdx.y << 3);   // grid (8, 32)
    const int xcd = flat & 7, s = flat >> 3;           // s: 0..31
    const int m0 = (xcd + ((s >> 3) << 3)) * 256;      // m-chunk == xcd (mod 8)
    const int n0 = (s & 7) * 128;

    f32x4 accY[4][4], accV[4][4];
#pragma unroll
    for (int i = 0; i < 4; ++i)
#pragma unroll
        for (int j = 0; j < 4; ++j) {
            accY[i][j] = (f32x4){0.f, 0.f, 0.f, 0.f};
            accV[i][j] = (f32x4){0.f, 0.f, 0.f, 0.f};
        }

    const int fr = lane & 15, quad = lane >> 4;
    const int qsw = quad ^ ((fr >> 2) & 3);

    // prologue: K-step 0 into buffer 0, steady-state issue order
    stage_async(Xhi, DIM, m0, 0, smem + 0,     tid);   // Ah x2
    stage128(Mthi, DIM, n0, 0, smem + 16384, tid);     // BYh
    stage128(Mtlo, DIM, n0, 0, smem + 20480, tid);     // BYl
    stage_async(Xlo, DIM, m0, 0, smem + 8192,  tid);   // Al x2
    stage128(WvT,  DIM, n0, 0, smem + 24576, tid);     // BVh

    bf16x8 ah[4], al[4], bh[4], bl[4], bv[4];

    for (int it = 0; it < DIM / 32 - 1; ++it) {
        const int cur = (it & 1) * 28672;
        const int nxt = 28672 - cur;
        const int k1 = it * 32 + 32;

        // ---- ph0: Y-hh ----
        stage_async(Xhi, DIM, m0, k1, smem + nxt, tid);
        asm volatile("s_waitcnt vmcnt(6)" ::: "memory");
        __builtin_amdgcn_s_barrier();
#pragma unroll
        for (int mt = 0; mt < 4; ++mt)
            ah[mt] = fragr(smem + cur, wm + mt * 16 + fr, qsw);
#pragma unroll
        for (int nt = 0; nt < 4; ++nt)
            bh[nt] = fragr(smem + cur + 16384, wn + nt * 16 + fr, qsw);
        __builtin_amdgcn_s_setprio(1);
#pragma unroll
        for (int nt = 0; nt < 4; ++nt)
#pragma unroll
            for (int mt = 0; mt < 4; ++mt)
                accY[mt][nt] = __builtin_amdgcn_mfma_f32_16x16x32_bf16(ah[mt], bh[nt], accY[mt][nt], 0, 0, 0);
        __builtin_amdgcn_s_setprio(0);

        // ---- ph1: Y-hl (ah held) ----
        stage128(Mthi, DIM, n0, k1, smem + nxt + 16384, tid);
        stage128(Mtlo, DIM, n0, k1, smem + nxt + 20480, tid);
        asm volatile("s_waitcnt vmcnt(7)" ::: "memory");
        __builtin_amdgcn_s_barrier();
#pragma unroll
        for (int nt = 0; nt < 4; ++nt)
            bl[nt] = fragr(smem + cur + 20480, wn + nt * 16 + fr, qsw);
        __builtin_amdgcn_s_setprio(1);
#pragma unroll
        for (int nt = 0; nt < 4; ++nt)
#pragma unroll
            for (int mt = 0; mt < 4; ++mt)
                accY[mt][nt] = __builtin_amdgcn_mfma_f32_16x16x32_bf16(ah[mt], bl[nt], accY[mt][nt], 0, 0, 0);
        __builtin_amdgcn_s_setprio(0);

        // ---- ph2: V-h (ah held) ----
        stage_async(Xlo, DIM, m0, k1, smem + nxt + 8192, tid);
        asm volatile("s_waitcnt vmcnt(6)" ::: "memory");
        __builtin_amdgcn_s_barrier();
#pragma unroll
        for (int nt = 0; nt < 4; ++nt)
            bv[nt] = fragr(smem + cur + 24576, wn + nt * 16 + fr, qsw);
        __builtin_amdgcn_s_setprio(1);
#pragma unroll
        for (int nt = 0; nt < 4; ++nt)
#pragma unroll
            for (int mt = 0; mt < 4; ++mt)
                accV[mt][nt] = __builtin_amdgcn_mfma_f32_16x16x32_bf16(ah[mt], bv[nt], accV[mt][nt], 0, 0, 0);
        __builtin_amdgcn_s_setprio(0);

        // ---- ph3: Y-lh (bh held) ----
        stage128(WvT, DIM, n0, k1, smem + nxt + 24576, tid);
        asm volatile("s_waitcnt vmcnt(8)" ::: "memory");
        __builtin_amdgcn_s_barrier();
#pragma unroll
        for (int mt = 0; mt < 4; ++mt)
            al[mt] = fragr(smem + cur + 8192, wm + mt * 16 + fr, qsw);
        __builtin_amdgcn_s_setprio(1);
#pragma unroll
        for (int nt = 0; nt < 4; ++nt)
#pragma unroll
            for (int mt = 0; mt < 4; ++mt)
                accY[mt][nt] = __builtin_amdgcn_mfma_f32_16x16x32_bf16(al[mt], bh[nt], accY[mt][nt], 0, 0, 0);
        __builtin_amdgcn_s_setprio(0);
    }

    {   // ---- peeled last K-step (cur = buffer 1): no prefetch ----
        const int cur = 28672;

        asm volatile("s_waitcnt vmcnt(4)" ::: "memory");
        __builtin_amdgcn_s_barrier();
#pragma unroll
        for (int mt = 0; mt < 4; ++mt)
            ah[mt] = fragr(smem + cur, wm + mt * 16 + fr, qsw);
#pragma unroll
        for (int nt = 0; nt < 4; ++nt)
            bh[nt] = fragr(smem + cur + 16384, wn + nt * 16 + fr, qsw);
        __builtin_amdgcn_s_setprio(1);
#pragma unroll
        for (int nt = 0; nt < 4; ++nt)
#pragma unroll
            for (int mt = 0; mt < 4; ++mt)
                accY[mt][nt] = __builtin_amdgcn_mfma_f32_16x16x32_bf16(ah[mt], bh[nt], accY[mt][nt], 0, 0, 0);
        __builtin_amdgcn_s_setprio(0);

        asm volatile("s_waitcnt vmcnt(3)" ::: "memory");
        __builtin_amdgcn_s_barrier();
#pragma unroll
        for (int nt = 0; nt < 4; ++nt)
            bl[nt] = fragr(smem + cur + 20480, wn + nt * 16 + fr, qsw);
        __builtin_amdgcn_s_setprio(1);
#pragma unroll
        for (int nt = 0; nt < 4; ++nt)
#pragma unroll
            for (int mt = 0; mt < 4; ++mt)
                accY[mt][nt] = __builtin_amdgcn_mfma_f32_16x16x32_bf16(ah[mt], bl[nt], accY[mt][nt], 0, 0, 0);
        __builtin_amdgcn_s_setprio(0);

        asm volatile("s_waitcnt vmcnt(0)" ::: "memory");
        __builtin_amdgcn_s_barrier();
#pragma unroll
        for (int nt = 0; nt < 4; ++nt)
            bv[nt] = fragr(smem + cur + 24576, wn + nt * 16 + fr, qsw);
        __builtin_amdgcn_s_setprio(1);
#pragma unroll
        for (int nt = 0; nt < 4; ++nt)
#pragma unroll
            for (int mt = 0; mt < 4; ++mt)
                accV[mt][nt] = __builtin_amdgcn_mfma_f32_16x16x32_bf16(ah[mt], bv[nt], accV[mt][nt], 0, 0, 0);
        __builtin_amdgcn_s_setprio(0);

        // Al already drained (older than BVh) and LDS valid after the barrier
#pragma unroll
        for (int mt = 0; mt < 4; ++mt)
            al[mt] = fragr(smem + cur + 8192, wm + mt * 16 + fr, qsw);
        __builtin_amdgcn_s_setprio(1);
#pragma unroll
        for (int nt = 0; nt < 4; ++nt)
#pragma unroll
            for (int mt = 0; mt < 4; ++mt)
                accY[mt][nt] = __builtin_amdgcn_mfma_f32_16x16x32_bf16(al[mt], bh[nt], accY[mt][nt], 0, 0, 0);
        __builtin_amdgcn_s_setprio(0);
    }

    const int col = lane & 15, rq = lane >> 4;
    // Y epilogue (hi/lo split)
#pragma unroll
    for (int mt = 0; mt < 4; ++mt)
#pragma unroll
        for (int nt = 0; nt < 4; ++nt)
#pragma unroll
            for (int e = 0; e < 4; ++e) {
                const int m = m0 + wm + mt * 16 + rq * 4 + e;
                const int n = n0 + wn + nt * 16 + col;
                const float v = accY[mt][nt][e];
                const unsigned short h = f2b(v);
                Yhi[(size_t)m * DIM + n] = h;
                Ylo[(size_t)m * DIM + n] = f2b(v - b2f(h));
            }
    // V epilogue: write transposed, Vt[b][n][s], 4 consecutive s per ushort4
#pragma unroll
    for (int mt = 0; mt < 4; ++mt)
#pragma unroll
        for (int nt = 0; nt < 4; ++nt) {
            const int m = m0 + wm + mt * 16 + rq * 4;      // 4-aligned
            const int bb = m >> 11, sr = m & (SEQ - 1);
            const int n = n0 + wn + nt * 16 + col;
            ushort4 pk;
            pk.x = f2b(accV[mt][nt][0]);
            pk.y = f2b(accV[mt][nt][1]);
            pk.z = f2b(accV[mt][nt][2]);
            pk.w = f2b(accV[mt][nt][3]);
            *(ushort4*)(Vt + (size_t)bb * DIM * SEQ + (size_t)n * SEQ + sr) = pk;
        }
}

// ---------------------------------------------------------------------------
// s_gemm256: S[b] = (Y[b] . X[b]^T) * 1/32, masked to -inf. fp32 output.
// 256x256 tile, BK=32, 512 threads (8 waves, 2Mx4N, 128x64 per wave).
// 6-PHASE term schedule, 16-MFMA clusters, counted vmcnt (T3+T4+T5).
// XCD-aware bijective block swizzle (T1): grid (8,8,4) = 256 blocks, q=32.
// ---------------------------------------------------------------------------
__global__ __launch_bounds__(512, 2) void s_gemm256_kernel(
    const unsigned short* __restrict__ Yhi, const unsigned short* __restrict__ Ylo,
    const unsigned short* __restrict__ Xhi, const unsigned short* __restrict__ Xlo,
    const unsigned long long* __restrict__ Mb, float* __restrict__ Sc)
{
    extern __shared__ unsigned short smem[];
    // layout (ushort offsets): buffer c at c*32768:
    //   Ah = +0, Al = +8192, Bh = +16384, Bl = +24576   (each 256x32)

    const int tid = threadIdx.x;
    const int w = tid >> 6, lane = tid & 63;
    const int wm = (w >> 2) * 128, wn = (w & 3) * 64;

    const int flat = blockIdx.x + (blockIdx.y << 3) + (blockIdx.z << 6);
    const int lid  = ((flat & 7) << 5) | (flat >> 3);     // bijective, nwg=256
    const int m0 = ((lid >> 3) & 7) * 256, n0 = (lid & 7) * 256;
    const int b  = lid >> 6;

    const unsigned short* __restrict__ Ahg = Yhi + (size_t)b * SEQ * DIM;
    const unsigned short* __restrict__ Alg = Ylo + (size_t)b * SEQ * DIM;
    const unsigned short* __restrict__ Bhg = Xhi + (size_t)b * SEQ * DIM;
    const unsigned short* __restrict__ Blg = Xlo + (size_t)b * SEQ * DIM;
    float* __restrict__ Sb = Sc + (size_t)b * SEQ * SEQ;

    f32x4 acc[8][4];
#pragma unroll
    for (int i = 0; i < 8; ++i)
#pragma unroll
        for (int j = 0; j < 4; ++j) acc[i][j] = (f32x4){0.f, 0.f, 0.f, 0.f};

    const int fr = lane & 15, quad = lane >> 4;
    const int qsw = quad ^ ((fr >> 2) & 3);

    // prologue: issue K-step 0 into buffer 0 in phase-consumption order.
    stage_async(Ahg, DIM, m0, 0, smem + 0,     tid);
    stage_async(Bhg, DIM, n0, 0, smem + 16384, tid);
    stage_async(Blg, DIM, n0, 0, smem + 24576, tid);
    stage_async(Alg, DIM, m0, 0, smem + 8192,  tid);

    for (int it = 0; it < DIM / 32 - 1; ++it) {
        const int cur = (it & 1) * 32768;
        const int nxt = cur ^ 32768;
        const unsigned short* Ah = smem + cur;
        const unsigned short* Al = smem + cur + 8192;
        const unsigned short* Bh = smem + cur + 16384;
        const unsigned short* Bl = smem + cur + 24576;
        const int k1 = it * 32 + 32;

        bf16x8 ah[8], al[8], bh[4], bl[4];

        // ---- ph0a (hh, m-half 0) ----
        stage_async(Ahg, DIM, m0, k1, smem + nxt, tid);
        asm volatile("s_waitcnt vmcnt(6)" ::: "memory");
        __builtin_amdgcn_s_barrier();
#pragma unroll
        for (int mt = 0; mt < 4; ++mt)
            ah[mt] = fragr(Ah, wm + mt * 16 + fr, qsw);
#pragma unroll
        for (int nt = 0; nt < 4; ++nt)
            bh[nt] = fragr(Bh, wn + nt * 16 + fr, qsw);
        __builtin_amdgcn_s_setprio(1);
#pragma unroll
        for (int nt = 0; nt < 4; ++nt)
#pragma unroll
            for (int mt = 0; mt < 4; ++mt)
                acc[mt][nt] = __builtin_amdgcn_mfma_f32_16x16x32_bf16(ah[mt], bh[nt], acc[mt][nt], 0, 0, 0);
        __builtin_amdgcn_s_setprio(0);

        // ---- ph0b (hh, m-half 1) ----
        stage_async(Bhg, DIM, n0, k1, smem + nxt + 16384, tid);
#pragma unroll
        for (int mt = 4; mt < 8; ++mt)
            ah[mt] = fragr(Ah, wm + mt * 16 + fr, qsw);
        __builtin_amdgcn_s_setprio(1);
#pragma unroll
        for (int nt = 0; nt < 4; ++nt)
#pragma unroll
            for (int mt = 4; mt < 8; ++mt)
                acc[mt][nt] = __builtin_amdgcn_mfma_f32_16x16x32_bf16(ah[mt], bh[nt], acc[mt][nt], 0, 0, 0);
        __builtin_amdgcn_s_setprio(0);

        // ---- ph1a (hl, m-half 0) ----
        stage_async(Blg, DIM, n0, k1, smem + nxt + 24576, tid);
        asm volatile("s_waitcnt vmcnt(8)" ::: "memory");
        __builtin_amdgcn_s_barrier();
#pragma unroll
        for (int nt = 0; nt < 4; ++nt)
            bl[nt] = fragr(Bl, wn + nt * 16 + fr, qsw);
        __builtin_amdgcn_s_setprio(1);
#pragma unroll
        for (int nt = 0; nt < 4; ++nt)
#pragma unroll
            for (int mt = 0; mt < 4; ++mt)
                acc[mt][nt] = __builtin_amdgcn_mfma_f32_16x16x32_bf16(ah[mt], bl[nt], acc[mt][nt], 0, 0, 0);
        __builtin_amdgcn_s_setprio(0);

        // ---- ph1b (hl, m-half 1) ----
        __builtin_amdgcn_s_setprio(1);
#pragma unroll
        for (int nt = 0; nt < 4; ++nt)
#pragma unroll
            for (int mt = 4; mt < 8; ++mt)
                acc[mt][nt] = __builtin_amdgcn_mfma_f32_16x16x32_bf16(ah[mt], bl[nt], acc[mt][nt], 0, 0, 0);
        __builtin_amdgcn_s_setprio(0);

        // ---- ph2a (lh, m-half 0) ----
        stage_async(Alg, DIM, m0, k1, smem + nxt + 8192, tid);
        asm volatile("s_waitcnt vmcnt(8)" ::: "memory");
        __builtin_amdgcn_s_barrier();
#pragma unroll
        for (int mt = 0; mt < 4; ++mt)
            al[mt] = fragr(Al, wm + mt * 16 + fr, qsw);
        __builtin_amdgcn_s_setprio(1);
#pragma unroll
        for (int nt = 0; nt < 4; ++nt)
#pragma unroll
            for (int mt = 0; mt < 4; ++mt)
                acc[mt][nt] = __builtin_amdgcn_mfma_f32_16x16x32_bf16(al[mt], bh[nt], acc[mt][nt], 0, 0, 0);
        __builtin_amdgcn_s_setprio(0);

        // ---- ph2b (lh, m-half 1) ----
#pragma unroll
        for (int mt = 4; mt < 8; ++mt)
            al[mt] = fragr(Al, wm + mt * 16 + fr, qsw);
        __builtin_amdgcn_s_setprio(1);
#pragma unroll
        for (int nt = 0; nt < 4; ++nt)
#pragma unroll
            for (int mt = 4; mt < 8; ++mt)
                acc[mt][nt] = __builtin_amdgcn_mfma_f32_16x16x32_bf16(al[mt], bh[nt], acc[mt][nt], 0, 0, 0);
        __builtin_amdgcn_s_setprio(0);
    }

    {   // ---- peeled last K-step (cur = buffer 1): no prefetch ----
        const unsigned short* Ah = smem + 32768;
        const unsigned short* Al = smem + 32768 + 8192;
        const unsigned short* Bh = smem + 32768 + 16384;
        const unsigned short* Bl = smem + 32768 + 24576;

        bf16x8 ah[8], al[8], bh[4], bl[4];

        asm volatile("s_waitcnt vmcnt(4)" ::: "memory");
        __builtin_amdgcn_s_barrier();
#pragma unroll
        for (int mt = 0; mt < 8; ++mt)
            ah[mt] = fragr(Ah, wm + mt * 16 + fr, qsw);
#pragma unroll
        for (int nt = 0; nt < 4; ++nt)
            bh[nt] = fragr(Bh, wn + nt * 16 + fr, qsw);
        __builtin_amdgcn_s_setprio(1);
#pragma unroll
        for (int nt = 0; nt < 4; ++nt)
#pragma unroll
            for (int mt = 0; mt < 8; ++mt)
                acc[mt][nt] = __builtin_amdgcn_mfma_f32_16x16x32_bf16(ah[mt], bh[nt], acc[mt][nt], 0, 0, 0);
        __builtin_amdgcn_s_setprio(0);

        asm volatile("s_waitcnt vmcnt(2)" ::: "memory");
        __builtin_amdgcn_s_barrier();
#pragma unroll
        for (int nt = 0; nt < 4; ++nt)
            bl[nt] = fragr(Bl, wn + nt * 16 + fr, qsw);
        __builtin_amdgcn_s_setprio(1);
#pragma unroll
        for (int nt = 0; nt < 4; ++nt)
#pragma unroll
            for (int mt = 0; mt < 8; ++mt)
                acc[mt][nt] = __builtin_amdgcn_mfma_f32_16x16x32_bf16(ah[mt], bl[nt], acc[mt][nt], 0, 0, 0);
        __builtin_amdgcn_s_setprio(0);

        asm volatile("s_waitcnt vmcnt(0)" ::: "memory");
        __builtin_amdgcn_s_barrier();
#pragma unroll
        for (int mt = 0; mt < 8; ++mt)
            al[mt] = fragr(Al, wm + mt * 16 + fr, qsw);
        __builtin_amdgcn_s_setprio(1);
#pragma unroll
        for (int nt = 0; nt < 4; ++nt)
#pragma unroll
            for (int mt = 0; mt < 8; ++mt)
                acc[mt][nt] = __builtin_amdgcn_mfma_f32_16x16x32_bf16(al[mt], bh[nt], acc[mt][nt], 0, 0, 0);
        __builtin_amdgcn_s_setprio(0);
    }

    const int col = lane & 15, rq = lane >> 4;
    const int wword = (n0 + wn) >> 6;             // one u64 covers nt*16+col
#pragma unroll
    for (int mt = 0; mt < 8; ++mt)
#pragma unroll
        for (int e = 0; e < 4; ++e) {
            const int m = m0 + wm + mt * 16 + rq * 4 + e;
            const unsigned long long word = Mb[(size_t)m * (SEQ / 64) + wword];
#pragma unroll
            for (int nt = 0; nt < 4; ++nt) {
                const int n = n0 + wn + nt * 16 + col;
                const float v = acc[mt][nt][e] * 0.03125f;
                const bool msk = (word >> (nt * 16 + col)) & 1ull;
                Sb[(size_t)m * SEQ + n] = msk ? -INFINITY : v;
            }
        }
}

// ---------------------------------------------------------------------------
// Row softmax on pre-masked, pre-scaled fp32 S; writes bf16 P in place.
// VECTORIZED: 2x float4 loads + one 16B bf16x8 store per thread. Safe:
// all reads complete before the first __syncthreads; all writes after the
// second; write range (floats 0..1023) never overlaps another thread's
// pre-sync read window.
// ---------------------------------------------------------------------------
__global__ __launch_bounds__(256) void softmax_kernel(float* __restrict__ Sc)
{
    const int r = blockIdx.x;          // b*2048 + m
    float* __restrict__ row = Sc + (size_t)r * SEQ;

    const int tid  = threadIdx.x;
    const int lane = tid & 63;
    const int wid  = tid >> 6;

    const float4 v0 = ((const float4*)row)[2 * tid];
    const float4 v1 = ((const float4*)row)[2 * tid + 1];
    float x[8] = {v0.x, v0.y, v0.z, v0.w, v1.x, v1.y, v1.z, v1.w};

    float mx = -INFINITY;
#pragma unroll
    for (int j = 0; j < 8; ++j) mx = fmaxf(mx, x[j]);
    __shared__ float redm[4];
#pragma unroll
    for (int off = 32; off > 0; off >>= 1)
        mx = fmaxf(mx, __shfl_down(mx, off, 64));
    if (lane == 0) redm[wid] = mx;
    __syncthreads();
    mx = fmaxf(fmaxf(redm[0], redm[1]), fmaxf(redm[2], redm[3]));

    float sum = 0.f;
#pragma unroll
    for (int j = 0; j < 8; ++j) {
        const float e = __expf(x[j] - mx);
        x[j] = e;
        sum += e;
    }
    __shared__ float reds[4];
#pragma unroll
    for (int off = 32; off > 0; off >>= 1)
        sum += __shfl_down(sum, off, 64);
    if (lane == 0) reds[wid] = sum;
    __syncthreads();
    sum = (reds[0] + reds[1]) + (reds[2] + reds[3]);

    const float inv = 1.0f / sum;
    unsigned short* __restrict__ prow = (unsigned short*)row;
    bf16x8 pk;
#pragma unroll
    for (int j = 0; j < 8; ++j)
        pk[j] = (short)f2b(x[j] * inv);
    *(bf16x8*)(prow + 8 * tid) = pk;
}

// ---------------------------------------------------------------------------
// O[b] = P[b] @ V[b] (REVERTED to round-6 measured-good version): 128x128
// tile, 256 threads, double-buffered BK=32 with counted vmcnt(4), two
// barriers per iter (2nd barrier guards the cur slot against next prefetch).
// XCD-aware bijective block swizzle: grid (8,16,4)=512, q=64.
// A = P rows (stride 4096 ushorts), B = Vt rows (n-major, k contiguous).
// ---------------------------------------------------------------------------
__global__ __launch_bounds__(256) void pv_mfma_kernel(
    const unsigned short* __restrict__ P, const unsigned short* __restrict__ Vt,
    float* __restrict__ O)
{
    __shared__ unsigned short As[2][128 * 32], Bs[2][128 * 32];

    const int tid = threadIdx.x;
    const int w = tid >> 6, lane = tid & 63;
    const int wm = (w >> 1) * 64, wn = (w & 1) * 64;

    const int flat = blockIdx.x + (blockIdx.y << 3) + (blockIdx.z << 7);
    const int lid  = ((flat & 7) << 6) | (flat >> 3);     // bijective, nwg=512
    const int m0 = ((lid >> 3) & 15) * 128, n0 = (lid & 7) * 128;
    const int b  = lid >> 7;

    const unsigned short* __restrict__ Ag = P + (size_t)b * SEQ * (2 * SEQ);
    const unsigned short* __restrict__ Bg = Vt + (size_t)b * DIM * SEQ;
    float* __restrict__ Ob = O + (size_t)b * SEQ * DIM;

    f32x4 acc[4][4];
#pragma unroll
    for (int i = 0; i < 4; ++i)
#pragma unroll
        for (int j = 0; j < 4; ++j) acc[i][j] = (f32x4){0.f, 0.f, 0.f, 0.f};

    const int fr = lane & 15, quad = lane >> 4;
    const int qsw = quad ^ ((fr >> 2) & 3);

    // prologue: stage K-step 0 into buffer 0
    stage_async(Ag, 2 * SEQ, m0, 0, As[0], tid);
    stage_async(Bg, SEQ,     n0, 0, Bs[0], tid);

    for (int it = 0; it < SEQ / 32 - 1; ++it) {
        const int cur = it & 1, nxt = cur ^ 1;
        const int k1 = it * 32 + 32;

        // prefetch next K-step, then wait only for the previous one
        stage_async(Ag, 2 * SEQ, m0, k1, As[nxt], tid);
        stage_async(Bg, SEQ,     n0, k1, Bs[nxt], tid);
        asm volatile("s_waitcnt vmcnt(4)" ::: "memory");
        __builtin_amdgcn_s_barrier();

        bf16x8 af[4];
#pragma unroll
        for (int mt = 0; mt < 4; ++mt)
            af[mt] = fragr(As[cur], wm + mt * 16 + fr, qsw);
        __builtin_amdgcn_s_setprio(1);
#pragma unroll
        for (int nt = 0; nt < 4; ++nt) {
            const bf16x8 bfg = fragr(Bs[cur], wn + nt * 16 + fr, qsw);
#pragma unroll
            for (int mt = 0; mt < 4; ++mt)
                acc[mt][nt] = __builtin_amdgcn_mfma_f32_16x16x32_bf16(af[mt], bfg, acc[mt][nt], 0, 0, 0);
        }
        __builtin_amdgcn_s_setprio(0);
        __builtin_amdgcn_s_barrier();   // guard cur slot against next prefetch
    }

    {   // peeled last K-step (cur = buffer 1)
        asm volatile("s_waitcnt vmcnt(0)" ::: "memory");
        __builtin_amdgcn_s_barrier();
        bf16x8 af[4];
#pragma unroll
        for (int mt = 0; mt < 4; ++mt)
            af[mt] = fragr(As[1], wm + mt * 16 + fr, qsw);
        __builtin_amdgcn_s_setprio(1);
#pragma unroll
        for (int nt = 0; nt < 4; ++nt) {
            const bf16x8 bfg = fragr(Bs[1], wn + nt * 16 + fr, qsw);
#pragma unroll
            for (int mt = 0; mt < 4; ++mt)
                acc[mt][nt] = __builtin_amdgcn_mfma_f32_16x16x32_bf16(af[mt], bfg, acc[mt][nt], 0, 0, 0);
        }
        __builtin_amdgcn_s_setprio(0);
    }

    const int col = lane & 15, rq = lane >> 4;
#pragma unroll
    for (int mt = 0; mt < 4; ++mt)
#pragma unroll
        for (int nt = 0; nt < 4; ++nt)
#pragma unroll
            for (int e = 0; e < 4; ++e) {
                const int m = m0 + wm + mt * 16 + rq * 4 + e;
                const int n = n0 + wn + nt * 16 + col;
                Ob[(size_t)m * DIM + n] = acc[mt][nt][e];
            }
}

// ---------------------------------------------------------------------------
// Workspace layout (bytes), ws = 167 772 160:
//   Xhi/Xlo/Yhi/Ylo/Vt : 5 x 16 777 216   (bf16 [8192][1024]-sized each)
//   Mthi/Mtlo          : 2 x  2 097 152   (bf16 [1024][1024])
//   Sc                 : 67 108 864       (fp32 [4][2048][2048])
//   Mbits              :    524 288       (u64  [2048][32])       -> 155.7 MB
// Transients aliased INSIDE Sc (consumed before s_gemm writes Sc):
//   Whi/Wlo (2x4.2 MB) + WvT (2.1 MB) + Mtp (4x4.2 MB fp32) = 27.3 MB
// P (bf16) written in place into Sc rows (row r at ushort offset r*4096).
// ---------------------------------------------------------------------------
extern "C" void kernel_launch(void* const* d_in, const int* in_sizes, int n_in,
                              void* d_out, int out_size, void* d_ws, size_t ws_size,
                              hipStream_t stream)
{
    const float* x    = (const float*)d_in[0];
    const int*   mask = (const int*)d_in[1];
    const float* wq   = (const float*)d_in[2];
    const float* wk   = (const float*)d_in[3];
    const float* wv   = (const float*)d_in[4];
    float* out = (float*)d_out;

    const size_t NQ = (size_t)BATCH * SEQ * DIM;     // 8 388 608
    const size_t NM = (size_t)DIM * DIM;             // 1 048 576
    unsigned short* Xhi  = (unsigned short*)d_ws;
    unsigned short* Xlo  = Xhi + NQ;
    unsigned short* Yhi  = Xlo + NQ;
    unsigned short* Ylo  = Yhi + NQ;
    unsigned short* Vt   = Ylo + NQ;
    unsigned short* Mthi = Vt + NQ;
    unsigned short* Mtlo = Mthi + NM;
    float* Sc = (float*)(Mtlo + NM);
    unsigned long long* Mb = (unsigned long long*)(Sc + (size_t)BATCH * SEQ * SEQ);

    unsigned short* Whi = (unsigned short*)Sc;       // transient aliases
    unsigned short* Wlo = Whi + 2 * NM;
    unsigned short* WvT = Wlo + 2 * NM;
    float* Mtp = (float*)(WvT + NM);

    // one-time: dynamic-LDS caps (128 KiB s_gemm, 112 KiB merged yv)
    static bool lds_attr_set = false;
    if (!lds_attr_set) {
        (void)hipFuncSetAttribute((const void*)s_gemm256_kernel,
                                  hipFuncAttributeMaxDynamicSharedMemorySize,
                                  131072);
        (void)hipFuncSetAttribute((const void*)yv_gemm_kernel,
                                  hipFuncAttributeMaxDynamicSharedMemorySize,
                                  114688);
        lds_attr_set = true;
    }

    // 1. FUSED prep: X->hi/lo, Wq/Wk->hi/lo, Wv->WvT, mask->bitmask
    prep_kernel<<<dim3(13312), 256, 0, stream>>>(
        x, wq, wk, wv, mask, Xhi, Xlo, Whi, Wlo, WvT, Mb);
    // 2. Mt = Wk.Wq^T (K-split x4, fp32 partials), then reduce + hi/lo split
    m_gemm_kernel<<<dim3(8, 8, 4), 256, 0, stream>>>(Whi, Wlo, Mtp);
    m_reduce_kernel<<<dim3(NM / 4 / 256), 256, 0, stream>>>(Mtp, Mthi, Mtlo);
    // 3. MERGED: Y = X.Mt^T (3-term hi/lo) AND V = Xhi.WvT^T -> Vt[b][d][s]
    yv_gemm_kernel<<<dim3(DIM / 128, (BATCH * SEQ) / 256), 512, 114688, stream>>>(
        Xhi, Xlo, Mthi, Mtlo, WvT, Yhi, Ylo, Vt);
    // 4. S = masked, scaled Y.X^T per batch (fp32 scores), 256^2 6-phase
    s_gemm256_kernel<<<dim3(SEQ / 256, SEQ / 256, BATCH), 512, 131072, stream>>>(
        Yhi, Ylo, Xhi, Xlo, Mb, Sc);
    // 5. softmax (vectorized); writes bf16 P in place
    softmax_kernel<<<dim3(BATCH * SEQ), 256, 0, stream>>>(Sc);
    // 6. O = P @ V (round-6 double-buffered 128^2, measured-good)
    pv_mfma_kernel<<<dim3(DIM / 128, SEQ / 128, BATCH), 256, 0, stream>>>(
        (const unsigned short*)Sc, Vt, out);
}